// Round 2
// baseline (1694.683 us; speedup 1.0000x reference)
//
#include <hip/hip_runtime.h>
#include <math.h>

#define B_ 16
#define N_ 1024
#define T_ 12
#define DM_ 512
#define H_ 3
#define K_ 3
#define C_ 32
#define RSQRT_DK 0.17677669529663687f

// ---------------- K1: temporal embedding LayerNorm over N ----------------
// TEmx[b,t,n] = LN_n(x[b,n,0,t] + posT[t,n]) * gT[n] + bT[n]
__global__ void k1_temporal_ln(const float* __restrict__ x, const float* __restrict__ posT,
                               const float* __restrict__ gT, const float* __restrict__ bT,
                               float* __restrict__ TEmx) {
  int row = blockIdx.x;                 // b*T + t
  int b = row / T_, t = row - b * T_;
  __shared__ float red[256], red2[256];
  float v[4]; float s = 0.f, s2 = 0.f;
  for (int i = 0; i < 4; ++i) {
    int n = threadIdx.x + (i << 8);
    float val = x[(b * N_ + n) * T_ + t] + posT[t * N_ + n];
    v[i] = val; s += val; s2 += val * val;
  }
  red[threadIdx.x] = s; red2[threadIdx.x] = s2;
  __syncthreads();
  for (int off = 128; off > 0; off >>= 1) {
    if (threadIdx.x < off) { red[threadIdx.x] += red[threadIdx.x + off]; red2[threadIdx.x] += red2[threadIdx.x + off]; }
    __syncthreads();
  }
  float mu = red[0] * (1.f / N_);
  float rs = rsqrtf(red2[0] * (1.f / N_) - mu * mu + 1e-5f);
  for (int i = 0; i < 4; ++i) {
    int n = threadIdx.x + (i << 8);
    TEmx[row * N_ + n] = (v[i] - mu) * rs * gT[n] + bT[n];
  }
}

// ---------------- K2: temporal Q/K/V projections ----------------
// qkv[row][0:96]=Q, [96:192]=K, [192:288]=V ; row = b*T+t
__global__ void k2_qkv(const float* __restrict__ TEmx, const float* __restrict__ WQ,
                       const float* __restrict__ WK, const float* __restrict__ WV,
                       float* __restrict__ qkv) {
  int row = blockIdx.x;
  __shared__ float e[N_];
  for (int i = threadIdx.x; i < N_; i += 256) e[i] = TEmx[row * N_ + i];
  __syncthreads();
  for (int col = threadIdx.x; col < 288; col += 256) {
    int which = col / 96, j = col - which * 96;
    const float* W = (which == 0) ? WQ : ((which == 1) ? WK : WV);
    float acc = 0.f;
    for (int n = 0; n < N_; ++n) acc += e[n] * W[n * 96 + j];
    qkv[row * 288 + col] = acc;
  }
}

// ---------------- K3a: temporal attention (writes re_At output) ----------------
__global__ void k3a_attn(const float* __restrict__ qkv, const float* __restrict__ res_att,
                         float* __restrict__ reAt_out, float* __restrict__ ctx) {
  int b = blockIdx.x;
  __shared__ float q_l[T_ * 288];
  __shared__ float s_l[H_ * T_ * T_];   // 432 scores -> probs
  for (int i = threadIdx.x; i < T_ * 288; i += 256) q_l[i] = qkv[b * T_ * 288 + i];
  __syncthreads();
  for (int idx = threadIdx.x; idx < H_ * T_ * T_; idx += 256) {
    int h = idx / 144, r = idx - h * 144, qi = r / 12, ki = r - qi * 12;
    float acc = 0.f;
    #pragma unroll
    for (int d = 0; d < 32; ++d)
      acc += q_l[qi * 288 + h * 32 + d] * q_l[ki * 288 + 96 + h * 32 + d];
    float sv = acc * RSQRT_DK + res_att[(b * H_ + h) * 144 + qi * 12 + ki];
    s_l[idx] = sv;
    reAt_out[(b * H_ + h) * 144 + qi * 12 + ki] = sv;
  }
  __syncthreads();
  if (threadIdx.x < 36) {               // softmax per (h,q) row of 12
    int h = threadIdx.x / 12, qi = threadIdx.x - h * 12;
    float mx = -1e30f;
    for (int ki = 0; ki < 12; ++ki) mx = fmaxf(mx, s_l[h * 144 + qi * 12 + ki]);
    float sum = 0.f;
    for (int ki = 0; ki < 12; ++ki) { float p = __expf(s_l[h * 144 + qi * 12 + ki] - mx); s_l[h * 144 + qi * 12 + ki] = p; sum += p; }
    float inv = 1.f / sum;
    for (int ki = 0; ki < 12; ++ki) s_l[h * 144 + qi * 12 + ki] *= inv;
  }
  __syncthreads();
  for (int idx = threadIdx.x; idx < T_ * 96; idx += 256) {
    int qi = idx / 96, hd = idx - qi * 96, h = hd >> 5, d = hd & 31;
    float acc = 0.f;
    for (int ki = 0; ki < 12; ++ki)
      acc += s_l[h * 144 + qi * 12 + ki] * q_l[ki * 288 + 192 + h * 32 + d];
    ctx[(b * T_ + qi) * 96 + hd] = acc;
  }
}

// ---------------- K3b: ctx @ fc_t + TEmx, LayerNorm(gamma=1,beta=0) ----------------
__global__ void k3b_tat(const float* __restrict__ ctx, const float* __restrict__ fc_t,
                        const float* __restrict__ TEmx, float* __restrict__ TAT) {
  int row = blockIdx.x;                 // b*T+t
  __shared__ float c_l[96];
  __shared__ float red[256], red2[256];
  if (threadIdx.x < 96) c_l[threadIdx.x] = ctx[row * 96 + threadIdx.x];
  __syncthreads();
  float v[4]; float s = 0.f, s2 = 0.f;
  for (int i = 0; i < 4; ++i) {
    int n = threadIdx.x + (i << 8);
    float acc = TEmx[row * N_ + n];
    for (int j = 0; j < 96; ++j) acc += c_l[j] * fc_t[j * N_ + n];
    v[i] = acc; s += acc; s2 += acc * acc;
  }
  red[threadIdx.x] = s; red2[threadIdx.x] = s2;
  __syncthreads();
  for (int off = 128; off > 0; off >>= 1) {
    if (threadIdx.x < off) { red[threadIdx.x] += red[threadIdx.x + off]; red2[threadIdx.x] += red2[threadIdx.x + off]; }
    __syncthreads();
  }
  float mu = red[0] * (1.f / N_);
  float rs = rsqrtf(red2[0] * (1.f / N_) - mu * mu + 1e-5f);
  for (int i = 0; i < 4; ++i) {
    int n = threadIdx.x + (i << 8);
    TAT[row * N_ + n] = (v[i] - mu) * rs;
  }
}

// ---------------- K4: pre_conv (over t) + pos_embed_S + LayerNorm over 512 ----------------
__global__ void k4_preconv_ln(const float* __restrict__ TAT, const float* __restrict__ pcw,
                              const float* __restrict__ pcb, const float* __restrict__ posS,
                              const float* __restrict__ gS, const float* __restrict__ bS,
                              float* __restrict__ SEmx) {
  int bn = blockIdx.x; int b = bn >> 10, n = bn & 1023;
  __shared__ float tc[12];
  __shared__ float red[256], red2[256];
  if (threadIdx.x < 12) tc[threadIdx.x] = TAT[(b * T_ + threadIdx.x) * N_ + n];
  __syncthreads();
  float v[2]; float s = 0.f, s2 = 0.f;
  for (int i = 0; i < 2; ++i) {
    int d = threadIdx.x + (i << 8);
    float acc = pcb[d];
    #pragma unroll
    for (int t = 0; t < 12; ++t) acc += tc[t] * pcw[d * 12 + t];
    acc += posS[n * DM_ + d];
    v[i] = acc; s += acc; s2 += acc * acc;
  }
  red[threadIdx.x] = s; red2[threadIdx.x] = s2;
  __syncthreads();
  for (int off = 128; off > 0; off >>= 1) {
    if (threadIdx.x < off) { red[threadIdx.x] += red[threadIdx.x + off]; red2[threadIdx.x] += red2[threadIdx.x + off]; }
    __syncthreads();
  }
  float mu = red[0] * (1.f / DM_);
  float rs = rsqrtf(red2[0] * (1.f / DM_) - mu * mu + 1e-5f);
  for (int i = 0; i < 2; ++i) {
    int d = threadIdx.x + (i << 8);
    SEmx[bn * DM_ + d] = (v[i] - mu) * rs * gS[d] + bS[d];
  }
}

// ---------------- K5: spatial Q/K projections ----------------
__global__ void k5_qks(const float* __restrict__ SEmx, const float* __restrict__ WQs,
                       const float* __restrict__ WKs, float* __restrict__ Qs, float* __restrict__ Ks) {
  int bn = blockIdx.x; int b = bn >> 10, n = bn & 1023;
  __shared__ float e[DM_];
  for (int i = threadIdx.x; i < DM_; i += 192) e[i] = SEmx[bn * DM_ + i];
  __syncthreads();
  int col = threadIdx.x;                // 0..191
  int which = col / 96, j = col - which * 96;
  const float* W = which ? WKs : WQs;
  float acc = 0.f;
  for (int d = 0; d < DM_; ++d) acc += e[d] * W[d * 96 + j];
  int k = j >> 5, dd = j & 31;
  float* o = which ? Ks : Qs;
  o[(((b * K_ + k) * N_) + n) * 32 + dd] = acc;
}

// ---------------- K6: fused spatial attention + cheb weighting (flash-style over rows) ----------------
// rhs[b,k,n,t] = sum_mu softmax_mu(Q[mu].K[n]/sqrt32 + adj[mu,n]*mask[k,mu,n]) * cheb[k,mu,n] * x[b,mu,t]
__global__ __launch_bounds__(384) void k6_spatial(
    const float* __restrict__ Qs, const float* __restrict__ Ks,
    const float* __restrict__ adj, const float* __restrict__ mask,
    const float* __restrict__ cheb, const float* __restrict__ x,
    float* __restrict__ rhs) {
  int n0 = blockIdx.x * 32;
  int k = blockIdx.y;
  int b = blockIdx.z;
  const float* maskk = mask + k * (N_ * N_);
  const float* chebk = cheb + k * (N_ * N_);
  const float* Qb = Qs + (size_t)((b * K_ + k) * N_) * 32;
  const float* Kb = Ks + (size_t)((b * K_ + k) * N_) * 32;
  const float* xb = x + b * N_ * T_;

  __shared__ float K_l[32 * 33];   // [d][n] padded
  __shared__ float Q_l[64 * 32];   // [m][d]
  __shared__ float s_l[64 * 32];   // scores -> p*cheb
  __shared__ float x_l[64 * 12];
  __shared__ float pred[8 * 32];   // partial max / partial sum
  __shared__ float mu[32], ell[32], fac[32];
  __shared__ float acc[32 * 13];   // [n][t] padded stride 13

  int tid = threadIdx.x;
  for (int idx = tid; idx < 1024; idx += 384) {
    int n = idx >> 5, d = idx & 31;
    K_l[d * 33 + n] = Kb[(n0 + n) * 32 + d];
  }
  if (tid < 32) { mu[tid] = -1e30f; ell[tid] = 0.f; }
  for (int idx = tid; idx < 32 * 13; idx += 384) acc[idx] = 0.f;
  __syncthreads();

  for (int m0 = 0; m0 < N_; m0 += 64) {
    for (int idx = tid; idx < 2048; idx += 384) Q_l[idx] = Qb[m0 * 32 + idx];
    for (int idx = tid; idx < 768; idx += 384) x_l[idx] = xb[m0 * 12 + idx];
    __syncthreads();
    // scores
    for (int idx = tid; idx < 2048; idx += 384) {
      int m = idx >> 5, n = idx & 31;
      float a = 0.f;
      #pragma unroll
      for (int d = 0; d < 32; ++d) a += Q_l[m * 32 + d] * K_l[d * 33 + n];
      int g = (m0 + m) * N_ + n0 + n;
      s_l[idx] = a * RSQRT_DK + adj[g] * maskk[g];
    }
    __syncthreads();
    if (tid < 256) {                       // column partial max
      int n = tid & 31, g = tid >> 5;
      float mx = -1e30f;
      #pragma unroll
      for (int i = 0; i < 8; ++i) mx = fmaxf(mx, s_l[(g * 8 + i) * 32 + n]);
      pred[g * 32 + n] = mx;
    }
    __syncthreads();
    if (tid < 32) {
      float tm = pred[tid];
      #pragma unroll
      for (int g = 1; g < 8; ++g) tm = fmaxf(tm, pred[g * 32 + tid]);
      float nm = fmaxf(mu[tid], tm);
      fac[tid] = __expf(mu[tid] - nm);
      mu[tid] = nm;
    }
    __syncthreads();
    if (tid < 256) {                       // p = exp(s-mu), keep p*cheb, partial sums of p
      int n = tid & 31, g = tid >> 5;
      float m_n = mu[n];
      float ps = 0.f;
      #pragma unroll
      for (int i = 0; i < 8; ++i) {
        int m = g * 8 + i;
        float p = __expf(s_l[m * 32 + n] - m_n);
        ps += p;
        s_l[m * 32 + n] = p * chebk[(m0 + m) * N_ + n0 + n];
      }
      pred[g * 32 + n] = ps;
    }
    __syncthreads();
    if (tid < 32) {
      float ssum = 0.f;
      #pragma unroll
      for (int g = 0; g < 8; ++g) ssum += pred[g * 32 + tid];
      ell[tid] = ell[tid] * fac[tid] + ssum;
    }
    {                                       // acc update: thread (n,t), all 384
      int n = tid & 31, t = tid >> 5;
      float a = acc[n * 13 + t] * fac[n];
      #pragma unroll 8
      for (int m = 0; m < 64; ++m) a += s_l[m * 32 + n] * x_l[m * 12 + t];
      acc[n * 13 + t] = a;
    }
    __syncthreads();
  }
  {
    int n = tid & 31, t = tid >> 5;
    rhs[((b * K_ + k) * N_ + n0 + n) * 12 + t] = acc[n * 13 + t] / ell[n];
  }
}

// ---------------- K7: Theta contraction + relu -> X in (B,N,C,T) ----------------
__global__ void k7_theta(const float* __restrict__ rhs, const float* __restrict__ Theta,
                         float* __restrict__ X) {
  int idx = blockIdx.x * 256 + threadIdx.x;   // (b,n,c,t), t fastest
  int t = idx % 12; int rest = idx / 12;
  int c = rest & 31; rest >>= 5;
  int n = rest & 1023; int b = rest >> 10;
  float a = 0.f;
  #pragma unroll
  for (int k = 0; k < 3; ++k) a += rhs[((b * 3 + k) * N_ + n) * 12 + t] * Theta[k * 32 + c];
  X[idx] = fmaxf(a, 0.f);
}

// ---------------- K8: GTU convs + fcmy + relu -> tco in (B,N,C,T) ----------------
template<int KS>
__device__ __forceinline__ float2 conv_pair(const float* __restrict__ X_l,
                                            const float* __restrict__ w,
                                            const float* __restrict__ bias,
                                            int c, int t0) {
  float ya = bias[c], yb = bias[c + 32];
  const float* wa = w + (c * 32) * KS;
  const float* wb = w + ((c + 32) * 32) * KS;
  #pragma unroll 4
  for (int ic = 0; ic < 32; ++ic) {
    #pragma unroll
    for (int dt = 0; dt < KS; ++dt) {
      float xv = X_l[ic * 12 + t0 + dt];
      ya += xv * wa[ic * KS + dt];
      yb += xv * wb[ic * KS + dt];
    }
  }
  return make_float2(ya, yb);
}

__global__ void k8_gtu(const float* __restrict__ X,
                       const float* __restrict__ w3, const float* __restrict__ b3,
                       const float* __restrict__ w5, const float* __restrict__ b5,
                       const float* __restrict__ w7, const float* __restrict__ b7,
                       const float* __restrict__ fw, const float* __restrict__ fb,
                       float* __restrict__ tco) {
  int bn = blockIdx.x;
  __shared__ float X_l[384];
  __shared__ float tc_l[768];     // [c][j], j<24
  int tid = threadIdx.x;
  for (int i = tid; i < 384; i += 256) X_l[i] = X[bn * 384 + i];   // FIX: full 384-elem tile
  __syncthreads();
  int c = tid >> 3, jj = tid & 7;
  for (int jr = 0; jr < 24; jr += 8) {
    int j = jj + jr;
    float2 y;
    if (j < 10)      y = conv_pair<3>(X_l, w3, b3, c, j);
    else if (j < 18) y = conv_pair<5>(X_l, w5, b5, c, j - 10);
    else             y = conv_pair<7>(X_l, w7, b7, c, j - 18);
    tc_l[c * 24 + j] = tanhf(y.x) * (1.f / (1.f + __expf(-y.y)));
  }
  __syncthreads();
  for (int idx = tid; idx < 384; idx += 256) {
    int cc = idx / 12, t = idx - cc * 12;
    float v = fb[t];
    #pragma unroll
    for (int j = 0; j < 24; ++j) v += tc_l[cc * 24 + j] * fw[j * 12 + t];
    tco[bn * 384 + idx] = fmaxf(v, 0.f);
  }
}

// ---------------- K9: residual conv + relu + LayerNorm over C -> out ----------------
__global__ __launch_bounds__(384) void k9_final(
    const float* __restrict__ x, const float* __restrict__ rw,
    const float* __restrict__ rb, const float* __restrict__ tco,
    const float* __restrict__ gf, const float* __restrict__ bf,
    float* __restrict__ out) {
  int bn = blockIdx.x;
  __shared__ float h_l[384];
  __shared__ float stat[24];
  int tid = threadIdx.x;               // 384: c = tid/12, t = tid%12
  int c = tid / 12, t = tid - c * 12;
  float xr = x[bn * 12 + t] * rw[c] + rb[c];
  float v = fmaxf(xr + tco[bn * 384 + tid], 0.f);
  h_l[tid] = v;
  __syncthreads();
  if (tid < 12) {
    float s = 0.f, s2 = 0.f;
    for (int cc = 0; cc < 32; ++cc) { float u = h_l[cc * 12 + tid]; s += u; s2 += u * u; }
    float m = s * (1.f / 32.f);
    stat[tid] = m;
    stat[12 + tid] = rsqrtf(s2 * (1.f / 32.f) - m * m + 1e-5f);
  }
  __syncthreads();
  out[bn * 384 + tid] = (v - stat[t]) * stat[12 + t] * gf[c] + bf[c];
}

// ---------------- launch ----------------
extern "C" void kernel_launch(void* const* d_in, const int* in_sizes, int n_in,
                              void* d_out, int out_size, void* d_ws, size_t ws_size,
                              hipStream_t stream) {
  const float* x       = (const float*)d_in[0];
  const float* res_att = (const float*)d_in[1];
  const float* posT    = (const float*)d_in[2];
  const float* gT      = (const float*)d_in[3];
  const float* bT      = (const float*)d_in[4];
  const float* WQt     = (const float*)d_in[5];
  const float* WKt     = (const float*)d_in[6];
  const float* WVt     = (const float*)d_in[7];
  const float* fct     = (const float*)d_in[8];
  const float* pcw     = (const float*)d_in[9];
  const float* pcb     = (const float*)d_in[10];
  const float* posS    = (const float*)d_in[11];
  const float* gS      = (const float*)d_in[12];
  const float* bS      = (const float*)d_in[13];
  const float* WQs     = (const float*)d_in[14];
  const float* WKs     = (const float*)d_in[15];
  const float* cheb    = (const float*)d_in[16];
  const float* adj     = (const float*)d_in[17];
  const float* mask    = (const float*)d_in[18];
  const float* Theta   = (const float*)d_in[19];
  const float* w3      = (const float*)d_in[20];
  const float* b3      = (const float*)d_in[21];
  const float* w5      = (const float*)d_in[22];
  const float* b5      = (const float*)d_in[23];
  const float* w7      = (const float*)d_in[24];
  const float* b7      = (const float*)d_in[25];
  const float* rw      = (const float*)d_in[26];
  const float* rb      = (const float*)d_in[27];
  const float* fw      = (const float*)d_in[28];
  const float* fb      = (const float*)d_in[29];
  const float* gf      = (const float*)d_in[30];
  const float* bf      = (const float*)d_in[31];

  float* ws = (float*)d_ws;
  float* TEmx = ws;                         // 196608
  float* qkv  = TEmx + 196608;              // 55296
  float* ctx  = qkv + 55296;                // 18432
  float* TAT  = ctx + 18432;                // 196608
  float* SEmx = TAT + 196608;               // 8388608 (reused as X after K5)
  float* Qs   = SEmx + 8388608;             // 1572864
  float* Ks   = Qs + 1572864;               // 1572864
  float* rhs  = Ks + 1572864;               // 589824
  float* tco  = rhs + 589824;               // 6291456
  float* X    = SEmx;                       // overlay: SEmx dead after K5

  float* out  = (float*)d_out;
  float* reAt = out + 6291456;

  k1_temporal_ln<<<B_ * T_, 256, 0, stream>>>(x, posT, gT, bT, TEmx);
  k2_qkv<<<B_ * T_, 256, 0, stream>>>(TEmx, WQt, WKt, WVt, qkv);
  k3a_attn<<<B_, 256, 0, stream>>>(qkv, res_att, reAt, ctx);
  k3b_tat<<<B_ * T_, 256, 0, stream>>>(ctx, fct, TEmx, TAT);
  k4_preconv_ln<<<B_ * N_, 256, 0, stream>>>(TAT, pcw, pcb, posS, gS, bS, SEmx);
  k5_qks<<<B_ * N_, 192, 0, stream>>>(SEmx, WQs, WKs, Qs, Ks);
  k6_spatial<<<dim3(N_ / 32, K_, B_), 384, 0, stream>>>(Qs, Ks, adj, mask, cheb, x, rhs);
  k7_theta<<<(B_ * N_ * C_ * T_) / 256, 256, 0, stream>>>(rhs, Theta, X);
  k8_gtu<<<B_ * N_, 256, 0, stream>>>(X, w3, b3, w5, b5, w7, b7, fw, fb, tco);
  k9_final<<<B_ * N_, 384, 0, stream>>>(x, rw, rb, tco, gf, bf, out);
}

// Round 4
// 1034.479 us; speedup vs baseline: 1.6382x; 1.6382x over previous
//
#include <hip/hip_runtime.h>
#include <math.h>

#define B_ 16
#define N_ 1024
#define T_ 12
#define DM_ 512
#define H_ 3
#define K_ 3
#define C_ 32
#define RSQRT_DK 0.17677669529663687f

// ---------------- K1: temporal embedding LayerNorm over N ----------------
__global__ void k1_temporal_ln(const float* __restrict__ x, const float* __restrict__ posT,
                               const float* __restrict__ gT, const float* __restrict__ bT,
                               float* __restrict__ TEmx) {
  int row = blockIdx.x;                 // b*T + t
  int b = row / T_, t = row - b * T_;
  __shared__ float red[256], red2[256];
  float v[4]; float s = 0.f, s2 = 0.f;
  for (int i = 0; i < 4; ++i) {
    int n = threadIdx.x + (i << 8);
    float val = x[(b * N_ + n) * T_ + t] + posT[t * N_ + n];
    v[i] = val; s += val; s2 += val * val;
  }
  red[threadIdx.x] = s; red2[threadIdx.x] = s2;
  __syncthreads();
  for (int off = 128; off > 0; off >>= 1) {
    if (threadIdx.x < off) { red[threadIdx.x] += red[threadIdx.x + off]; red2[threadIdx.x] += red2[threadIdx.x + off]; }
    __syncthreads();
  }
  float mu = red[0] * (1.f / N_);
  float rs = rsqrtf(red2[0] * (1.f / N_) - mu * mu + 1e-5f);
  for (int i = 0; i < 4; ++i) {
    int n = threadIdx.x + (i << 8);
    TEmx[row * N_ + n] = (v[i] - mu) * rs * gT[n] + bT[n];
  }
}

// ---------------- K2: temporal Q/K/V projections ----------------
__global__ void k2_qkv(const float* __restrict__ TEmx, const float* __restrict__ WQ,
                       const float* __restrict__ WK, const float* __restrict__ WV,
                       float* __restrict__ qkv) {
  int row = blockIdx.x;
  __shared__ float e[N_];
  for (int i = threadIdx.x; i < N_; i += 256) e[i] = TEmx[row * N_ + i];
  __syncthreads();
  for (int col = threadIdx.x; col < 288; col += 256) {
    int which = col / 96, j = col - which * 96;
    const float* W = (which == 0) ? WQ : ((which == 1) ? WK : WV);
    float acc = 0.f;
    for (int n = 0; n < N_; ++n) acc += e[n] * W[n * 96 + j];
    qkv[row * 288 + col] = acc;
  }
}

// ---------------- K3a: temporal attention (writes re_At output) ----------------
__global__ void k3a_attn(const float* __restrict__ qkv, const float* __restrict__ res_att,
                         float* __restrict__ reAt_out, float* __restrict__ ctx) {
  int b = blockIdx.x;
  __shared__ float q_l[T_ * 288];
  __shared__ float s_l[H_ * T_ * T_];
  for (int i = threadIdx.x; i < T_ * 288; i += 256) q_l[i] = qkv[b * T_ * 288 + i];
  __syncthreads();
  for (int idx = threadIdx.x; idx < H_ * T_ * T_; idx += 256) {
    int h = idx / 144, r = idx - h * 144, qi = r / 12, ki = r - qi * 12;
    float acc = 0.f;
    #pragma unroll
    for (int d = 0; d < 32; ++d)
      acc += q_l[qi * 288 + h * 32 + d] * q_l[ki * 288 + 96 + h * 32 + d];
    float sv = acc * RSQRT_DK + res_att[(b * H_ + h) * 144 + qi * 12 + ki];
    s_l[idx] = sv;
    reAt_out[(b * H_ + h) * 144 + qi * 12 + ki] = sv;
  }
  __syncthreads();
  if (threadIdx.x < 36) {
    int h = threadIdx.x / 12, qi = threadIdx.x - h * 12;
    float mx = -1e30f;
    for (int ki = 0; ki < 12; ++ki) mx = fmaxf(mx, s_l[h * 144 + qi * 12 + ki]);
    float sum = 0.f;
    for (int ki = 0; ki < 12; ++ki) { float p = __expf(s_l[h * 144 + qi * 12 + ki] - mx); s_l[h * 144 + qi * 12 + ki] = p; sum += p; }
    float inv = 1.f / sum;
    for (int ki = 0; ki < 12; ++ki) s_l[h * 144 + qi * 12 + ki] *= inv;
  }
  __syncthreads();
  for (int idx = threadIdx.x; idx < T_ * 96; idx += 256) {
    int qi = idx / 96, hd = idx - qi * 96, h = hd >> 5, d = hd & 31;
    float acc = 0.f;
    for (int ki = 0; ki < 12; ++ki)
      acc += s_l[h * 144 + qi * 12 + ki] * q_l[ki * 288 + 192 + h * 32 + d];
    ctx[(b * T_ + qi) * 96 + hd] = acc;
  }
}

// ---------------- K3b: ctx @ fc_t + TEmx, LayerNorm ----------------
__global__ void k3b_tat(const float* __restrict__ ctx, const float* __restrict__ fc_t,
                        const float* __restrict__ TEmx, float* __restrict__ TAT) {
  int row = blockIdx.x;
  __shared__ float c_l[96];
  __shared__ float red[256], red2[256];
  if (threadIdx.x < 96) c_l[threadIdx.x] = ctx[row * 96 + threadIdx.x];
  __syncthreads();
  float v[4]; float s = 0.f, s2 = 0.f;
  for (int i = 0; i < 4; ++i) {
    int n = threadIdx.x + (i << 8);
    float acc = TEmx[row * N_ + n];
    for (int j = 0; j < 96; ++j) acc += c_l[j] * fc_t[j * N_ + n];
    v[i] = acc; s += acc; s2 += acc * acc;
  }
  red[threadIdx.x] = s; red2[threadIdx.x] = s2;
  __syncthreads();
  for (int off = 128; off > 0; off >>= 1) {
    if (threadIdx.x < off) { red[threadIdx.x] += red[threadIdx.x + off]; red2[threadIdx.x] += red2[threadIdx.x + off]; }
    __syncthreads();
  }
  float mu = red[0] * (1.f / N_);
  float rs = rsqrtf(red2[0] * (1.f / N_) - mu * mu + 1e-5f);
  for (int i = 0; i < 4; ++i) {
    int n = threadIdx.x + (i << 8);
    TAT[row * N_ + n] = (v[i] - mu) * rs;
  }
}

// ---------------- K4: pre_conv + pos_embed_S + LayerNorm over 512 ----------------
__global__ void k4_preconv_ln(const float* __restrict__ TAT, const float* __restrict__ pcw,
                              const float* __restrict__ pcb, const float* __restrict__ posS,
                              const float* __restrict__ gS, const float* __restrict__ bS,
                              float* __restrict__ SEmx) {
  int bn = blockIdx.x; int b = bn >> 10, n = bn & 1023;
  __shared__ float tc[12];
  __shared__ float red[256], red2[256];
  if (threadIdx.x < 12) tc[threadIdx.x] = TAT[(b * T_ + threadIdx.x) * N_ + n];
  __syncthreads();
  float v[2]; float s = 0.f, s2 = 0.f;
  for (int i = 0; i < 2; ++i) {
    int d = threadIdx.x + (i << 8);
    float acc = pcb[d];
    #pragma unroll
    for (int t = 0; t < 12; ++t) acc += tc[t] * pcw[d * 12 + t];
    acc += posS[n * DM_ + d];
    v[i] = acc; s += acc; s2 += acc * acc;
  }
  red[threadIdx.x] = s; red2[threadIdx.x] = s2;
  __syncthreads();
  for (int off = 128; off > 0; off >>= 1) {
    if (threadIdx.x < off) { red[threadIdx.x] += red[threadIdx.x + off]; red2[threadIdx.x] += red2[threadIdx.x + off]; }
    __syncthreads();
  }
  float mu = red[0] * (1.f / DM_);
  float rs = rsqrtf(red2[0] * (1.f / DM_) - mu * mu + 1e-5f);
  for (int i = 0; i < 2; ++i) {
    int d = threadIdx.x + (i << 8);
    SEmx[bn * DM_ + d] = (v[i] - mu) * rs * gS[d] + bS[d];
  }
}

// ---------------- K5 v2: spatial Q/K projections as tiled GEMM ----------------
__global__ __launch_bounds__(256) void k5_qks(const float* __restrict__ SEmx,
                                              const float* __restrict__ WQs,
                                              const float* __restrict__ WKs,
                                              float* __restrict__ Qs, float* __restrict__ Ks) {
  int b = blockIdx.y, n0 = blockIdx.x * 64;
  __shared__ float SE_l[64 * 65];        // [n][d], stride 65
  __shared__ float W_l[64 * 196];        // [d][col], stride 196 (16B-aligned rows)
  int tid = threadIdx.x;
  int ng = tid >> 4, cg = tid & 15;      // 16 ngroups x 4n, 16 colgroups x 12
  int ng4 = ng * 4, col0 = cg * 12;
  float acc[4][12];
  #pragma unroll
  for (int i = 0; i < 4; ++i)
    #pragma unroll
    for (int j = 0; j < 12; ++j) acc[i][j] = 0.f;

  for (int dc = 0; dc < DM_; dc += 64) {
    for (int idx = tid; idx < 64 * 64; idx += 256) {
      int i = idx >> 6, j = idx & 63;
      SE_l[i * 65 + j] = SEmx[((b << 10) + n0 + i) * DM_ + dc + j];
    }
    for (int idx = tid; idx < 64 * 192; idx += 256) {
      int d = idx / 192, c = idx - d * 192;
      float v = (c < 96) ? WQs[(dc + d) * 96 + c] : WKs[(dc + d) * 96 + (c - 96)];
      W_l[d * 196 + c] = v;
    }
    __syncthreads();
    #pragma unroll 4
    for (int d = 0; d < 64; ++d) {
      float se[4];
      #pragma unroll
      for (int i = 0; i < 4; ++i) se[i] = SE_l[(ng4 + i) * 65 + d];
      const float4* wp = (const float4*)&W_l[d * 196 + col0];
      float4 w0 = wp[0], w1 = wp[1], w2 = wp[2];
      float wv[12] = {w0.x, w0.y, w0.z, w0.w, w1.x, w1.y, w1.z, w1.w, w2.x, w2.y, w2.z, w2.w};
      #pragma unroll
      for (int i = 0; i < 4; ++i)
        #pragma unroll
        for (int j = 0; j < 12; ++j)
          acc[i][j] = fmaf(se[i], wv[j], acc[i][j]);
    }
    __syncthreads();
  }
  #pragma unroll
  for (int i = 0; i < 4; ++i) {
    int n = n0 + ng4 + i;
    #pragma unroll
    for (int jj = 0; jj < 12; ++jj) {
      int col = col0 + jj;
      int j = (col < 96) ? col : col - 96;
      int k = j >> 5, dd = j & 31;
      float* o = (col < 96) ? Qs : Ks;
      o[(((b * K_ + k) * N_) + n) * 32 + dd] = acc[i][jj];
    }
  }
}

// ---------------- K6: fused spatial attention + cheb weighting ----------------
__global__ __launch_bounds__(384) void k6_spatial(
    const float* __restrict__ Qs, const float* __restrict__ Ks,
    const float* __restrict__ adj, const float* __restrict__ mask,
    const float* __restrict__ cheb, const float* __restrict__ x,
    float* __restrict__ rhs) {
  int n0 = blockIdx.x * 32;
  int k = blockIdx.y;
  int b = blockIdx.z;
  const float* maskk = mask + k * (N_ * N_);
  const float* chebk = cheb + k * (N_ * N_);
  const float* Qb = Qs + (size_t)((b * K_ + k) * N_) * 32;
  const float* Kb = Ks + (size_t)((b * K_ + k) * N_) * 32;
  const float* xb = x + b * N_ * T_;

  __shared__ float K_l[32 * 33];
  __shared__ float Q_l[64 * 32];
  __shared__ float s_l[64 * 32];
  __shared__ float x_l[64 * 12];
  __shared__ float pred[8 * 32];
  __shared__ float mu[32], ell[32], fac[32];
  __shared__ float acc[32 * 13];

  int tid = threadIdx.x;
  for (int idx = tid; idx < 1024; idx += 384) {
    int n = idx >> 5, d = idx & 31;
    K_l[d * 33 + n] = Kb[(n0 + n) * 32 + d];
  }
  if (tid < 32) { mu[tid] = -1e30f; ell[tid] = 0.f; }
  for (int idx = tid; idx < 32 * 13; idx += 384) acc[idx] = 0.f;
  __syncthreads();

  for (int m0 = 0; m0 < N_; m0 += 64) {
    for (int idx = tid; idx < 2048; idx += 384) Q_l[idx] = Qb[m0 * 32 + idx];
    for (int idx = tid; idx < 768; idx += 384) x_l[idx] = xb[m0 * 12 + idx];
    __syncthreads();
    for (int idx = tid; idx < 2048; idx += 384) {
      int m = idx >> 5, n = idx & 31;
      float a = 0.f;
      #pragma unroll
      for (int d = 0; d < 32; ++d) a += Q_l[m * 32 + d] * K_l[d * 33 + n];
      int g = (m0 + m) * N_ + n0 + n;
      s_l[idx] = a * RSQRT_DK + adj[g] * maskk[g];
    }
    __syncthreads();
    if (tid < 256) {
      int n = tid & 31, g = tid >> 5;
      float mx = -1e30f;
      #pragma unroll
      for (int i = 0; i < 8; ++i) mx = fmaxf(mx, s_l[(g * 8 + i) * 32 + n]);
      pred[g * 32 + n] = mx;
    }
    __syncthreads();
    if (tid < 32) {
      float tm = pred[tid];
      #pragma unroll
      for (int g = 1; g < 8; ++g) tm = fmaxf(tm, pred[g * 32 + tid]);
      float nm = fmaxf(mu[tid], tm);
      fac[tid] = __expf(mu[tid] - nm);
      mu[tid] = nm;
    }
    __syncthreads();
    if (tid < 256) {
      int n = tid & 31, g = tid >> 5;
      float m_n = mu[n];
      float ps = 0.f;
      #pragma unroll
      for (int i = 0; i < 8; ++i) {
        int m = g * 8 + i;
        float p = __expf(s_l[m * 32 + n] - m_n);
        ps += p;
        s_l[m * 32 + n] = p * chebk[(m0 + m) * N_ + n0 + n];
      }
      pred[g * 32 + n] = ps;
    }
    __syncthreads();
    if (tid < 32) {
      float ssum = 0.f;
      #pragma unroll
      for (int g = 0; g < 8; ++g) ssum += pred[g * 32 + tid];
      ell[tid] = ell[tid] * fac[tid] + ssum;
    }
    {
      int n = tid & 31, t = tid >> 5;
      float a = acc[n * 13 + t] * fac[n];
      #pragma unroll 8
      for (int m = 0; m < 64; ++m) a += s_l[m * 32 + n] * x_l[m * 12 + t];
      acc[n * 13 + t] = a;
    }
    __syncthreads();
  }
  {
    int n = tid & 31, t = tid >> 5;
    rhs[((b * K_ + k) * N_ + n0 + n) * 12 + t] = acc[n * 13 + t] / ell[n];
  }
}

// ---------------- K7: Theta contraction + relu -> X in (B,N,C,T) ----------------
__global__ void k7_theta(const float* __restrict__ rhs, const float* __restrict__ Theta,
                         float* __restrict__ X) {
  int idx = blockIdx.x * 256 + threadIdx.x;
  int t = idx % 12; int rest = idx / 12;
  int c = rest & 31; rest >>= 5;
  int n = rest & 1023; int b = rest >> 10;
  float a = 0.f;
  #pragma unroll
  for (int k = 0; k < 3; ++k) a += rhs[((b * 3 + k) * N_ + n) * 12 + t] * Theta[k * 32 + c];
  X[idx] = fmaxf(a, 0.f);
}

// ---------------- K8 v2: GTU convs + fcmy, LDS-staged weights ----------------
template<int KS, int J, int JB, int WSTRIDE>
__device__ __forceinline__ void conv_phase(const float* X_s, const float* w_c,
                                           float ya[24], float yb[24]) {
  #pragma unroll 2
  for (int ic = 0; ic < 32; ++ic) {
    const float4* xp = (const float4*)(X_s + ic * 12);
    float4 a0 = xp[0], a1 = xp[1], a2 = xp[2];
    float xr[12] = {a0.x, a0.y, a0.z, a0.w, a1.x, a1.y, a1.z, a1.w, a2.x, a2.y, a2.z, a2.w};
    #pragma unroll
    for (int dt = 0; dt < KS; ++dt) {
      float2 w = *(const float2*)(w_c + (ic * KS + dt) * 2);
      #pragma unroll
      for (int j = 0; j < J; ++j) {
        ya[JB + j] = fmaf(xr[j + dt], w.x, ya[JB + j]);
        yb[JB + j] = fmaf(xr[j + dt], w.y, yb[JB + j]);
      }
    }
  }
}

__global__ __launch_bounds__(256) void k8_gtu(const float* __restrict__ X,
                       const float* __restrict__ w3, const float* __restrict__ b3,
                       const float* __restrict__ w5, const float* __restrict__ b5,
                       const float* __restrict__ w7, const float* __restrict__ b7,
                       const float* __restrict__ fw, const float* __restrict__ fb,
                       float* __restrict__ tco) {
  int bn0 = blockIdx.x * 8;
  __shared__ float X_l[8 * 388];          // [site][c*12+t], stride 388
  __shared__ float wl[14400];             // interleaved pairs; strides 194/322/450
  __shared__ float fw_l[288];
  __shared__ float fb_l[12];
  __shared__ float bias_l[3][64];
  int tid = threadIdx.x;
  int c = tid >> 3, site = tid & 7;
  const float* X_s = &X_l[site * 388];

  for (int idx = tid; idx < 8 * 384; idx += 256) {
    int s = idx / 384, r = idx - s * 384;
    X_l[s * 388 + r] = X[(bn0 + s) * 384 + r];
  }
  for (int i = tid; i < 288; i += 256) fw_l[i] = fw[i];   // FIX: full 288 staged
  if (tid < 12) fb_l[tid] = fb[tid];
  if (tid < 64) { bias_l[0][tid] = b3[tid]; bias_l[1][tid] = b5[tid]; bias_l[2][tid] = b7[tid]; }
  // stage w3: [co][r<96] -> wl[(co&31)*194 + r*2 + (co>>5)]
  for (int idx = tid; idx < 6144; idx += 256) {
    int co = idx / 96, r = idx - co * 96;
    wl[(co & 31) * 194 + r * 2 + (co >> 5)] = w3[idx];
  }
  float ya[24], yb[24];
  #pragma unroll
  for (int j = 0; j < 24; ++j) { ya[j] = 0.f; yb[j] = 0.f; }
  __syncthreads();
  conv_phase<3, 10, 0, 194>(X_s, &wl[c * 194], ya, yb);
  __syncthreads();
  for (int idx = tid; idx < 10240; idx += 256) {
    int co = idx / 160, r = idx - co * 160;
    wl[(co & 31) * 322 + r * 2 + (co >> 5)] = w5[idx];
  }
  __syncthreads();
  conv_phase<5, 8, 10, 322>(X_s, &wl[c * 322], ya, yb);
  __syncthreads();
  for (int idx = tid; idx < 14336; idx += 256) {
    int co = idx / 224, r = idx - co * 224;
    wl[(co & 31) * 450 + r * 2 + (co >> 5)] = w7[idx];
  }
  __syncthreads();
  conv_phase<7, 6, 18, 450>(X_s, &wl[c * 450], ya, yb);

  // gate: tc[j] = tanh(ya+ba)*sigmoid(yb+bb)
  float tc[24];
  #pragma unroll
  for (int j = 0; j < 24; ++j) {
    int cv = (j < 10) ? 0 : ((j < 18) ? 1 : 2);
    float a = ya[j] + bias_l[cv][c];
    float g = yb[j] + bias_l[cv][c + 32];
    float e2a = __expf(2.f * a);
    float th = 1.f - 2.f / (e2a + 1.f);
    float sg = 1.f / (1.f + __expf(-g));
    tc[j] = th * sg;
  }
  // fcmy
  float o[12];
  #pragma unroll
  for (int t = 0; t < 12; ++t) o[t] = fb_l[t];
  #pragma unroll
  for (int j = 0; j < 24; ++j) {
    const float4* fp = (const float4*)&fw_l[j * 12];
    float4 f0 = fp[0], f1 = fp[1], f2 = fp[2];
    float fr[12] = {f0.x, f0.y, f0.z, f0.w, f1.x, f1.y, f1.z, f1.w, f2.x, f2.y, f2.z, f2.w};
    #pragma unroll
    for (int t = 0; t < 12; ++t) o[t] = fmaf(tc[j], fr[t], o[t]);
  }
  float* op = &tco[(bn0 + site) * 384 + c * 12];
  float4 s0 = {fmaxf(o[0],0.f), fmaxf(o[1],0.f), fmaxf(o[2],0.f), fmaxf(o[3],0.f)};
  float4 s1 = {fmaxf(o[4],0.f), fmaxf(o[5],0.f), fmaxf(o[6],0.f), fmaxf(o[7],0.f)};
  float4 s2 = {fmaxf(o[8],0.f), fmaxf(o[9],0.f), fmaxf(o[10],0.f), fmaxf(o[11],0.f)};
  ((float4*)op)[0] = s0; ((float4*)op)[1] = s1; ((float4*)op)[2] = s2;
}

// ---------------- K9: residual conv + relu + LayerNorm over C -> out ----------------
__global__ __launch_bounds__(384) void k9_final(
    const float* __restrict__ x, const float* __restrict__ rw,
    const float* __restrict__ rb, const float* __restrict__ tco,
    const float* __restrict__ gf, const float* __restrict__ bf,
    float* __restrict__ out) {
  int bn = blockIdx.x;
  __shared__ float h_l[384];
  __shared__ float stat[24];
  int tid = threadIdx.x;
  int c = tid / 12, t = tid - c * 12;
  float xr = x[bn * 12 + t] * rw[c] + rb[c];
  float v = fmaxf(xr + tco[bn * 384 + tid], 0.f);
  h_l[tid] = v;
  __syncthreads();
  if (tid < 12) {
    float s = 0.f, s2 = 0.f;
    for (int cc = 0; cc < 32; ++cc) { float u = h_l[cc * 12 + tid]; s += u; s2 += u * u; }
    float m = s * (1.f / 32.f);
    stat[tid] = m;
    stat[12 + tid] = rsqrtf(s2 * (1.f / 32.f) - m * m + 1e-5f);
  }
  __syncthreads();
  out[bn * 384 + tid] = (v - stat[t]) * stat[12 + t] * gf[c] + bf[c];
}

// ---------------- launch ----------------
extern "C" void kernel_launch(void* const* d_in, const int* in_sizes, int n_in,
                              void* d_out, int out_size, void* d_ws, size_t ws_size,
                              hipStream_t stream) {
  const float* x       = (const float*)d_in[0];
  const float* res_att = (const float*)d_in[1];
  const float* posT    = (const float*)d_in[2];
  const float* gT      = (const float*)d_in[3];
  const float* bT      = (const float*)d_in[4];
  const float* WQt     = (const float*)d_in[5];
  const float* WKt     = (const float*)d_in[6];
  const float* WVt     = (const float*)d_in[7];
  const float* fct     = (const float*)d_in[8];
  const float* pcw     = (const float*)d_in[9];
  const float* pcb     = (const float*)d_in[10];
  const float* posS    = (const float*)d_in[11];
  const float* gS      = (const float*)d_in[12];
  const float* bS      = (const float*)d_in[13];
  const float* WQs     = (const float*)d_in[14];
  const float* WKs     = (const float*)d_in[15];
  const float* cheb    = (const float*)d_in[16];
  const float* adj     = (const float*)d_in[17];
  const float* mask    = (const float*)d_in[18];
  const float* Theta   = (const float*)d_in[19];
  const float* w3      = (const float*)d_in[20];
  const float* b3      = (const float*)d_in[21];
  const float* w5      = (const float*)d_in[22];
  const float* b5      = (const float*)d_in[23];
  const float* w7      = (const float*)d_in[24];
  const float* b7      = (const float*)d_in[25];
  const float* rw      = (const float*)d_in[26];
  const float* rb      = (const float*)d_in[27];
  const float* fw      = (const float*)d_in[28];
  const float* fb      = (const float*)d_in[29];
  const float* gf      = (const float*)d_in[30];
  const float* bf      = (const float*)d_in[31];

  float* ws = (float*)d_ws;
  float* TEmx = ws;                         // 196608
  float* qkv  = TEmx + 196608;              // 55296
  float* ctx  = qkv + 55296;                // 18432
  float* TAT  = ctx + 18432;                // 196608
  float* SEmx = TAT + 196608;               // 8388608 (reused as X after K5)
  float* Qs   = SEmx + 8388608;             // 1572864
  float* Ks   = Qs + 1572864;               // 1572864
  float* rhs  = Ks + 1572864;               // 589824
  float* tco  = rhs + 589824;               // 6291456
  float* X    = SEmx;                       // overlay: SEmx dead after K5

  float* out  = (float*)d_out;
  float* reAt = out + 6291456;

  k1_temporal_ln<<<B_ * T_, 256, 0, stream>>>(x, posT, gT, bT, TEmx);
  k2_qkv<<<B_ * T_, 256, 0, stream>>>(TEmx, WQt, WKt, WVt, qkv);
  k3a_attn<<<B_, 256, 0, stream>>>(qkv, res_att, reAt, ctx);
  k3b_tat<<<B_ * T_, 256, 0, stream>>>(ctx, fct, TEmx, TAT);
  k4_preconv_ln<<<B_ * N_, 256, 0, stream>>>(TAT, pcw, pcb, posS, gS, bS, SEmx);
  k5_qks<<<dim3(N_ / 64, B_), 256, 0, stream>>>(SEmx, WQs, WKs, Qs, Ks);
  k6_spatial<<<dim3(N_ / 32, K_, B_), 384, 0, stream>>>(Qs, Ks, adj, mask, cheb, x, rhs);
  k7_theta<<<(B_ * N_ * C_ * T_) / 256, 256, 0, stream>>>(rhs, Theta, X);
  k8_gtu<<<B_ * N_ / 8, 256, 0, stream>>>(X, w3, b3, w5, b5, w7, b7, fw, fb, tco);
  k9_final<<<B_ * N_, 384, 0, stream>>>(x, rw, rb, tco, gf, bf, out);
}

// Round 5
// 717.990 us; speedup vs baseline: 2.3603x; 1.4408x over previous
//
#include <hip/hip_runtime.h>
#include <hip/hip_bf16.h>
#include <math.h>

#define B_ 16
#define N_ 1024
#define T_ 12
#define DM_ 512
#define H_ 3
#define K_ 3
#define C_ 32
#define RSQRT_DK 0.17677669529663687f

typedef __attribute__((ext_vector_type(8))) short bf16x8;
typedef __attribute__((ext_vector_type(4))) float f32x4;

// ---------------- K1: temporal embedding LayerNorm over N ----------------
__global__ void k1_temporal_ln(const float* __restrict__ x, const float* __restrict__ posT,
                               const float* __restrict__ gT, const float* __restrict__ bT,
                               float* __restrict__ TEmx) {
  int row = blockIdx.x;                 // b*T + t
  int b = row / T_, t = row - b * T_;
  __shared__ float red[256], red2[256];
  float v[4]; float s = 0.f, s2 = 0.f;
  for (int i = 0; i < 4; ++i) {
    int n = threadIdx.x + (i << 8);
    float val = x[(b * N_ + n) * T_ + t] + posT[t * N_ + n];
    v[i] = val; s += val; s2 += val * val;
  }
  red[threadIdx.x] = s; red2[threadIdx.x] = s2;
  __syncthreads();
  for (int off = 128; off > 0; off >>= 1) {
    if (threadIdx.x < off) { red[threadIdx.x] += red[threadIdx.x + off]; red2[threadIdx.x] += red2[threadIdx.x + off]; }
    __syncthreads();
  }
  float mu = red[0] * (1.f / N_);
  float rs = rsqrtf(red2[0] * (1.f / N_) - mu * mu + 1e-5f);
  for (int i = 0; i < 4; ++i) {
    int n = threadIdx.x + (i << 8);
    TEmx[row * N_ + n] = (v[i] - mu) * rs * gT[n] + bT[n];
  }
}

// ---------------- K2: temporal Q/K/V projections ----------------
__global__ void k2_qkv(const float* __restrict__ TEmx, const float* __restrict__ WQ,
                       const float* __restrict__ WK, const float* __restrict__ WV,
                       float* __restrict__ qkv) {
  int row = blockIdx.x;
  __shared__ float e[N_];
  for (int i = threadIdx.x; i < N_; i += 256) e[i] = TEmx[row * N_ + i];
  __syncthreads();
  for (int col = threadIdx.x; col < 288; col += 256) {
    int which = col / 96, j = col - which * 96;
    const float* W = (which == 0) ? WQ : ((which == 1) ? WK : WV);
    float acc = 0.f;
    for (int n = 0; n < N_; ++n) acc += e[n] * W[n * 96 + j];
    qkv[row * 288 + col] = acc;
  }
}

// ---------------- K3a: temporal attention (writes re_At output) ----------------
__global__ void k3a_attn(const float* __restrict__ qkv, const float* __restrict__ res_att,
                         float* __restrict__ reAt_out, float* __restrict__ ctx) {
  int b = blockIdx.x;
  __shared__ float q_l[T_ * 288];
  __shared__ float s_l[H_ * T_ * T_];
  for (int i = threadIdx.x; i < T_ * 288; i += 256) q_l[i] = qkv[b * T_ * 288 + i];
  __syncthreads();
  for (int idx = threadIdx.x; idx < H_ * T_ * T_; idx += 256) {
    int h = idx / 144, r = idx - h * 144, qi = r / 12, ki = r - qi * 12;
    float acc = 0.f;
    #pragma unroll
    for (int d = 0; d < 32; ++d)
      acc += q_l[qi * 288 + h * 32 + d] * q_l[ki * 288 + 96 + h * 32 + d];
    float sv = acc * RSQRT_DK + res_att[(b * H_ + h) * 144 + qi * 12 + ki];
    s_l[idx] = sv;
    reAt_out[(b * H_ + h) * 144 + qi * 12 + ki] = sv;
  }
  __syncthreads();
  if (threadIdx.x < 36) {
    int h = threadIdx.x / 12, qi = threadIdx.x - h * 12;
    float mx = -1e30f;
    for (int ki = 0; ki < 12; ++ki) mx = fmaxf(mx, s_l[h * 144 + qi * 12 + ki]);
    float sum = 0.f;
    for (int ki = 0; ki < 12; ++ki) { float p = __expf(s_l[h * 144 + qi * 12 + ki] - mx); s_l[h * 144 + qi * 12 + ki] = p; sum += p; }
    float inv = 1.f / sum;
    for (int ki = 0; ki < 12; ++ki) s_l[h * 144 + qi * 12 + ki] *= inv;
  }
  __syncthreads();
  for (int idx = threadIdx.x; idx < T_ * 96; idx += 256) {
    int qi = idx / 96, hd = idx - qi * 96, h = hd >> 5, d = hd & 31;
    float acc = 0.f;
    for (int ki = 0; ki < 12; ++ki)
      acc += s_l[h * 144 + qi * 12 + ki] * q_l[ki * 288 + 192 + h * 32 + d];
    ctx[(b * T_ + qi) * 96 + hd] = acc;
  }
}

// ---------------- K3b: ctx @ fc_t + TEmx, LayerNorm ----------------
__global__ void k3b_tat(const float* __restrict__ ctx, const float* __restrict__ fc_t,
                        const float* __restrict__ TEmx, float* __restrict__ TAT) {
  int row = blockIdx.x;
  __shared__ float c_l[96];
  __shared__ float red[256], red2[256];
  if (threadIdx.x < 96) c_l[threadIdx.x] = ctx[row * 96 + threadIdx.x];
  __syncthreads();
  float v[4]; float s = 0.f, s2 = 0.f;
  for (int i = 0; i < 4; ++i) {
    int n = threadIdx.x + (i << 8);
    float acc = TEmx[row * N_ + n];
    for (int j = 0; j < 96; ++j) acc += c_l[j] * fc_t[j * N_ + n];
    v[i] = acc; s += acc; s2 += acc * acc;
  }
  red[threadIdx.x] = s; red2[threadIdx.x] = s2;
  __syncthreads();
  for (int off = 128; off > 0; off >>= 1) {
    if (threadIdx.x < off) { red[threadIdx.x] += red[threadIdx.x + off]; red2[threadIdx.x] += red2[threadIdx.x + off]; }
    __syncthreads();
  }
  float mu = red[0] * (1.f / N_);
  float rs = rsqrtf(red2[0] * (1.f / N_) - mu * mu + 1e-5f);
  for (int i = 0; i < 4; ++i) {
    int n = threadIdx.x + (i << 8);
    TAT[row * N_ + n] = (v[i] - mu) * rs;
  }
}

// ---------------- K4: pre_conv + pos_embed_S + LayerNorm over 512 ----------------
__global__ void k4_preconv_ln(const float* __restrict__ TAT, const float* __restrict__ pcw,
                              const float* __restrict__ pcb, const float* __restrict__ posS,
                              const float* __restrict__ gS, const float* __restrict__ bS,
                              float* __restrict__ SEmx) {
  int bn = blockIdx.x; int b = bn >> 10, n = bn & 1023;
  __shared__ float tc[12];
  __shared__ float red[256], red2[256];
  if (threadIdx.x < 12) tc[threadIdx.x] = TAT[(b * T_ + threadIdx.x) * N_ + n];
  __syncthreads();
  float v[2]; float s = 0.f, s2 = 0.f;
  for (int i = 0; i < 2; ++i) {
    int d = threadIdx.x + (i << 8);
    float acc = pcb[d];
    #pragma unroll
    for (int t = 0; t < 12; ++t) acc += tc[t] * pcw[d * 12 + t];
    acc += posS[n * DM_ + d];
    v[i] = acc; s += acc; s2 += acc * acc;
  }
  red[threadIdx.x] = s; red2[threadIdx.x] = s2;
  __syncthreads();
  for (int off = 128; off > 0; off >>= 1) {
    if (threadIdx.x < off) { red[threadIdx.x] += red[threadIdx.x + off]; red2[threadIdx.x] += red2[threadIdx.x + off]; }
    __syncthreads();
  }
  float mu = red[0] * (1.f / DM_);
  float rs = rsqrtf(red2[0] * (1.f / DM_) - mu * mu + 1e-5f);
  for (int i = 0; i < 2; ++i) {
    int d = threadIdx.x + (i << 8);
    SEmx[bn * DM_ + d] = (v[i] - mu) * rs * gS[d] + bS[d];
  }
}

// ---------------- K5 v3: spatial Q/K projections as tiled GEMM, bf16 out ----------------
__global__ __launch_bounds__(256) void k5_qks(const float* __restrict__ SEmx,
                                              const float* __restrict__ WQs,
                                              const float* __restrict__ WKs,
                                              __hip_bfloat16* __restrict__ Qs,
                                              __hip_bfloat16* __restrict__ Ks) {
  int b = blockIdx.y, n0 = blockIdx.x * 64;
  __shared__ float SE_l[64 * 65];        // [n][d], stride 65
  __shared__ float W_l[64 * 196];        // [d][col], stride 196
  int tid = threadIdx.x;
  int ng = tid >> 4, cg = tid & 15;      // 16 ngroups x 4n, 16 colgroups x 12
  int ng4 = ng * 4, col0 = cg * 12;
  float acc[4][12];
  #pragma unroll
  for (int i = 0; i < 4; ++i)
    #pragma unroll
    for (int j = 0; j < 12; ++j) acc[i][j] = 0.f;

  for (int dc = 0; dc < DM_; dc += 64) {
    for (int idx = tid; idx < 64 * 64; idx += 256) {
      int i = idx >> 6, j = idx & 63;
      SE_l[i * 65 + j] = SEmx[((b << 10) + n0 + i) * DM_ + dc + j];
    }
    for (int idx = tid; idx < 64 * 192; idx += 256) {
      int d = idx / 192, c = idx - d * 192;
      float v = (c < 96) ? WQs[(dc + d) * 96 + c] : WKs[(dc + d) * 96 + (c - 96)];
      W_l[d * 196 + c] = v;
    }
    __syncthreads();
    #pragma unroll 4
    for (int d = 0; d < 64; ++d) {
      float se[4];
      #pragma unroll
      for (int i = 0; i < 4; ++i) se[i] = SE_l[(ng4 + i) * 65 + d];
      const float4* wp = (const float4*)&W_l[d * 196 + col0];
      float4 w0 = wp[0], w1 = wp[1], w2 = wp[2];
      float wv[12] = {w0.x, w0.y, w0.z, w0.w, w1.x, w1.y, w1.z, w1.w, w2.x, w2.y, w2.z, w2.w};
      #pragma unroll
      for (int i = 0; i < 4; ++i)
        #pragma unroll
        for (int j = 0; j < 12; ++j)
          acc[i][j] = fmaf(se[i], wv[j], acc[i][j]);
    }
    __syncthreads();
  }
  #pragma unroll
  for (int i = 0; i < 4; ++i) {
    int n = n0 + ng4 + i;
    #pragma unroll
    for (int jj = 0; jj < 12; ++jj) {
      int col = col0 + jj;
      int j = (col < 96) ? col : col - 96;
      int k = j >> 5, dd = j & 31;
      __hip_bfloat16* o = (col < 96) ? Qs : Ks;
      o[(((b * K_ + k) * N_) + n) * 32 + dd] = __float2bfloat16(acc[i][jj]);
    }
  }
}

// ---------------- K6pre: pack {adj*mask, cheb} as float2 ----------------
__global__ void k6_pre(const float* __restrict__ adj, const float* __restrict__ mask,
                       const float* __restrict__ cheb, float2* __restrict__ pk) {
  int idx = blockIdx.x * 256 + threadIdx.x;     // over 3*1024*1024
  int mn = idx & (N_ * N_ - 1);
  pk[idx] = make_float2(adj[mn] * mask[idx], cheb[idx]);
}

// ---------------- K6 v3: MFMA scores + online softmax + cheb-weighted acc ----------------
// rhs[b,k,n,t] = (1/ell[n]) sum_m exp(s[m,n]-mu[n]) * cheb[k,m,n] * x[b,m,t]
// s[m,n] = Q[m].K[n]*RSQRT_DK + adj[m,n]*mask[k,m,n]
__global__ __launch_bounds__(256) void k6_spatial(
    const __hip_bfloat16* __restrict__ Qs, const __hip_bfloat16* __restrict__ Ks,
    const float2* __restrict__ pk, const float* __restrict__ x,
    float* __restrict__ rhs) {
  const int n0 = blockIdx.x * 32;
  const int k  = blockIdx.y;
  const int b  = blockIdx.z;
  const ushort* Qb = (const ushort*)(Qs + (size_t)((b * K_ + k) * N_) * 32);
  const ushort* Kb = (const ushort*)(Ks + (size_t)((b * K_ + k) * N_) * 32);
  const float2* pkk = pk + (size_t)k * (N_ * N_);
  const float*  xb  = x + b * N_ * T_;

  __shared__ __align__(16) ushort Q_lh[64 * 32];  // [m][d] bf16
  __shared__ __align__(16) ushort K_lh[32 * 32];  // [n][d] bf16
  __shared__ __align__(16) float  x_l[64 * 12];
  __shared__ float s_l[64 * 36];                  // p*cheb, stride 36
  __shared__ float pm[4 * 32], ps[4 * 32];
  __shared__ float mu[32], ell[32], fac[32], inv[32];
  __shared__ float red[8 * 32 * 12];

  const int tid  = threadIdx.x;
  const int w    = tid >> 6, lane = tid & 63;
  const int quad = lane >> 4, c16 = lane & 15;
  const int mg   = tid >> 5, nn = tid & 31;       // acc-phase mapping

  if (tid < 128) *(uint4*)(&K_lh[tid * 8]) = *(const uint4*)(Kb + (size_t)n0 * 32 + tid * 8);
  if (tid < 32) { mu[tid] = -1e30f; ell[tid] = 0.f; }
  float accp[12];
  #pragma unroll
  for (int t = 0; t < 12; ++t) accp[t] = 0.f;
  __syncthreads();

  for (int m0 = 0; m0 < N_; m0 += 64) {
    // stage Q tile (4 KB bf16, flat copy) + x tile (3 KB)
    *(uint4*)(&Q_lh[tid * 8]) = *(const uint4*)(Qb + (size_t)m0 * 32 + tid * 8);
    if (tid < 192) *(float4*)(&x_l[tid * 4]) = *(const float4*)(xb + m0 * 12 + tid * 4);
    __syncthreads();

    // scores: wave w owns m-rows [m0+w*16, +16); 2 n-subtiles of 16
    bf16x8 afrag = *(const bf16x8*)(&Q_lh[(w * 16 + c16) * 32 + quad * 8]);
    f32x4 sc[2];
    float am[2][4], ch[2][4];
    #pragma unroll
    for (int ns = 0; ns < 2; ++ns) {
      bf16x8 bfrag = *(const bf16x8*)(&K_lh[(ns * 16 + c16) * 32 + quad * 8]);
      f32x4 z = {0.f, 0.f, 0.f, 0.f};
      sc[ns] = __builtin_amdgcn_mfma_f32_16x16x32_bf16(afrag, bfrag, z, 0, 0, 0);
      #pragma unroll
      for (int r = 0; r < 4; ++r) {          // C layout: row=quad*4+r, col=c16
        int m = m0 + w * 16 + quad * 4 + r;
        float2 p2 = pkk[(size_t)m * N_ + n0 + ns * 16 + c16];
        am[ns][r] = p2.x; ch[ns][r] = p2.y;
      }
    }
    float sv[2][4];
    #pragma unroll
    for (int ns = 0; ns < 2; ++ns) {
      float cmax = -1e30f;
      #pragma unroll
      for (int r = 0; r < 4; ++r) {
        sv[ns][r] = sc[ns][r] * RSQRT_DK + am[ns][r];
        cmax = fmaxf(cmax, sv[ns][r]);
      }
      cmax = fmaxf(cmax, __shfl_xor(cmax, 16));
      cmax = fmaxf(cmax, __shfl_xor(cmax, 32));
      if (lane < 16) pm[w * 32 + ns * 16 + lane] = cmax;
    }
    __syncthreads();
    if (tid < 32) {
      float tm = fmaxf(fmaxf(pm[tid], pm[32 + tid]), fmaxf(pm[64 + tid], pm[96 + tid]));
      float nm = fmaxf(mu[tid], tm);
      fac[tid] = __expf(mu[tid] - nm);
      mu[tid] = nm;
    }
    __syncthreads();
    {   // rescale running accumulators
      float f = fac[nn];
      #pragma unroll
      for (int t = 0; t < 12; ++t) accp[t] *= f;
    }
    #pragma unroll
    for (int ns = 0; ns < 2; ++ns) {
      float mcol = mu[ns * 16 + c16];
      float psum = 0.f;
      #pragma unroll
      for (int r = 0; r < 4; ++r) {
        float p = __expf(sv[ns][r] - mcol);
        psum += p;
        s_l[(w * 16 + quad * 4 + r) * 36 + ns * 16 + c16] = p * ch[ns][r];
      }
      psum += __shfl_xor(psum, 16);
      psum += __shfl_xor(psum, 32);
      if (lane < 16) ps[w * 32 + ns * 16 + lane] = psum;
    }
    __syncthreads();
    if (tid < 32)
      ell[tid] = ell[tid] * fac[tid] + ps[tid] + ps[32 + tid] + ps[64 + tid] + ps[96 + tid];
    // acc: thread (mg,nn) accumulates its 8 m-rows into 12 registers
    #pragma unroll
    for (int mi = 0; mi < 8; ++mi) {
      int m = mg * 8 + mi;
      float pv = s_l[m * 36 + nn];
      const float* xr = &x_l[m * 12];
      #pragma unroll
      for (int t = 0; t < 12; ++t) accp[t] = fmaf(pv, xr[t], accp[t]);
    }
    __syncthreads();
  }
  if (tid < 32) inv[tid] = 1.f / ell[tid];
  #pragma unroll
  for (int t = 0; t < 12; ++t) red[(mg * 32 + nn) * 12 + t] = accp[t];
  __syncthreads();
  for (int idx = tid; idx < 384; idx += 256) {
    int n = idx / 12, t = idx - n * 12;
    float s = 0.f;
    #pragma unroll
    for (int g = 0; g < 8; ++g) s += red[(g * 32 + n) * 12 + t];
    rhs[((size_t)(b * K_ + k) * N_ + n0 + n) * 12 + t] = s * inv[n];
  }
}

// ---------------- K7: Theta contraction + relu -> X in (B,N,C,T) ----------------
__global__ void k7_theta(const float* __restrict__ rhs, const float* __restrict__ Theta,
                         float* __restrict__ X) {
  int idx = blockIdx.x * 256 + threadIdx.x;
  int t = idx % 12; int rest = idx / 12;
  int c = rest & 31; rest >>= 5;
  int n = rest & 1023; int b = rest >> 10;
  float a = 0.f;
  #pragma unroll
  for (int k = 0; k < 3; ++k) a += rhs[((b * 3 + k) * N_ + n) * 12 + t] * Theta[k * 32 + c];
  X[idx] = fmaxf(a, 0.f);
}

// ---------------- K8 v2: GTU convs + fcmy, LDS-staged weights ----------------
template<int KS, int J, int JB, int WSTRIDE>
__device__ __forceinline__ void conv_phase(const float* X_s, const float* w_c,
                                           float ya[24], float yb[24]) {
  #pragma unroll 2
  for (int ic = 0; ic < 32; ++ic) {
    const float4* xp = (const float4*)(X_s + ic * 12);
    float4 a0 = xp[0], a1 = xp[1], a2 = xp[2];
    float xr[12] = {a0.x, a0.y, a0.z, a0.w, a1.x, a1.y, a1.z, a1.w, a2.x, a2.y, a2.z, a2.w};
    #pragma unroll
    for (int dt = 0; dt < KS; ++dt) {
      float2 w = *(const float2*)(w_c + (ic * KS + dt) * 2);
      #pragma unroll
      for (int j = 0; j < J; ++j) {
        ya[JB + j] = fmaf(xr[j + dt], w.x, ya[JB + j]);
        yb[JB + j] = fmaf(xr[j + dt], w.y, yb[JB + j]);
      }
    }
  }
}

__global__ __launch_bounds__(256) void k8_gtu(const float* __restrict__ X,
                       const float* __restrict__ w3, const float* __restrict__ b3,
                       const float* __restrict__ w5, const float* __restrict__ b5,
                       const float* __restrict__ w7, const float* __restrict__ b7,
                       const float* __restrict__ fw, const float* __restrict__ fb,
                       float* __restrict__ tco) {
  int bn0 = blockIdx.x * 8;
  __shared__ float X_l[8 * 388];
  __shared__ float wl[14400];
  __shared__ float fw_l[288];
  __shared__ float fb_l[12];
  __shared__ float bias_l[3][64];
  int tid = threadIdx.x;
  int c = tid >> 3, site = tid & 7;
  const float* X_s = &X_l[site * 388];

  for (int idx = tid; idx < 8 * 384; idx += 256) {
    int s = idx / 384, r = idx - s * 384;
    X_l[s * 388 + r] = X[(bn0 + s) * 384 + r];
  }
  for (int i = tid; i < 288; i += 256) fw_l[i] = fw[i];
  if (tid < 12) fb_l[tid] = fb[tid];
  if (tid < 64) { bias_l[0][tid] = b3[tid]; bias_l[1][tid] = b5[tid]; bias_l[2][tid] = b7[tid]; }
  for (int idx = tid; idx < 6144; idx += 256) {
    int co = idx / 96, r = idx - co * 96;
    wl[(co & 31) * 194 + r * 2 + (co >> 5)] = w3[idx];
  }
  float ya[24], yb[24];
  #pragma unroll
  for (int j = 0; j < 24; ++j) { ya[j] = 0.f; yb[j] = 0.f; }
  __syncthreads();
  conv_phase<3, 10, 0, 194>(X_s, &wl[c * 194], ya, yb);
  __syncthreads();
  for (int idx = tid; idx < 10240; idx += 256) {
    int co = idx / 160, r = idx - co * 160;
    wl[(co & 31) * 322 + r * 2 + (co >> 5)] = w5[idx];
  }
  __syncthreads();
  conv_phase<5, 8, 10, 322>(X_s, &wl[c * 322], ya, yb);
  __syncthreads();
  for (int idx = tid; idx < 14336; idx += 256) {
    int co = idx / 224, r = idx - co * 224;
    wl[(co & 31) * 450 + r * 2 + (co >> 5)] = w7[idx];
  }
  __syncthreads();
  conv_phase<7, 6, 18, 450>(X_s, &wl[c * 450], ya, yb);

  float tc[24];
  #pragma unroll
  for (int j = 0; j < 24; ++j) {
    int cv = (j < 10) ? 0 : ((j < 18) ? 1 : 2);
    float a = ya[j] + bias_l[cv][c];
    float g = yb[j] + bias_l[cv][c + 32];
    float e2a = __expf(2.f * a);
    float th = 1.f - 2.f / (e2a + 1.f);
    float sg = 1.f / (1.f + __expf(-g));
    tc[j] = th * sg;
  }
  float o[12];
  #pragma unroll
  for (int t = 0; t < 12; ++t) o[t] = fb_l[t];
  #pragma unroll
  for (int j = 0; j < 24; ++j) {
    const float4* fp = (const float4*)&fw_l[j * 12];
    float4 f0 = fp[0], f1 = fp[1], f2 = fp[2];
    float fr[12] = {f0.x, f0.y, f0.z, f0.w, f1.x, f1.y, f1.z, f1.w, f2.x, f2.y, f2.z, f2.w};
    #pragma unroll
    for (int t = 0; t < 12; ++t) o[t] = fmaf(tc[j], fr[t], o[t]);
  }
  float* op = &tco[(bn0 + site) * 384 + c * 12];
  float4 s0 = {fmaxf(o[0],0.f), fmaxf(o[1],0.f), fmaxf(o[2],0.f), fmaxf(o[3],0.f)};
  float4 s1 = {fmaxf(o[4],0.f), fmaxf(o[5],0.f), fmaxf(o[6],0.f), fmaxf(o[7],0.f)};
  float4 s2 = {fmaxf(o[8],0.f), fmaxf(o[9],0.f), fmaxf(o[10],0.f), fmaxf(o[11],0.f)};
  ((float4*)op)[0] = s0; ((float4*)op)[1] = s1; ((float4*)op)[2] = s2;
}

// ---------------- K9: residual conv + relu + LayerNorm over C -> out ----------------
__global__ __launch_bounds__(384) void k9_final(
    const float* __restrict__ x, const float* __restrict__ rw,
    const float* __restrict__ rb, const float* __restrict__ tco,
    const float* __restrict__ gf, const float* __restrict__ bf,
    float* __restrict__ out) {
  int bn = blockIdx.x;
  __shared__ float h_l[384];
  __shared__ float stat[24];
  int tid = threadIdx.x;
  int c = tid / 12, t = tid - c * 12;
  float xr = x[bn * 12 + t] * rw[c] + rb[c];
  float v = fmaxf(xr + tco[bn * 384 + tid], 0.f);
  h_l[tid] = v;
  __syncthreads();
  if (tid < 12) {
    float s = 0.f, s2 = 0.f;
    for (int cc = 0; cc < 32; ++cc) { float u = h_l[cc * 12 + tid]; s += u; s2 += u * u; }
    float m = s * (1.f / 32.f);
    stat[tid] = m;
    stat[12 + tid] = rsqrtf(s2 * (1.f / 32.f) - m * m + 1e-5f);
  }
  __syncthreads();
  out[bn * 384 + tid] = (v - stat[t]) * stat[12 + t] * gf[c] + bf[c];
}

// ---------------- launch ----------------
extern "C" void kernel_launch(void* const* d_in, const int* in_sizes, int n_in,
                              void* d_out, int out_size, void* d_ws, size_t ws_size,
                              hipStream_t stream) {
  const float* x       = (const float*)d_in[0];
  const float* res_att = (const float*)d_in[1];
  const float* posT    = (const float*)d_in[2];
  const float* gT      = (const float*)d_in[3];
  const float* bT      = (const float*)d_in[4];
  const float* WQt     = (const float*)d_in[5];
  const float* WKt     = (const float*)d_in[6];
  const float* WVt     = (const float*)d_in[7];
  const float* fct     = (const float*)d_in[8];
  const float* pcw     = (const float*)d_in[9];
  const float* pcb     = (const float*)d_in[10];
  const float* posS    = (const float*)d_in[11];
  const float* gS      = (const float*)d_in[12];
  const float* bS      = (const float*)d_in[13];
  const float* WQs     = (const float*)d_in[14];
  const float* WKs     = (const float*)d_in[15];
  const float* cheb    = (const float*)d_in[16];
  const float* adj     = (const float*)d_in[17];
  const float* mask    = (const float*)d_in[18];
  const float* Theta   = (const float*)d_in[19];
  const float* w3      = (const float*)d_in[20];
  const float* b3      = (const float*)d_in[21];
  const float* w5      = (const float*)d_in[22];
  const float* b5      = (const float*)d_in[23];
  const float* w7      = (const float*)d_in[24];
  const float* b7      = (const float*)d_in[25];
  const float* rw      = (const float*)d_in[26];
  const float* rb      = (const float*)d_in[27];
  const float* fw      = (const float*)d_in[28];
  const float* fb      = (const float*)d_in[29];
  const float* gf      = (const float*)d_in[30];
  const float* bf      = (const float*)d_in[31];

  float* ws = (float*)d_ws;
  float* TEmx = ws;                         // 196608
  float* qkv  = TEmx + 196608;              // 55296
  float* ctx  = qkv + 55296;                // 18432
  float* TAT  = ctx + 18432;                // 196608
  float* SEmx = TAT + 196608;               // 8388608 (reused: pk during k6, X after)
  float* Qsf  = SEmx + 8388608;             // 1572864 slots (bf16 uses half)
  float* Ksf  = Qsf + 1572864;              // 1572864
  float* rhs  = Ksf + 1572864;              // 589824
  float* tco  = rhs + 589824;               // 6291456
  float* X    = SEmx;                       // overlay: SEmx dead after k5; pk dead after k6

  __hip_bfloat16* Qh = (__hip_bfloat16*)Qsf;
  __hip_bfloat16* Kh = (__hip_bfloat16*)Ksf;
  float2* pk = (float2*)SEmx;               // 3*1024*1024 float2 = 6.29M floats < 8.39M

  float* out  = (float*)d_out;
  float* reAt = out + 6291456;

  k1_temporal_ln<<<B_ * T_, 256, 0, stream>>>(x, posT, gT, bT, TEmx);
  k2_qkv<<<B_ * T_, 256, 0, stream>>>(TEmx, WQt, WKt, WVt, qkv);
  k3a_attn<<<B_, 256, 0, stream>>>(qkv, res_att, reAt, ctx);
  k3b_tat<<<B_ * T_, 256, 0, stream>>>(ctx, fct, TEmx, TAT);
  k4_preconv_ln<<<B_ * N_, 256, 0, stream>>>(TAT, pcw, pcb, posS, gS, bS, SEmx);
  k5_qks<<<dim3(N_ / 64, B_), 256, 0, stream>>>(SEmx, WQs, WKs, Qh, Kh);
  k6_pre<<<(K_ * N_ * N_) / 256, 256, 0, stream>>>(adj, mask, cheb, pk);
  k6_spatial<<<dim3(N_ / 32, K_, B_), 256, 0, stream>>>(Qh, Kh, pk, x, rhs);
  k7_theta<<<(B_ * N_ * C_ * T_) / 256, 256, 0, stream>>>(rhs, Theta, X);
  k8_gtu<<<B_ * N_ / 8, 256, 0, stream>>>(X, w3, b3, w5, b5, w7, b7, fw, fb, tco);
  k9_final<<<B_ * N_, 384, 0, stream>>>(x, rw, rb, tco, gf, bf, out);
}

// Round 6
// 654.735 us; speedup vs baseline: 2.5883x; 1.0966x over previous
//
#include <hip/hip_runtime.h>
#include <hip/hip_bf16.h>
#include <math.h>

#define B_ 16
#define N_ 1024
#define T_ 12
#define DM_ 512
#define H_ 3
#define K_ 3
#define C_ 32
#define RSQRT_DK 0.17677669529663687f

typedef __attribute__((ext_vector_type(8))) short bf16x8;
typedef __attribute__((ext_vector_type(4))) float f32x4;

// ---------------- K1: temporal embedding LayerNorm over N ----------------
__global__ void k1_temporal_ln(const float* __restrict__ x, const float* __restrict__ posT,
                               const float* __restrict__ gT, const float* __restrict__ bT,
                               float* __restrict__ TEmx) {
  int row = blockIdx.x;                 // b*T + t
  int b = row / T_, t = row - b * T_;
  __shared__ float red[256], red2[256];
  float v[4]; float s = 0.f, s2 = 0.f;
  for (int i = 0; i < 4; ++i) {
    int n = threadIdx.x + (i << 8);
    float val = x[(b * N_ + n) * T_ + t] + posT[t * N_ + n];
    v[i] = val; s += val; s2 += val * val;
  }
  red[threadIdx.x] = s; red2[threadIdx.x] = s2;
  __syncthreads();
  for (int off = 128; off > 0; off >>= 1) {
    if (threadIdx.x < off) { red[threadIdx.x] += red[threadIdx.x + off]; red2[threadIdx.x] += red2[threadIdx.x + off]; }
    __syncthreads();
  }
  float mu = red[0] * (1.f / N_);
  float rs = rsqrtf(red2[0] * (1.f / N_) - mu * mu + 1e-5f);
  for (int i = 0; i < 4; ++i) {
    int n = threadIdx.x + (i << 8);
    TEmx[row * N_ + n] = (v[i] - mu) * rs * gT[n] + bT[n];
  }
}

// ---------------- K2 v2: temporal Q/K/V projections, K-split x4 ----------------
// part[(row*4+kc)*288 + col] = partial dot over n in [kc*256, kc*256+256)
__global__ __launch_bounds__(256) void k2_qkv(const float* __restrict__ TEmx,
                       const float* __restrict__ WQ, const float* __restrict__ WK,
                       const float* __restrict__ WV, float* __restrict__ part) {
  int kc = blockIdx.x, row = blockIdx.y;
  __shared__ float e[256];
  int tid = threadIdx.x;
  e[tid] = TEmx[row * N_ + kc * 256 + tid];
  __syncthreads();
  for (int col = tid; col < 288; col += 256) {
    int which = col / 96, j = col - which * 96;
    const float* W = (which == 0) ? WQ : ((which == 1) ? WK : WV);
    const float* Wp = W + (size_t)(kc * 256) * 96 + j;
    float acc = 0.f;
    #pragma unroll 8
    for (int n = 0; n < 256; ++n) acc += e[n] * Wp[n * 96];
    part[(row * 4 + kc) * 288 + col] = acc;
  }
}

// ---------------- K3a: temporal attention (sums k2 partials during staging) ----------------
__global__ void k3a_attn(const float* __restrict__ part, const float* __restrict__ res_att,
                         float* __restrict__ reAt_out, float* __restrict__ ctx) {
  int b = blockIdx.x;
  __shared__ float q_l[T_ * 288];
  __shared__ float s_l[H_ * T_ * T_];
  for (int i = threadIdx.x; i < T_ * 288; i += 256) {
    int t = i / 288, col = i - t * 288;
    const float* pr = &part[(size_t)((b * T_ + t) * 4) * 288 + col];
    q_l[i] = pr[0] + pr[288] + pr[576] + pr[864];
  }
  __syncthreads();
  for (int idx = threadIdx.x; idx < H_ * T_ * T_; idx += 256) {
    int h = idx / 144, r = idx - h * 144, qi = r / 12, ki = r - qi * 12;
    float acc = 0.f;
    #pragma unroll
    for (int d = 0; d < 32; ++d)
      acc += q_l[qi * 288 + h * 32 + d] * q_l[ki * 288 + 96 + h * 32 + d];
    float sv = acc * RSQRT_DK + res_att[(b * H_ + h) * 144 + qi * 12 + ki];
    s_l[idx] = sv;
    reAt_out[(b * H_ + h) * 144 + qi * 12 + ki] = sv;
  }
  __syncthreads();
  if (threadIdx.x < 36) {
    int h = threadIdx.x / 12, qi = threadIdx.x - h * 12;
    float mx = -1e30f;
    for (int ki = 0; ki < 12; ++ki) mx = fmaxf(mx, s_l[h * 144 + qi * 12 + ki]);
    float sum = 0.f;
    for (int ki = 0; ki < 12; ++ki) { float p = __expf(s_l[h * 144 + qi * 12 + ki] - mx); s_l[h * 144 + qi * 12 + ki] = p; sum += p; }
    float inv = 1.f / sum;
    for (int ki = 0; ki < 12; ++ki) s_l[h * 144 + qi * 12 + ki] *= inv;
  }
  __syncthreads();
  for (int idx = threadIdx.x; idx < T_ * 96; idx += 256) {
    int qi = idx / 96, hd = idx - qi * 96, h = hd >> 5, d = hd & 31;
    float acc = 0.f;
    for (int ki = 0; ki < 12; ++ki)
      acc += s_l[h * 144 + qi * 12 + ki] * q_l[ki * 288 + 192 + h * 32 + d];
    ctx[(b * T_ + qi) * 96 + hd] = acc;
  }
}

// ---------------- K3b: ctx @ fc_t + TEmx, LayerNorm ----------------
__global__ void k3b_tat(const float* __restrict__ ctx, const float* __restrict__ fc_t,
                        const float* __restrict__ TEmx, float* __restrict__ TAT) {
  int row = blockIdx.x;
  __shared__ float c_l[96];
  __shared__ float red[256], red2[256];
  if (threadIdx.x < 96) c_l[threadIdx.x] = ctx[row * 96 + threadIdx.x];
  __syncthreads();
  float v[4]; float s = 0.f, s2 = 0.f;
  for (int i = 0; i < 4; ++i) {
    int n = threadIdx.x + (i << 8);
    float acc = TEmx[row * N_ + n];
    for (int j = 0; j < 96; ++j) acc += c_l[j] * fc_t[j * N_ + n];
    v[i] = acc; s += acc; s2 += acc * acc;
  }
  red[threadIdx.x] = s; red2[threadIdx.x] = s2;
  __syncthreads();
  for (int off = 128; off > 0; off >>= 1) {
    if (threadIdx.x < off) { red[threadIdx.x] += red[threadIdx.x + off]; red2[threadIdx.x] += red2[threadIdx.x + off]; }
    __syncthreads();
  }
  float mu = red[0] * (1.f / N_);
  float rs = rsqrtf(red2[0] * (1.f / N_) - mu * mu + 1e-5f);
  for (int i = 0; i < 4; ++i) {
    int n = threadIdx.x + (i << 8);
    TAT[row * N_ + n] = (v[i] - mu) * rs;
  }
}

// ---------------- K4: pre_conv + pos_embed_S + LayerNorm over 512 ----------------
__global__ void k4_preconv_ln(const float* __restrict__ TAT, const float* __restrict__ pcw,
                              const float* __restrict__ pcb, const float* __restrict__ posS,
                              const float* __restrict__ gS, const float* __restrict__ bS,
                              float* __restrict__ SEmx) {
  int bn = blockIdx.x; int b = bn >> 10, n = bn & 1023;
  __shared__ float tc[12];
  __shared__ float red[256], red2[256];
  if (threadIdx.x < 12) tc[threadIdx.x] = TAT[(b * T_ + threadIdx.x) * N_ + n];
  __syncthreads();
  float v[2]; float s = 0.f, s2 = 0.f;
  for (int i = 0; i < 2; ++i) {
    int d = threadIdx.x + (i << 8);
    float acc = pcb[d];
    #pragma unroll
    for (int t = 0; t < 12; ++t) acc += tc[t] * pcw[d * 12 + t];
    acc += posS[n * DM_ + d];
    v[i] = acc; s += acc; s2 += acc * acc;
  }
  red[threadIdx.x] = s; red2[threadIdx.x] = s2;
  __syncthreads();
  for (int off = 128; off > 0; off >>= 1) {
    if (threadIdx.x < off) { red[threadIdx.x] += red[threadIdx.x + off]; red2[threadIdx.x] += red2[threadIdx.x + off]; }
    __syncthreads();
  }
  float mu = red[0] * (1.f / DM_);
  float rs = rsqrtf(red2[0] * (1.f / DM_) - mu * mu + 1e-5f);
  for (int i = 0; i < 2; ++i) {
    int d = threadIdx.x + (i << 8);
    SEmx[bn * DM_ + d] = (v[i] - mu) * rs * gS[d] + bS[d];
  }
}

// ---------------- K5 v4: spatial Q/K GEMM, 32-row tiles (2 blocks/CU) ----------------
__global__ __launch_bounds__(256) void k5_qks(const float* __restrict__ SEmx,
                                              const float* __restrict__ WQs,
                                              const float* __restrict__ WKs,
                                              __hip_bfloat16* __restrict__ Qs,
                                              __hip_bfloat16* __restrict__ Ks) {
  int b = blockIdx.y, n0 = blockIdx.x * 32;
  __shared__ float SE_l[32 * 65];        // [n][d], stride 65
  __shared__ float W_l[64 * 196];        // [d][col], stride 196
  int tid = threadIdx.x;
  int ng = tid >> 4, cg = tid & 15;      // 16 ngroups x 2n, 16 colgroups x 12
  int ng2 = ng * 2, col0 = cg * 12;
  float acc[2][12];
  #pragma unroll
  for (int i = 0; i < 2; ++i)
    #pragma unroll
    for (int j = 0; j < 12; ++j) acc[i][j] = 0.f;

  for (int dc = 0; dc < DM_; dc += 64) {
    for (int idx = tid; idx < 32 * 64; idx += 256) {
      int i = idx >> 6, j = idx & 63;
      SE_l[i * 65 + j] = SEmx[((b << 10) + n0 + i) * DM_ + dc + j];
    }
    for (int idx = tid; idx < 64 * 192; idx += 256) {
      int d = idx / 192, c = idx - d * 192;
      float v = (c < 96) ? WQs[(dc + d) * 96 + c] : WKs[(dc + d) * 96 + (c - 96)];
      W_l[d * 196 + c] = v;
    }
    __syncthreads();
    #pragma unroll 4
    for (int d = 0; d < 64; ++d) {
      float se[2];
      #pragma unroll
      for (int i = 0; i < 2; ++i) se[i] = SE_l[(ng2 + i) * 65 + d];
      const float4* wp = (const float4*)&W_l[d * 196 + col0];
      float4 w0 = wp[0], w1 = wp[1], w2 = wp[2];
      float wv[12] = {w0.x, w0.y, w0.z, w0.w, w1.x, w1.y, w1.z, w1.w, w2.x, w2.y, w2.z, w2.w};
      #pragma unroll
      for (int i = 0; i < 2; ++i)
        #pragma unroll
        for (int j = 0; j < 12; ++j)
          acc[i][j] = fmaf(se[i], wv[j], acc[i][j]);
    }
    __syncthreads();
  }
  #pragma unroll
  for (int i = 0; i < 2; ++i) {
    int n = n0 + ng2 + i;
    #pragma unroll
    for (int jj = 0; jj < 12; ++jj) {
      int col = col0 + jj;
      int j = (col < 96) ? col : col - 96;
      int k = j >> 5, dd = j & 31;
      __hip_bfloat16* o = (col < 96) ? Qs : Ks;
      o[(((b * K_ + k) * N_) + n) * 32 + dd] = __float2bfloat16(acc[i][jj]);
    }
  }
}

// ---------------- K6pre: pack {adj*mask, cheb} as float2 ----------------
__global__ void k6_pre(const float* __restrict__ adj, const float* __restrict__ mask,
                       const float* __restrict__ cheb, float2* __restrict__ pk) {
  int idx = blockIdx.x * 256 + threadIdx.x;     // over 3*1024*1024
  int mn = idx & (N_ * N_ - 1);
  pk[idx] = make_float2(adj[mn] * mask[idx], cheb[idx]);
}

// ---------------- K6 v3: MFMA scores + online softmax + cheb-weighted acc ----------------
__global__ __launch_bounds__(256) void k6_spatial(
    const __hip_bfloat16* __restrict__ Qs, const __hip_bfloat16* __restrict__ Ks,
    const float2* __restrict__ pk, const float* __restrict__ x,
    float* __restrict__ rhs) {
  const int n0 = blockIdx.x * 32;
  const int k  = blockIdx.y;
  const int b  = blockIdx.z;
  const ushort* Qb = (const ushort*)(Qs + (size_t)((b * K_ + k) * N_) * 32);
  const ushort* Kb = (const ushort*)(Ks + (size_t)((b * K_ + k) * N_) * 32);
  const float2* pkk = pk + (size_t)k * (N_ * N_);
  const float*  xb  = x + b * N_ * T_;

  __shared__ __align__(16) ushort Q_lh[64 * 32];  // [m][d] bf16
  __shared__ __align__(16) ushort K_lh[32 * 32];  // [n][d] bf16
  __shared__ __align__(16) float  x_l[64 * 12];
  __shared__ float s_l[64 * 36];                  // p*cheb, stride 36
  __shared__ float pm[4 * 32], ps[4 * 32];
  __shared__ float mu[32], ell[32], fac[32], inv[32];
  __shared__ float red[8 * 32 * 12];

  const int tid  = threadIdx.x;
  const int w    = tid >> 6, lane = tid & 63;
  const int quad = lane >> 4, c16 = lane & 15;
  const int mg   = tid >> 5, nn = tid & 31;       // acc-phase mapping

  if (tid < 128) *(uint4*)(&K_lh[tid * 8]) = *(const uint4*)(Kb + (size_t)n0 * 32 + tid * 8);
  if (tid < 32) { mu[tid] = -1e30f; ell[tid] = 0.f; }
  float accp[12];
  #pragma unroll
  for (int t = 0; t < 12; ++t) accp[t] = 0.f;
  __syncthreads();

  for (int m0 = 0; m0 < N_; m0 += 64) {
    *(uint4*)(&Q_lh[tid * 8]) = *(const uint4*)(Qb + (size_t)m0 * 32 + tid * 8);
    if (tid < 192) *(float4*)(&x_l[tid * 4]) = *(const float4*)(xb + m0 * 12 + tid * 4);
    __syncthreads();

    bf16x8 afrag = *(const bf16x8*)(&Q_lh[(w * 16 + c16) * 32 + quad * 8]);
    f32x4 sc[2];
    float am[2][4], ch[2][4];
    #pragma unroll
    for (int ns = 0; ns < 2; ++ns) {
      bf16x8 bfrag = *(const bf16x8*)(&K_lh[(ns * 16 + c16) * 32 + quad * 8]);
      f32x4 z = {0.f, 0.f, 0.f, 0.f};
      sc[ns] = __builtin_amdgcn_mfma_f32_16x16x32_bf16(afrag, bfrag, z, 0, 0, 0);
      #pragma unroll
      for (int r = 0; r < 4; ++r) {
        int m = m0 + w * 16 + quad * 4 + r;
        float2 p2 = pkk[(size_t)m * N_ + n0 + ns * 16 + c16];
        am[ns][r] = p2.x; ch[ns][r] = p2.y;
      }
    }
    float sv[2][4];
    #pragma unroll
    for (int ns = 0; ns < 2; ++ns) {
      float cmax = -1e30f;
      #pragma unroll
      for (int r = 0; r < 4; ++r) {
        sv[ns][r] = sc[ns][r] * RSQRT_DK + am[ns][r];
        cmax = fmaxf(cmax, sv[ns][r]);
      }
      cmax = fmaxf(cmax, __shfl_xor(cmax, 16));
      cmax = fmaxf(cmax, __shfl_xor(cmax, 32));
      if (lane < 16) pm[w * 32 + ns * 16 + lane] = cmax;
    }
    __syncthreads();
    if (tid < 32) {
      float tm = fmaxf(fmaxf(pm[tid], pm[32 + tid]), fmaxf(pm[64 + tid], pm[96 + tid]));
      float nm = fmaxf(mu[tid], tm);
      fac[tid] = __expf(mu[tid] - nm);
      mu[tid] = nm;
    }
    __syncthreads();
    {
      float f = fac[nn];
      #pragma unroll
      for (int t = 0; t < 12; ++t) accp[t] *= f;
    }
    #pragma unroll
    for (int ns = 0; ns < 2; ++ns) {
      float mcol = mu[ns * 16 + c16];
      float psum = 0.f;
      #pragma unroll
      for (int r = 0; r < 4; ++r) {
        float p = __expf(sv[ns][r] - mcol);
        psum += p;
        s_l[(w * 16 + quad * 4 + r) * 36 + ns * 16 + c16] = p * ch[ns][r];
      }
      psum += __shfl_xor(psum, 16);
      psum += __shfl_xor(psum, 32);
      if (lane < 16) ps[w * 32 + ns * 16 + lane] = psum;
    }
    __syncthreads();
    if (tid < 32)
      ell[tid] = ell[tid] * fac[tid] + ps[tid] + ps[32 + tid] + ps[64 + tid] + ps[96 + tid];
    #pragma unroll
    for (int mi = 0; mi < 8; ++mi) {
      int m = mg * 8 + mi;
      float pv = s_l[m * 36 + nn];
      const float* xr = &x_l[m * 12];
      #pragma unroll
      for (int t = 0; t < 12; ++t) accp[t] = fmaf(pv, xr[t], accp[t]);
    }
    __syncthreads();
  }
  if (tid < 32) inv[tid] = 1.f / ell[tid];
  #pragma unroll
  for (int t = 0; t < 12; ++t) red[(mg * 32 + nn) * 12 + t] = accp[t];
  __syncthreads();
  for (int idx = tid; idx < 384; idx += 256) {
    int n = idx / 12, t = idx - n * 12;
    float s = 0.f;
    #pragma unroll
    for (int g = 0; g < 8; ++g) s += red[(g * 32 + n) * 12 + t];
    rhs[((size_t)(b * K_ + k) * N_ + n0 + n) * 12 + t] = s * inv[n];
  }
}

// ---------------- K7: Theta contraction + relu -> X in (B,N,C,T) ----------------
__global__ void k7_theta(const float* __restrict__ rhs, const float* __restrict__ Theta,
                         float* __restrict__ X) {
  int idx = blockIdx.x * 256 + threadIdx.x;
  int t = idx % 12; int rest = idx / 12;
  int c = rest & 31; rest >>= 5;
  int n = rest & 1023; int b = rest >> 10;
  float a = 0.f;
  #pragma unroll
  for (int k = 0; k < 3; ++k) a += rhs[((b * 3 + k) * N_ + n) * 12 + t] * Theta[k * 32 + c];
  X[idx] = fmaxf(a, 0.f);
}

// ---------------- K8 v3: GTU convs + fcmy; 1024 threads, 32 sites/block ----------------
// Lane mapping keeps R5's conflict-free bank patterns: within a wave,
// site = lane&7 (8 distinct, stride-388 -> 8 distinct bank groups),
// c = (lane>>3)&31 (8 distinct per wave, broadcast x8).
template<int KS, int J, int JB, int WSTRIDE>
__device__ __forceinline__ void conv_phase(const float* X_s, const float* w_c,
                                           float ya[24], float yb[24]) {
  #pragma unroll 2
  for (int ic = 0; ic < 32; ++ic) {
    const float4* xp = (const float4*)(X_s + ic * 12);
    float4 a0 = xp[0], a1 = xp[1], a2 = xp[2];
    float xr[12] = {a0.x, a0.y, a0.z, a0.w, a1.x, a1.y, a1.z, a1.w, a2.x, a2.y, a2.z, a2.w};
    #pragma unroll
    for (int dt = 0; dt < KS; ++dt) {
      float2 w = *(const float2*)(w_c + (ic * KS + dt) * 2);
      #pragma unroll
      for (int j = 0; j < J; ++j) {
        ya[JB + j] = fmaf(xr[j + dt], w.x, ya[JB + j]);
        yb[JB + j] = fmaf(xr[j + dt], w.y, yb[JB + j]);
      }
    }
  }
}

__global__ __launch_bounds__(1024) void k8_gtu(const float* __restrict__ X,
                       const float* __restrict__ w3, const float* __restrict__ b3,
                       const float* __restrict__ w5, const float* __restrict__ b5,
                       const float* __restrict__ w7, const float* __restrict__ b7,
                       const float* __restrict__ fw, const float* __restrict__ fb,
                       float* __restrict__ tco) {
  int bn0 = blockIdx.x * 32;
  __shared__ float X_l[32 * 388];         // 49.7 KB
  __shared__ float wl[14400];             // 57.6 KB, strides 194/322/450
  __shared__ float fw_l[288];
  __shared__ float fb_l[12];
  __shared__ float bias_l[3][64];
  int tid = threadIdx.x;
  int c = (tid >> 3) & 31;
  int site = (tid & 7) | ((tid >> 8) << 3);
  const float* X_s = &X_l[site * 388];

  for (int idx = tid; idx < 32 * 384; idx += 1024) {
    int s = idx / 384, r = idx - s * 384;
    X_l[s * 388 + r] = X[(bn0 + s) * 384 + r];
  }
  for (int i = tid; i < 288; i += 1024) fw_l[i] = fw[i];
  if (tid < 12) fb_l[tid] = fb[tid];
  if (tid < 64) { bias_l[0][tid] = b3[tid]; bias_l[1][tid] = b5[tid]; bias_l[2][tid] = b7[tid]; }
  for (int idx = tid; idx < 6144; idx += 1024) {
    int co = idx / 96, r = idx - co * 96;
    wl[(co & 31) * 194 + r * 2 + (co >> 5)] = w3[idx];
  }
  float ya[24], yb[24];
  #pragma unroll
  for (int j = 0; j < 24; ++j) { ya[j] = 0.f; yb[j] = 0.f; }
  __syncthreads();
  conv_phase<3, 10, 0, 194>(X_s, &wl[c * 194], ya, yb);
  __syncthreads();
  for (int idx = tid; idx < 10240; idx += 1024) {
    int co = idx / 160, r = idx - co * 160;
    wl[(co & 31) * 322 + r * 2 + (co >> 5)] = w5[idx];
  }
  __syncthreads();
  conv_phase<5, 8, 10, 322>(X_s, &wl[c * 322], ya, yb);
  __syncthreads();
  for (int idx = tid; idx < 14336; idx += 1024) {
    int co = idx / 224, r = idx - co * 224;
    wl[(co & 31) * 450 + r * 2 + (co >> 5)] = w7[idx];
  }
  __syncthreads();
  conv_phase<7, 6, 18, 450>(X_s, &wl[c * 450], ya, yb);

  float tc[24];
  #pragma unroll
  for (int j = 0; j < 24; ++j) {
    int cv = (j < 10) ? 0 : ((j < 18) ? 1 : 2);
    float a = ya[j] + bias_l[cv][c];
    float g = yb[j] + bias_l[cv][c + 32];
    float e2a = __expf(2.f * a);
    float th = 1.f - 2.f / (e2a + 1.f);
    float sg = 1.f / (1.f + __expf(-g));
    tc[j] = th * sg;
  }
  float o[12];
  #pragma unroll
  for (int t = 0; t < 12; ++t) o[t] = fb_l[t];
  #pragma unroll
  for (int j = 0; j < 24; ++j) {
    const float4* fp = (const float4*)&fw_l[j * 12];
    float4 f0 = fp[0], f1 = fp[1], f2 = fp[2];
    float fr[12] = {f0.x, f0.y, f0.z, f0.w, f1.x, f1.y, f1.z, f1.w, f2.x, f2.y, f2.z, f2.w};
    #pragma unroll
    for (int t = 0; t < 12; ++t) o[t] = fmaf(tc[j], fr[t], o[t]);
  }
  float* op = &tco[(bn0 + site) * 384 + c * 12];
  float4 s0 = {fmaxf(o[0],0.f), fmaxf(o[1],0.f), fmaxf(o[2],0.f), fmaxf(o[3],0.f)};
  float4 s1 = {fmaxf(o[4],0.f), fmaxf(o[5],0.f), fmaxf(o[6],0.f), fmaxf(o[7],0.f)};
  float4 s2 = {fmaxf(o[8],0.f), fmaxf(o[9],0.f), fmaxf(o[10],0.f), fmaxf(o[11],0.f)};
  ((float4*)op)[0] = s0; ((float4*)op)[1] = s1; ((float4*)op)[2] = s2;
}

// ---------------- K9: residual conv + relu + LayerNorm over C -> out ----------------
__global__ __launch_bounds__(384) void k9_final(
    const float* __restrict__ x, const float* __restrict__ rw,
    const float* __restrict__ rb, const float* __restrict__ tco,
    const float* __restrict__ gf, const float* __restrict__ bf,
    float* __restrict__ out) {
  int bn = blockIdx.x;
  __shared__ float h_l[384];
  __shared__ float stat[24];
  int tid = threadIdx.x;
  int c = tid / 12, t = tid - c * 12;
  float xr = x[bn * 12 + t] * rw[c] + rb[c];
  float v = fmaxf(xr + tco[bn * 384 + tid], 0.f);
  h_l[tid] = v;
  __syncthreads();
  if (tid < 12) {
    float s = 0.f, s2 = 0.f;
    for (int cc = 0; cc < 32; ++cc) { float u = h_l[cc * 12 + tid]; s += u; s2 += u * u; }
    float m = s * (1.f / 32.f);
    stat[tid] = m;
    stat[12 + tid] = rsqrtf(s2 * (1.f / 32.f) - m * m + 1e-5f);
  }
  __syncthreads();
  out[bn * 384 + tid] = (v - stat[t]) * stat[12 + t] * gf[c] + bf[c];
}

// ---------------- launch ----------------
extern "C" void kernel_launch(void* const* d_in, const int* in_sizes, int n_in,
                              void* d_out, int out_size, void* d_ws, size_t ws_size,
                              hipStream_t stream) {
  const float* x       = (const float*)d_in[0];
  const float* res_att = (const float*)d_in[1];
  const float* posT    = (const float*)d_in[2];
  const float* gT      = (const float*)d_in[3];
  const float* bT      = (const float*)d_in[4];
  const float* WQt     = (const float*)d_in[5];
  const float* WKt     = (const float*)d_in[6];
  const float* WVt     = (const float*)d_in[7];
  const float* fct     = (const float*)d_in[8];
  const float* pcw     = (const float*)d_in[9];
  const float* pcb     = (const float*)d_in[10];
  const float* posS    = (const float*)d_in[11];
  const float* gS      = (const float*)d_in[12];
  const float* bS      = (const float*)d_in[13];
  const float* WQs     = (const float*)d_in[14];
  const float* WKs     = (const float*)d_in[15];
  const float* cheb    = (const float*)d_in[16];
  const float* adj     = (const float*)d_in[17];
  const float* mask    = (const float*)d_in[18];
  const float* Theta   = (const float*)d_in[19];
  const float* w3      = (const float*)d_in[20];
  const float* b3      = (const float*)d_in[21];
  const float* w5      = (const float*)d_in[22];
  const float* b5      = (const float*)d_in[23];
  const float* w7      = (const float*)d_in[24];
  const float* b7      = (const float*)d_in[25];
  const float* rw      = (const float*)d_in[26];
  const float* rb      = (const float*)d_in[27];
  const float* fw      = (const float*)d_in[28];
  const float* fb      = (const float*)d_in[29];
  const float* gf      = (const float*)d_in[30];
  const float* bf      = (const float*)d_in[31];

  float* ws = (float*)d_ws;
  float* TEmx = ws;                         // 196608
  float* qkv  = TEmx + 196608;              // 55296 (unused now)
  float* ctx  = qkv + 55296;                // 18432
  float* TAT  = ctx + 18432;                // 196608
  float* SEmx = TAT + 196608;               // 8388608 (reused: part pre-k4, pk during k6, X after)
  float* Qsf  = SEmx + 8388608;             // 1572864 slots (bf16 uses half)
  float* Ksf  = Qsf + 1572864;              // 1572864
  float* rhs  = Ksf + 1572864;              // 589824
  float* tco  = rhs + 589824;               // 6291456
  float* X    = SEmx;                       // overlay
  float* part = SEmx;                       // overlay: k2 partials (221184 floats), dead before k4

  __hip_bfloat16* Qh = (__hip_bfloat16*)Qsf;
  __hip_bfloat16* Kh = (__hip_bfloat16*)Ksf;
  float2* pk = (float2*)SEmx;

  float* out  = (float*)d_out;
  float* reAt = out + 6291456;

  k1_temporal_ln<<<B_ * T_, 256, 0, stream>>>(x, posT, gT, bT, TEmx);
  k2_qkv<<<dim3(4, B_ * T_), 256, 0, stream>>>(TEmx, WQt, WKt, WVt, part);
  k3a_attn<<<B_, 256, 0, stream>>>(part, res_att, reAt, ctx);
  k3b_tat<<<B_ * T_, 256, 0, stream>>>(ctx, fct, TEmx, TAT);
  k4_preconv_ln<<<B_ * N_, 256, 0, stream>>>(TAT, pcw, pcb, posS, gS, bS, SEmx);
  k5_qks<<<dim3(N_ / 32, B_), 256, 0, stream>>>(SEmx, WQs, WKs, Qh, Kh);
  k6_pre<<<(K_ * N_ * N_) / 256, 256, 0, stream>>>(adj, mask, cheb, pk);
  k6_spatial<<<dim3(N_ / 32, K_, B_), 256, 0, stream>>>(Qh, Kh, pk, x, rhs);
  k7_theta<<<(B_ * N_ * C_ * T_) / 256, 256, 0, stream>>>(rhs, Theta, X);
  k8_gtu<<<B_ * N_ / 32, 1024, 0, stream>>>(X, w3, b3, w5, b5, w7, b7, fw, fb, tco);
  k9_final<<<B_ * N_, 384, 0, stream>>>(x, rw, rb, tco, gf, bf, out);
}

// Round 7
// 613.379 us; speedup vs baseline: 2.7629x; 1.0674x over previous
//
#include <hip/hip_runtime.h>
#include <hip/hip_bf16.h>
#include <math.h>

#define B_ 16
#define N_ 1024
#define T_ 12
#define DM_ 512
#define H_ 3
#define K_ 3
#define C_ 32
#define RSQRT_DK 0.17677669529663687f

typedef __attribute__((ext_vector_type(8))) short bf16x8;
typedef __attribute__((ext_vector_type(4))) float f32x4;

__device__ __forceinline__ ushort f2bf(float f) {   // RNE float->bf16 bits
  uint u = __float_as_uint(f);
  return (ushort)((u + 0x7FFF + ((u >> 16) & 1)) >> 16);
}

// ---------------- K1: temporal embedding LayerNorm over N ----------------
__global__ void k1_temporal_ln(const float* __restrict__ x, const float* __restrict__ posT,
                               const float* __restrict__ gT, const float* __restrict__ bT,
                               float* __restrict__ TEmx) {
  int row = blockIdx.x;                 // b*T + t
  int b = row / T_, t = row - b * T_;
  __shared__ float red[256], red2[256];
  float v[4]; float s = 0.f, s2 = 0.f;
  for (int i = 0; i < 4; ++i) {
    int n = threadIdx.x + (i << 8);
    float val = x[(b * N_ + n) * T_ + t] + posT[t * N_ + n];
    v[i] = val; s += val; s2 += val * val;
  }
  red[threadIdx.x] = s; red2[threadIdx.x] = s2;
  __syncthreads();
  for (int off = 128; off > 0; off >>= 1) {
    if (threadIdx.x < off) { red[threadIdx.x] += red[threadIdx.x + off]; red2[threadIdx.x] += red2[threadIdx.x + off]; }
    __syncthreads();
  }
  float mu = red[0] * (1.f / N_);
  float rs = rsqrtf(red2[0] * (1.f / N_) - mu * mu + 1e-5f);
  for (int i = 0; i < 4; ++i) {
    int n = threadIdx.x + (i << 8);
    TEmx[row * N_ + n] = (v[i] - mu) * rs * gT[n] + bT[n];
  }
}

// ---------------- K2 v2: temporal Q/K/V projections, K-split x4 ----------------
__global__ __launch_bounds__(256) void k2_qkv(const float* __restrict__ TEmx,
                       const float* __restrict__ WQ, const float* __restrict__ WK,
                       const float* __restrict__ WV, float* __restrict__ part) {
  int kc = blockIdx.x, row = blockIdx.y;
  __shared__ float e[256];
  int tid = threadIdx.x;
  e[tid] = TEmx[row * N_ + kc * 256 + tid];
  __syncthreads();
  for (int col = tid; col < 288; col += 256) {
    int which = col / 96, j = col - which * 96;
    const float* W = (which == 0) ? WQ : ((which == 1) ? WK : WV);
    const float* Wp = W + (size_t)(kc * 256) * 96 + j;
    float acc = 0.f;
    #pragma unroll 8
    for (int n = 0; n < 256; ++n) acc += e[n] * Wp[n * 96];
    part[(row * 4 + kc) * 288 + col] = acc;
  }
}

// ---------------- K3a: temporal attention (sums k2 partials during staging) ----------------
__global__ void k3a_attn(const float* __restrict__ part, const float* __restrict__ res_att,
                         float* __restrict__ reAt_out, float* __restrict__ ctx) {
  int b = blockIdx.x;
  __shared__ float q_l[T_ * 288];
  __shared__ float s_l[H_ * T_ * T_];
  for (int i = threadIdx.x; i < T_ * 288; i += 256) {
    int t = i / 288, col = i - t * 288;
    const float* pr = &part[(size_t)((b * T_ + t) * 4) * 288 + col];
    q_l[i] = pr[0] + pr[288] + pr[576] + pr[864];
  }
  __syncthreads();
  for (int idx = threadIdx.x; idx < H_ * T_ * T_; idx += 256) {
    int h = idx / 144, r = idx - h * 144, qi = r / 12, ki = r - qi * 12;
    float acc = 0.f;
    #pragma unroll
    for (int d = 0; d < 32; ++d)
      acc += q_l[qi * 288 + h * 32 + d] * q_l[ki * 288 + 96 + h * 32 + d];
    float sv = acc * RSQRT_DK + res_att[(b * H_ + h) * 144 + qi * 12 + ki];
    s_l[idx] = sv;
    reAt_out[(b * H_ + h) * 144 + qi * 12 + ki] = sv;
  }
  __syncthreads();
  if (threadIdx.x < 36) {
    int h = threadIdx.x / 12, qi = threadIdx.x - h * 12;
    float mx = -1e30f;
    for (int ki = 0; ki < 12; ++ki) mx = fmaxf(mx, s_l[h * 144 + qi * 12 + ki]);
    float sum = 0.f;
    for (int ki = 0; ki < 12; ++ki) { float p = __expf(s_l[h * 144 + qi * 12 + ki] - mx); s_l[h * 144 + qi * 12 + ki] = p; sum += p; }
    float inv = 1.f / sum;
    for (int ki = 0; ki < 12; ++ki) s_l[h * 144 + qi * 12 + ki] *= inv;
  }
  __syncthreads();
  for (int idx = threadIdx.x; idx < T_ * 96; idx += 256) {
    int qi = idx / 96, hd = idx - qi * 96, h = hd >> 5, d = hd & 31;
    float acc = 0.f;
    for (int ki = 0; ki < 12; ++ki)
      acc += s_l[h * 144 + qi * 12 + ki] * q_l[ki * 288 + 192 + h * 32 + d];
    ctx[(b * T_ + qi) * 96 + hd] = acc;
  }
}

// ---------------- K3b: ctx @ fc_t + TEmx, LayerNorm ----------------
__global__ void k3b_tat(const float* __restrict__ ctx, const float* __restrict__ fc_t,
                        const float* __restrict__ TEmx, float* __restrict__ TAT) {
  int row = blockIdx.x;
  __shared__ float c_l[96];
  __shared__ float red[256], red2[256];
  if (threadIdx.x < 96) c_l[threadIdx.x] = ctx[row * 96 + threadIdx.x];
  __syncthreads();
  float v[4]; float s = 0.f, s2 = 0.f;
  for (int i = 0; i < 4; ++i) {
    int n = threadIdx.x + (i << 8);
    float acc = TEmx[row * N_ + n];
    for (int j = 0; j < 96; ++j) acc += c_l[j] * fc_t[j * N_ + n];
    v[i] = acc; s += acc; s2 += acc * acc;
  }
  red[threadIdx.x] = s; red2[threadIdx.x] = s2;
  __syncthreads();
  for (int off = 128; off > 0; off >>= 1) {
    if (threadIdx.x < off) { red[threadIdx.x] += red[threadIdx.x + off]; red2[threadIdx.x] += red2[threadIdx.x + off]; }
    __syncthreads();
  }
  float mu = red[0] * (1.f / N_);
  float rs = rsqrtf(red2[0] * (1.f / N_) - mu * mu + 1e-5f);
  for (int i = 0; i < 4; ++i) {
    int n = threadIdx.x + (i << 8);
    TAT[row * N_ + n] = (v[i] - mu) * rs;
  }
}

// ---------------- K4: pre_conv + pos_embed_S + LayerNorm over 512 ----------------
__global__ void k4_preconv_ln(const float* __restrict__ TAT, const float* __restrict__ pcw,
                              const float* __restrict__ pcb, const float* __restrict__ posS,
                              const float* __restrict__ gS, const float* __restrict__ bS,
                              float* __restrict__ SEmx) {
  int bn = blockIdx.x; int b = bn >> 10, n = bn & 1023;
  __shared__ float tc[12];
  __shared__ float red[256], red2[256];
  if (threadIdx.x < 12) tc[threadIdx.x] = TAT[(b * T_ + threadIdx.x) * N_ + n];
  __syncthreads();
  float v[2]; float s = 0.f, s2 = 0.f;
  for (int i = 0; i < 2; ++i) {
    int d = threadIdx.x + (i << 8);
    float acc = pcb[d];
    #pragma unroll
    for (int t = 0; t < 12; ++t) acc += tc[t] * pcw[d * 12 + t];
    acc += posS[n * DM_ + d];
    v[i] = acc; s += acc; s2 += acc * acc;
  }
  red[threadIdx.x] = s; red2[threadIdx.x] = s2;
  __syncthreads();
  for (int off = 128; off > 0; off >>= 1) {
    if (threadIdx.x < off) { red[threadIdx.x] += red[threadIdx.x + off]; red2[threadIdx.x] += red2[threadIdx.x + off]; }
    __syncthreads();
  }
  float mu = red[0] * (1.f / DM_);
  float rs = rsqrtf(red2[0] * (1.f / DM_) - mu * mu + 1e-5f);
  for (int i = 0; i < 2; ++i) {
    int d = threadIdx.x + (i << 8);
    SEmx[bn * DM_ + d] = (v[i] - mu) * rs * gS[d] + bS[d];
  }
}

// ---------------- K5 v4: spatial Q/K GEMM, 32-row tiles ----------------
__global__ __launch_bounds__(256) void k5_qks(const float* __restrict__ SEmx,
                                              const float* __restrict__ WQs,
                                              const float* __restrict__ WKs,
                                              __hip_bfloat16* __restrict__ Qs,
                                              __hip_bfloat16* __restrict__ Ks) {
  int b = blockIdx.y, n0 = blockIdx.x * 32;
  __shared__ float SE_l[32 * 65];
  __shared__ float W_l[64 * 196];
  int tid = threadIdx.x;
  int ng = tid >> 4, cg = tid & 15;
  int ng2 = ng * 2, col0 = cg * 12;
  float acc[2][12];
  #pragma unroll
  for (int i = 0; i < 2; ++i)
    #pragma unroll
    for (int j = 0; j < 12; ++j) acc[i][j] = 0.f;

  for (int dc = 0; dc < DM_; dc += 64) {
    for (int idx = tid; idx < 32 * 64; idx += 256) {
      int i = idx >> 6, j = idx & 63;
      SE_l[i * 65 + j] = SEmx[((b << 10) + n0 + i) * DM_ + dc + j];
    }
    for (int idx = tid; idx < 64 * 192; idx += 256) {
      int d = idx / 192, c = idx - d * 192;
      float v = (c < 96) ? WQs[(dc + d) * 96 + c] : WKs[(dc + d) * 96 + (c - 96)];
      W_l[d * 196 + c] = v;
    }
    __syncthreads();
    #pragma unroll 4
    for (int d = 0; d < 64; ++d) {
      float se[2];
      #pragma unroll
      for (int i = 0; i < 2; ++i) se[i] = SE_l[(ng2 + i) * 65 + d];
      const float4* wp = (const float4*)&W_l[d * 196 + col0];
      float4 w0 = wp[0], w1 = wp[1], w2 = wp[2];
      float wv[12] = {w0.x, w0.y, w0.z, w0.w, w1.x, w1.y, w1.z, w1.w, w2.x, w2.y, w2.z, w2.w};
      #pragma unroll
      for (int i = 0; i < 2; ++i)
        #pragma unroll
        for (int j = 0; j < 12; ++j)
          acc[i][j] = fmaf(se[i], wv[j], acc[i][j]);
    }
    __syncthreads();
  }
  #pragma unroll
  for (int i = 0; i < 2; ++i) {
    int n = n0 + ng2 + i;
    #pragma unroll
    for (int jj = 0; jj < 12; ++jj) {
      int col = col0 + jj;
      int j = (col < 96) ? col : col - 96;
      int k = j >> 5, dd = j & 31;
      __hip_bfloat16* o = (col < 96) ? Qs : Ks;
      o[(((b * K_ + k) * N_) + n) * 32 + dd] = __float2bfloat16(acc[i][jj]);
    }
  }
}

// ---------------- K6pre v2: pack {adj*mask, cheb} as 2xbf16 in uint ----------------
__global__ void k6_pre(const float* __restrict__ adj, const float* __restrict__ mask,
                       const float* __restrict__ cheb, uint* __restrict__ pk) {
  int idx = blockIdx.x * 256 + threadIdx.x;     // over 3*1024*1024
  int mn = idx & (N_ * N_ - 1);
  uint lo = f2bf(adj[mn] * mask[idx]);
  uint hi = f2bf(cheb[idx]);
  pk[idx] = lo | (hi << 16);
}

// ---------------- K6 v4: MFMA scores + online softmax; packed pk; b-major grid ----------------
__global__ __launch_bounds__(256) void k6_spatial(
    const __hip_bfloat16* __restrict__ Qs, const __hip_bfloat16* __restrict__ Ks,
    const uint* __restrict__ pk, const float* __restrict__ x,
    float* __restrict__ rhs) {
  const int b  = blockIdx.x;
  const int k  = blockIdx.y;
  const int n0 = blockIdx.z * 32;
  const ushort* Qb = (const ushort*)(Qs + (size_t)((b * K_ + k) * N_) * 32);
  const ushort* Kb = (const ushort*)(Ks + (size_t)((b * K_ + k) * N_) * 32);
  const uint* pkk = pk + (size_t)k * (N_ * N_);
  const float*  xb  = x + b * N_ * T_;

  __shared__ __align__(16) ushort Q_lh[64 * 32];
  __shared__ __align__(16) ushort K_lh[32 * 32];
  __shared__ __align__(16) float  x_l[64 * 12];
  __shared__ float s_l[64 * 36];
  __shared__ float pm[4 * 32], ps[4 * 32];
  __shared__ float mu[32], ell[32], fac[32], inv[32];
  __shared__ float red[8 * 32 * 12];

  const int tid  = threadIdx.x;
  const int w    = tid >> 6, lane = tid & 63;
  const int quad = lane >> 4, c16 = lane & 15;
  const int mg   = tid >> 5, nn = tid & 31;

  if (tid < 128) *(uint4*)(&K_lh[tid * 8]) = *(const uint4*)(Kb + (size_t)n0 * 32 + tid * 8);
  if (tid < 32) { mu[tid] = -1e30f; ell[tid] = 0.f; }
  float accp[12];
  #pragma unroll
  for (int t = 0; t < 12; ++t) accp[t] = 0.f;
  __syncthreads();

  for (int m0 = 0; m0 < N_; m0 += 64) {
    *(uint4*)(&Q_lh[tid * 8]) = *(const uint4*)(Qb + (size_t)m0 * 32 + tid * 8);
    if (tid < 192) *(float4*)(&x_l[tid * 4]) = *(const float4*)(xb + m0 * 12 + tid * 4);
    __syncthreads();

    bf16x8 afrag = *(const bf16x8*)(&Q_lh[(w * 16 + c16) * 32 + quad * 8]);
    f32x4 sc[2];
    float am[2][4], ch[2][4];
    #pragma unroll
    for (int ns = 0; ns < 2; ++ns) {
      bf16x8 bfrag = *(const bf16x8*)(&K_lh[(ns * 16 + c16) * 32 + quad * 8]);
      f32x4 z = {0.f, 0.f, 0.f, 0.f};
      sc[ns] = __builtin_amdgcn_mfma_f32_16x16x32_bf16(afrag, bfrag, z, 0, 0, 0);
      #pragma unroll
      for (int r = 0; r < 4; ++r) {
        int m = m0 + w * 16 + quad * 4 + r;
        uint p2 = pkk[(size_t)m * N_ + n0 + ns * 16 + c16];
        am[ns][r] = __uint_as_float(p2 << 16);
        ch[ns][r] = __uint_as_float(p2 & 0xFFFF0000u);
      }
    }
    float sv[2][4];
    #pragma unroll
    for (int ns = 0; ns < 2; ++ns) {
      float cmax = -1e30f;
      #pragma unroll
      for (int r = 0; r < 4; ++r) {
        sv[ns][r] = sc[ns][r] * RSQRT_DK + am[ns][r];
        cmax = fmaxf(cmax, sv[ns][r]);
      }
      cmax = fmaxf(cmax, __shfl_xor(cmax, 16));
      cmax = fmaxf(cmax, __shfl_xor(cmax, 32));
      if (lane < 16) pm[w * 32 + ns * 16 + lane] = cmax;
    }
    __syncthreads();
    if (tid < 32) {
      float tm = fmaxf(fmaxf(pm[tid], pm[32 + tid]), fmaxf(pm[64 + tid], pm[96 + tid]));
      float nm = fmaxf(mu[tid], tm);
      fac[tid] = __expf(mu[tid] - nm);
      mu[tid] = nm;
    }
    __syncthreads();
    {
      float f = fac[nn];
      #pragma unroll
      for (int t = 0; t < 12; ++t) accp[t] *= f;
    }
    #pragma unroll
    for (int ns = 0; ns < 2; ++ns) {
      float mcol = mu[ns * 16 + c16];
      float psum = 0.f;
      #pragma unroll
      for (int r = 0; r < 4; ++r) {
        float p = __expf(sv[ns][r] - mcol);
        psum += p;
        s_l[(w * 16 + quad * 4 + r) * 36 + ns * 16 + c16] = p * ch[ns][r];
      }
      psum += __shfl_xor(psum, 16);
      psum += __shfl_xor(psum, 32);
      if (lane < 16) ps[w * 32 + ns * 16 + lane] = psum;
    }
    __syncthreads();
    if (tid < 32)
      ell[tid] = ell[tid] * fac[tid] + ps[tid] + ps[32 + tid] + ps[64 + tid] + ps[96 + tid];
    #pragma unroll
    for (int mi = 0; mi < 8; ++mi) {
      int m = mg * 8 + mi;
      float pv = s_l[m * 36 + nn];
      const float* xr = &x_l[m * 12];
      #pragma unroll
      for (int t = 0; t < 12; ++t) accp[t] = fmaf(pv, xr[t], accp[t]);
    }
    __syncthreads();
  }
  if (tid < 32) inv[tid] = 1.f / ell[tid];
  #pragma unroll
  for (int t = 0; t < 12; ++t) red[(mg * 32 + nn) * 12 + t] = accp[t];
  __syncthreads();
  for (int idx = tid; idx < 384; idx += 256) {
    int n = idx / 12, t = idx - n * 12;
    float s = 0.f;
    #pragma unroll
    for (int g = 0; g < 8; ++g) s += red[(g * 32 + n) * 12 + t];
    rhs[((size_t)(b * K_ + k) * N_ + n0 + n) * 12 + t] = s * inv[n];
  }
}

// ---------------- K8 fused: Theta+relu -> GTU convs -> fcmy -> residual+LN -> out ----------------
template<int KS, int J, int JB, int WSTRIDE>
__device__ __forceinline__ void conv_phase(const float* X_s, const float* w_c,
                                           float ya[24], float yb[24]) {
  #pragma unroll 2
  for (int ic = 0; ic < 32; ++ic) {
    const float4* xp = (const float4*)(X_s + ic * 12);
    float4 a0 = xp[0], a1 = xp[1], a2 = xp[2];
    float xr[12] = {a0.x, a0.y, a0.z, a0.w, a1.x, a1.y, a1.z, a1.w, a2.x, a2.y, a2.z, a2.w};
    #pragma unroll
    for (int dt = 0; dt < KS; ++dt) {
      float2 w = *(const float2*)(w_c + (ic * KS + dt) * 2);
      #pragma unroll
      for (int j = 0; j < J; ++j) {
        ya[JB + j] = fmaf(xr[j + dt], w.x, ya[JB + j]);
        yb[JB + j] = fmaf(xr[j + dt], w.y, yb[JB + j]);
      }
    }
  }
}

__global__ __launch_bounds__(1024) void k8_fused(
                       const float* __restrict__ rhs, const float* __restrict__ Theta,
                       const float* __restrict__ x, const float* __restrict__ rw,
                       const float* __restrict__ rb,
                       const float* __restrict__ w3, const float* __restrict__ b3,
                       const float* __restrict__ w5, const float* __restrict__ b5,
                       const float* __restrict__ w7, const float* __restrict__ b7,
                       const float* __restrict__ fw, const float* __restrict__ fb,
                       const float* __restrict__ gf, const float* __restrict__ bf,
                       float* __restrict__ out) {
  int bn0 = blockIdx.x * 32;
  int b = bn0 >> 10, n0 = bn0 & 1023;
  __shared__ float X_l[32 * 388];         // 49.7 KB; reused for v in epilogue
  __shared__ float wl[14400];             // 57.6 KB, strides 194/322/450
  __shared__ float fw_l[288];
  __shared__ float fb_l[12];
  __shared__ float bias_l[3][64];
  __shared__ float rhs_l[32 * 36];        // [site][k*12+t]
  __shared__ float Th_l[96];
  __shared__ float xr_l[32 * 12];
  __shared__ float rw_l[32], rb_l[32], gf_l[32], bf_l[32];
  __shared__ float stm[384], str[384];    // per (site,t) mean / rsqrt
  int tid = threadIdx.x;
  int c = (tid >> 3) & 31;
  int site = (tid & 7) | ((tid >> 8) << 3);
  const float* X_s = &X_l[site * 388];

  // ---- stage everything global ----
  for (int idx = tid; idx < 1152; idx += 1024) {
    int s = idx / 36, r = idx - s * 36;
    int k = r / 12, t = r - k * 12;
    rhs_l[idx] = rhs[((size_t)(b * 3 + k) * N_ + n0 + s) * 12 + t];
  }
  if (tid < 384) xr_l[tid] = x[(size_t)(b * N_ + n0) * 12 + tid];
  if (tid < 96) Th_l[tid] = Theta[tid];
  if (tid < 288) fw_l[tid] = fw[tid];
  if (tid < 12) fb_l[tid] = fb[tid];
  if (tid < 64) { bias_l[0][tid] = b3[tid]; bias_l[1][tid] = b5[tid]; bias_l[2][tid] = b7[tid]; }
  if (tid >= 64 && tid < 96)  rw_l[tid - 64] = rw[tid - 64];
  if (tid >= 96 && tid < 128) rb_l[tid - 96] = rb[tid - 96];
  if (tid >= 128 && tid < 160) gf_l[tid - 128] = gf[tid - 128];
  if (tid >= 160 && tid < 192) bf_l[tid - 160] = bf[tid - 160];
  for (int idx = tid; idx < 6144; idx += 1024) {
    int co = idx / 96, r = idx - co * 96;
    wl[(co & 31) * 194 + r * 2 + (co >> 5)] = w3[idx];
  }
  __syncthreads();

  // ---- prologue: X[c][t] = relu(sum_k rhs[k][t]*Theta[k][c]) ----
  {
    float th0 = Th_l[c], th1 = Th_l[32 + c], th2 = Th_l[64 + c];
    const float* rs_ = &rhs_l[site * 36];
    float* xo = &X_l[site * 388 + c * 12];
    #pragma unroll
    for (int t = 0; t < 12; ++t) {
      float a = rs_[t] * th0 + rs_[12 + t] * th1 + rs_[24 + t] * th2;
      xo[t] = fmaxf(a, 0.f);
    }
  }
  __syncthreads();

  float ya[24], yb[24];
  #pragma unroll
  for (int j = 0; j < 24; ++j) { ya[j] = 0.f; yb[j] = 0.f; }
  conv_phase<3, 10, 0, 194>(X_s, &wl[c * 194], ya, yb);
  __syncthreads();
  for (int idx = tid; idx < 10240; idx += 1024) {
    int co = idx / 160, r = idx - co * 160;
    wl[(co & 31) * 322 + r * 2 + (co >> 5)] = w5[idx];
  }
  __syncthreads();
  conv_phase<5, 8, 10, 322>(X_s, &wl[c * 322], ya, yb);
  __syncthreads();
  for (int idx = tid; idx < 14336; idx += 1024) {
    int co = idx / 224, r = idx - co * 224;
    wl[(co & 31) * 450 + r * 2 + (co >> 5)] = w7[idx];
  }
  __syncthreads();
  conv_phase<7, 6, 18, 450>(X_s, &wl[c * 450], ya, yb);

  // ---- gate + fcmy (registers) ----
  float tc[24];
  #pragma unroll
  for (int j = 0; j < 24; ++j) {
    int cv = (j < 10) ? 0 : ((j < 18) ? 1 : 2);
    float a = ya[j] + bias_l[cv][c];
    float g = yb[j] + bias_l[cv][c + 32];
    float e2a = __expf(2.f * a);
    float th = 1.f - 2.f / (e2a + 1.f);
    float sg = 1.f / (1.f + __expf(-g));
    tc[j] = th * sg;
  }
  float o[12];
  #pragma unroll
  for (int t = 0; t < 12; ++t) o[t] = fb_l[t];
  #pragma unroll
  for (int j = 0; j < 24; ++j) {
    const float4* fp = (const float4*)&fw_l[j * 12];
    float4 f0 = fp[0], f1 = fp[1], f2 = fp[2];
    float fr[12] = {f0.x, f0.y, f0.z, f0.w, f1.x, f1.y, f1.z, f1.w, f2.x, f2.y, f2.z, f2.w};
    #pragma unroll
    for (int t = 0; t < 12; ++t) o[t] = fmaf(tc[j], fr[t], o[t]);
  }

  // ---- epilogue: v = relu(x_res + relu(o)); LN over c per (site,t) ----
  __syncthreads();                         // all conv reads of X_l done
  float v[12];
  {
    float rwc = rw_l[c], rbc = rb_l[c];
    const float* xs = &xr_l[site * 12];
    float* xo = &X_l[site * 388 + c * 12];
    #pragma unroll
    for (int t = 0; t < 12; ++t) {
      float xres = xs[t] * rwc + rbc;
      v[t] = fmaxf(xres + fmaxf(o[t], 0.f), 0.f);
      xo[t] = v[t];
    }
  }
  __syncthreads();
  if (tid < 384) {
    int s = tid / 12, t = tid - s * 12;
    float sm = 0.f, s2 = 0.f;
    #pragma unroll 8
    for (int cc = 0; cc < 32; ++cc) {
      float u = X_l[s * 388 + cc * 12 + t];
      sm += u; s2 += u * u;
    }
    float m = sm * (1.f / 32.f);
    stm[tid] = m;
    str[tid] = rsqrtf(s2 * (1.f / 32.f) - m * m + 1e-5f);
  }
  __syncthreads();
  {
    float gfc = gf_l[c], bfc = bf_l[c];
    const float* sm_ = &stm[site * 12];
    const float* sr_ = &str[site * 12];
    float q[12];
    #pragma unroll
    for (int t = 0; t < 12; ++t) q[t] = (v[t] - sm_[t]) * sr_[t] * gfc + bfc;
    float* op = &out[(size_t)(bn0 + site) * 384 + c * 12];
    ((float4*)op)[0] = make_float4(q[0], q[1], q[2], q[3]);
    ((float4*)op)[1] = make_float4(q[4], q[5], q[6], q[7]);
    ((float4*)op)[2] = make_float4(q[8], q[9], q[10], q[11]);
  }
}

// ---------------- launch ----------------
extern "C" void kernel_launch(void* const* d_in, const int* in_sizes, int n_in,
                              void* d_out, int out_size, void* d_ws, size_t ws_size,
                              hipStream_t stream) {
  const float* x       = (const float*)d_in[0];
  const float* res_att = (const float*)d_in[1];
  const float* posT    = (const float*)d_in[2];
  const float* gT      = (const float*)d_in[3];
  const float* bT      = (const float*)d_in[4];
  const float* WQt     = (const float*)d_in[5];
  const float* WKt     = (const float*)d_in[6];
  const float* WVt     = (const float*)d_in[7];
  const float* fct     = (const float*)d_in[8];
  const float* pcw     = (const float*)d_in[9];
  const float* pcb     = (const float*)d_in[10];
  const float* posS    = (const float*)d_in[11];
  const float* gS      = (const float*)d_in[12];
  const float* bS      = (const float*)d_in[13];
  const float* WQs     = (const float*)d_in[14];
  const float* WKs     = (const float*)d_in[15];
  const float* cheb    = (const float*)d_in[16];
  const float* adj     = (const float*)d_in[17];
  const float* mask    = (const float*)d_in[18];
  const float* Theta   = (const float*)d_in[19];
  const float* w3      = (const float*)d_in[20];
  const float* b3      = (const float*)d_in[21];
  const float* w5      = (const float*)d_in[22];
  const float* b5      = (const float*)d_in[23];
  const float* w7      = (const float*)d_in[24];
  const float* b7      = (const float*)d_in[25];
  const float* rw      = (const float*)d_in[26];
  const float* rb      = (const float*)d_in[27];
  const float* fw      = (const float*)d_in[28];
  const float* fb      = (const float*)d_in[29];
  const float* gf      = (const float*)d_in[30];
  const float* bf      = (const float*)d_in[31];

  float* ws = (float*)d_ws;
  float* TEmx = ws;                         // 196608
  float* qkv  = TEmx + 196608;              // 55296 (unused)
  float* ctx  = qkv + 55296;                // 18432
  float* TAT  = ctx + 18432;                // 196608
  float* SEmx = TAT + 196608;               // 8388608 (reused: part pre-k4, pk during k6)
  float* Qsf  = SEmx + 8388608;             // 1572864 slots (bf16 uses half)
  float* Ksf  = Qsf + 1572864;              // 1572864
  float* rhs  = Ksf + 1572864;              // 589824
  float* part = SEmx;                       // overlay: k2 partials, dead before k4

  __hip_bfloat16* Qh = (__hip_bfloat16*)Qsf;
  __hip_bfloat16* Kh = (__hip_bfloat16*)Ksf;
  uint* pk = (uint*)SEmx;                   // 3M uints = 12 MB, dead after k6

  float* out  = (float*)d_out;
  float* reAt = out + 6291456;

  k1_temporal_ln<<<B_ * T_, 256, 0, stream>>>(x, posT, gT, bT, TEmx);
  k2_qkv<<<dim3(4, B_ * T_), 256, 0, stream>>>(TEmx, WQt, WKt, WVt, part);
  k3a_attn<<<B_, 256, 0, stream>>>(part, res_att, reAt, ctx);
  k3b_tat<<<B_ * T_, 256, 0, stream>>>(ctx, fct, TEmx, TAT);
  k4_preconv_ln<<<B_ * N_, 256, 0, stream>>>(TAT, pcw, pcb, posS, gS, bS, SEmx);
  k5_qks<<<dim3(N_ / 32, B_), 256, 0, stream>>>(SEmx, WQs, WKs, Qh, Kh);
  k6_pre<<<(K_ * N_ * N_) / 256, 256, 0, stream>>>(adj, mask, cheb, pk);
  k6_spatial<<<dim3(B_, K_, N_ / 32), 256, 0, stream>>>(Qh, Kh, pk, x, rhs);
  k8_fused<<<B_ * N_ / 32, 1024, 0, stream>>>(rhs, Theta, x, rw, rb,
                                              w3, b3, w5, b5, w7, b7, fw, fb, gf, bf, out);
}

// Round 8
// 513.558 us; speedup vs baseline: 3.2999x; 1.1944x over previous
//
#include <hip/hip_runtime.h>
#include <hip/hip_bf16.h>
#include <math.h>

#define B_ 16
#define N_ 1024
#define T_ 12
#define DM_ 512
#define H_ 3
#define K_ 3
#define C_ 32
#define RSQRT_DK 0.17677669529663687f

typedef __attribute__((ext_vector_type(8))) short bf16x8;
typedef __attribute__((ext_vector_type(4))) float f32x4;

__device__ __forceinline__ ushort f2bf(float f) {   // RNE float->bf16 bits
  uint u = __float_as_uint(f);
  return (ushort)((u + 0x7FFF + ((u >> 16) & 1)) >> 16);
}

// ---------------- K1: temporal embedding LayerNorm over N ----------------
__global__ void k1_temporal_ln(const float* __restrict__ x, const float* __restrict__ posT,
                               const float* __restrict__ gT, const float* __restrict__ bT,
                               float* __restrict__ TEmx) {
  int row = blockIdx.x;                 // b*T + t
  int b = row / T_, t = row - b * T_;
  __shared__ float red[256], red2[256];
  float v[4]; float s = 0.f, s2 = 0.f;
  for (int i = 0; i < 4; ++i) {
    int n = threadIdx.x + (i << 8);
    float val = x[(b * N_ + n) * T_ + t] + posT[t * N_ + n];
    v[i] = val; s += val; s2 += val * val;
  }
  red[threadIdx.x] = s; red2[threadIdx.x] = s2;
  __syncthreads();
  for (int off = 128; off > 0; off >>= 1) {
    if (threadIdx.x < off) { red[threadIdx.x] += red[threadIdx.x + off]; red2[threadIdx.x] += red2[threadIdx.x + off]; }
    __syncthreads();
  }
  float mu = red[0] * (1.f / N_);
  float rs = rsqrtf(red2[0] * (1.f / N_) - mu * mu + 1e-5f);
  for (int i = 0; i < 4; ++i) {
    int n = threadIdx.x + (i << 8);
    TEmx[row * N_ + n] = (v[i] - mu) * rs * gT[n] + bT[n];
  }
}

// ---------------- K2 v2: temporal Q/K/V projections, K-split x4 ----------------
__global__ __launch_bounds__(256) void k2_qkv(const float* __restrict__ TEmx,
                       const float* __restrict__ WQ, const float* __restrict__ WK,
                       const float* __restrict__ WV, float* __restrict__ part) {
  int kc = blockIdx.x, row = blockIdx.y;
  __shared__ float e[256];
  int tid = threadIdx.x;
  e[tid] = TEmx[row * N_ + kc * 256 + tid];
  __syncthreads();
  for (int col = tid; col < 288; col += 256) {
    int which = col / 96, j = col - which * 96;
    const float* W = (which == 0) ? WQ : ((which == 1) ? WK : WV);
    const float* Wp = W + (size_t)(kc * 256) * 96 + j;
    float acc = 0.f;
    #pragma unroll 8
    for (int n = 0; n < 256; ++n) acc += e[n] * Wp[n * 96];
    part[(row * 4 + kc) * 288 + col] = acc;
  }
}

// ---------------- K3a: temporal attention (sums k2 partials during staging) ----------------
__global__ void k3a_attn(const float* __restrict__ part, const float* __restrict__ res_att,
                         float* __restrict__ reAt_out, float* __restrict__ ctx) {
  int b = blockIdx.x;
  __shared__ float q_l[T_ * 288];
  __shared__ float s_l[H_ * T_ * T_];
  for (int i = threadIdx.x; i < T_ * 288; i += 256) {
    int t = i / 288, col = i - t * 288;
    const float* pr = &part[(size_t)((b * T_ + t) * 4) * 288 + col];
    q_l[i] = pr[0] + pr[288] + pr[576] + pr[864];
  }
  __syncthreads();
  for (int idx = threadIdx.x; idx < H_ * T_ * T_; idx += 256) {
    int h = idx / 144, r = idx - h * 144, qi = r / 12, ki = r - qi * 12;
    float acc = 0.f;
    #pragma unroll
    for (int d = 0; d < 32; ++d)
      acc += q_l[qi * 288 + h * 32 + d] * q_l[ki * 288 + 96 + h * 32 + d];
    float sv = acc * RSQRT_DK + res_att[(b * H_ + h) * 144 + qi * 12 + ki];
    s_l[idx] = sv;
    reAt_out[(b * H_ + h) * 144 + qi * 12 + ki] = sv;
  }
  __syncthreads();
  if (threadIdx.x < 36) {
    int h = threadIdx.x / 12, qi = threadIdx.x - h * 12;
    float mx = -1e30f;
    for (int ki = 0; ki < 12; ++ki) mx = fmaxf(mx, s_l[h * 144 + qi * 12 + ki]);
    float sum = 0.f;
    for (int ki = 0; ki < 12; ++ki) { float p = __expf(s_l[h * 144 + qi * 12 + ki] - mx); s_l[h * 144 + qi * 12 + ki] = p; sum += p; }
    float inv = 1.f / sum;
    for (int ki = 0; ki < 12; ++ki) s_l[h * 144 + qi * 12 + ki] *= inv;
  }
  __syncthreads();
  for (int idx = threadIdx.x; idx < T_ * 96; idx += 256) {
    int qi = idx / 96, hd = idx - qi * 96, h = hd >> 5, d = hd & 31;
    float acc = 0.f;
    for (int ki = 0; ki < 12; ++ki)
      acc += s_l[h * 144 + qi * 12 + ki] * q_l[ki * 288 + 192 + h * 32 + d];
    ctx[(b * T_ + qi) * 96 + hd] = acc;
  }
}

// ---------------- K3b: ctx @ fc_t + TEmx, LayerNorm ----------------
__global__ void k3b_tat(const float* __restrict__ ctx, const float* __restrict__ fc_t,
                        const float* __restrict__ TEmx, float* __restrict__ TAT) {
  int row = blockIdx.x;
  __shared__ float c_l[96];
  __shared__ float red[256], red2[256];
  if (threadIdx.x < 96) c_l[threadIdx.x] = ctx[row * 96 + threadIdx.x];
  __syncthreads();
  float v[4]; float s = 0.f, s2 = 0.f;
  for (int i = 0; i < 4; ++i) {
    int n = threadIdx.x + (i << 8);
    float acc = TEmx[row * N_ + n];
    for (int j = 0; j < 96; ++j) acc += c_l[j] * fc_t[j * N_ + n];
    v[i] = acc; s += acc; s2 += acc * acc;
  }
  red[threadIdx.x] = s; red2[threadIdx.x] = s2;
  __syncthreads();
  for (int off = 128; off > 0; off >>= 1) {
    if (threadIdx.x < off) { red[threadIdx.x] += red[threadIdx.x + off]; red2[threadIdx.x] += red2[threadIdx.x + off]; }
    __syncthreads();
  }
  float mu = red[0] * (1.f / N_);
  float rs = rsqrtf(red2[0] * (1.f / N_) - mu * mu + 1e-5f);
  for (int i = 0; i < 4; ++i) {
    int n = threadIdx.x + (i << 8);
    TAT[row * N_ + n] = (v[i] - mu) * rs;
  }
}

// ---------------- K4: pre_conv + pos_embed_S + LayerNorm over 512 ----------------
__global__ void k4_preconv_ln(const float* __restrict__ TAT, const float* __restrict__ pcw,
                              const float* __restrict__ pcb, const float* __restrict__ posS,
                              const float* __restrict__ gS, const float* __restrict__ bS,
                              float* __restrict__ SEmx) {
  int bn = blockIdx.x; int b = bn >> 10, n = bn & 1023;
  __shared__ float tc[12];
  __shared__ float red[256], red2[256];
  if (threadIdx.x < 12) tc[threadIdx.x] = TAT[(b * T_ + threadIdx.x) * N_ + n];
  __syncthreads();
  float v[2]; float s = 0.f, s2 = 0.f;
  for (int i = 0; i < 2; ++i) {
    int d = threadIdx.x + (i << 8);
    float acc = pcb[d];
    #pragma unroll
    for (int t = 0; t < 12; ++t) acc += tc[t] * pcw[d * 12 + t];
    acc += posS[n * DM_ + d];
    v[i] = acc; s += acc; s2 += acc * acc;
  }
  red[threadIdx.x] = s; red2[threadIdx.x] = s2;
  __syncthreads();
  for (int off = 128; off > 0; off >>= 1) {
    if (threadIdx.x < off) { red[threadIdx.x] += red[threadIdx.x + off]; red2[threadIdx.x] += red2[threadIdx.x + off]; }
    __syncthreads();
  }
  float mu = red[0] * (1.f / DM_);
  float rs = rsqrtf(red2[0] * (1.f / DM_) - mu * mu + 1e-5f);
  for (int i = 0; i < 2; ++i) {
    int d = threadIdx.x + (i << 8);
    SEmx[bn * DM_ + d] = (v[i] - mu) * rs * gS[d] + bS[d];
  }
}

// ---------------- K5 v4: spatial Q/K GEMM, 32-row tiles ----------------
__global__ __launch_bounds__(256) void k5_qks(const float* __restrict__ SEmx,
                                              const float* __restrict__ WQs,
                                              const float* __restrict__ WKs,
                                              __hip_bfloat16* __restrict__ Qs,
                                              __hip_bfloat16* __restrict__ Ks) {
  int b = blockIdx.y, n0 = blockIdx.x * 32;
  __shared__ float SE_l[32 * 65];
  __shared__ float W_l[64 * 196];
  int tid = threadIdx.x;
  int ng = tid >> 4, cg = tid & 15;
  int ng2 = ng * 2, col0 = cg * 12;
  float acc[2][12];
  #pragma unroll
  for (int i = 0; i < 2; ++i)
    #pragma unroll
    for (int j = 0; j < 12; ++j) acc[i][j] = 0.f;

  for (int dc = 0; dc < DM_; dc += 64) {
    for (int idx = tid; idx < 32 * 64; idx += 256) {
      int i = idx >> 6, j = idx & 63;
      SE_l[i * 65 + j] = SEmx[((b << 10) + n0 + i) * DM_ + dc + j];
    }
    for (int idx = tid; idx < 64 * 192; idx += 256) {
      int d = idx / 192, c = idx - d * 192;
      float v = (c < 96) ? WQs[(dc + d) * 96 + c] : WKs[(dc + d) * 96 + (c - 96)];
      W_l[d * 196 + c] = v;
    }
    __syncthreads();
    #pragma unroll 4
    for (int d = 0; d < 64; ++d) {
      float se[2];
      #pragma unroll
      for (int i = 0; i < 2; ++i) se[i] = SE_l[(ng2 + i) * 65 + d];
      const float4* wp = (const float4*)&W_l[d * 196 + col0];
      float4 w0 = wp[0], w1 = wp[1], w2 = wp[2];
      float wv[12] = {w0.x, w0.y, w0.z, w0.w, w1.x, w1.y, w1.z, w1.w, w2.x, w2.y, w2.z, w2.w};
      #pragma unroll
      for (int i = 0; i < 2; ++i)
        #pragma unroll
        for (int j = 0; j < 12; ++j)
          acc[i][j] = fmaf(se[i], wv[j], acc[i][j]);
    }
    __syncthreads();
  }
  #pragma unroll
  for (int i = 0; i < 2; ++i) {
    int n = n0 + ng2 + i;
    #pragma unroll
    for (int jj = 0; jj < 12; ++jj) {
      int col = col0 + jj;
      int j = (col < 96) ? col : col - 96;
      int k = j >> 5, dd = j & 31;
      __hip_bfloat16* o = (col < 96) ? Qs : Ks;
      o[(((b * K_ + k) * N_) + n) * 32 + dd] = __float2bfloat16(acc[i][jj]);
    }
  }
}

// ---------------- K6pre v2: pack {adj*mask, cheb} as 2xbf16 in uint ----------------
__global__ void k6_pre(const float* __restrict__ adj, const float* __restrict__ mask,
                       const float* __restrict__ cheb, uint* __restrict__ pk) {
  int idx = blockIdx.x * 256 + threadIdx.x;     // over 3*1024*1024
  int mn = idx & (N_ * N_ - 1);
  uint lo = f2bf(adj[mn] * mask[idx]);
  uint hi = f2bf(cheb[idx]);
  pk[idx] = lo | (hi << 16);
}

// ---------------- K6 v4: MFMA scores + online softmax; packed pk; b-major grid ----------------
__global__ __launch_bounds__(256) void k6_spatial(
    const __hip_bfloat16* __restrict__ Qs, const __hip_bfloat16* __restrict__ Ks,
    const uint* __restrict__ pk, const float* __restrict__ x,
    float* __restrict__ rhs) {
  const int b  = blockIdx.x;
  const int k  = blockIdx.y;
  const int n0 = blockIdx.z * 32;
  const ushort* Qb = (const ushort*)(Qs + (size_t)((b * K_ + k) * N_) * 32);
  const ushort* Kb = (const ushort*)(Ks + (size_t)((b * K_ + k) * N_) * 32);
  const uint* pkk = pk + (size_t)k * (N_ * N_);
  const float*  xb  = x + b * N_ * T_;

  __shared__ __align__(16) ushort Q_lh[64 * 32];
  __shared__ __align__(16) ushort K_lh[32 * 32];
  __shared__ __align__(16) float  x_l[64 * 12];
  __shared__ float s_l[64 * 36];
  __shared__ float pm[4 * 32], ps[4 * 32];
  __shared__ float mu[32], ell[32], fac[32], inv[32];
  __shared__ float red[8 * 32 * 12];

  const int tid  = threadIdx.x;
  const int w    = tid >> 6, lane = tid & 63;
  const int quad = lane >> 4, c16 = lane & 15;
  const int mg   = tid >> 5, nn = tid & 31;

  if (tid < 128) *(uint4*)(&K_lh[tid * 8]) = *(const uint4*)(Kb + (size_t)n0 * 32 + tid * 8);
  if (tid < 32) { mu[tid] = -1e30f; ell[tid] = 0.f; }
  float accp[12];
  #pragma unroll
  for (int t = 0; t < 12; ++t) accp[t] = 0.f;
  __syncthreads();

  for (int m0 = 0; m0 < N_; m0 += 64) {
    *(uint4*)(&Q_lh[tid * 8]) = *(const uint4*)(Qb + (size_t)m0 * 32 + tid * 8);
    if (tid < 192) *(float4*)(&x_l[tid * 4]) = *(const float4*)(xb + m0 * 12 + tid * 4);
    __syncthreads();

    bf16x8 afrag = *(const bf16x8*)(&Q_lh[(w * 16 + c16) * 32 + quad * 8]);
    f32x4 sc[2];
    float am[2][4], ch[2][4];
    #pragma unroll
    for (int ns = 0; ns < 2; ++ns) {
      bf16x8 bfrag = *(const bf16x8*)(&K_lh[(ns * 16 + c16) * 32 + quad * 8]);
      f32x4 z = {0.f, 0.f, 0.f, 0.f};
      sc[ns] = __builtin_amdgcn_mfma_f32_16x16x32_bf16(afrag, bfrag, z, 0, 0, 0);
      #pragma unroll
      for (int r = 0; r < 4; ++r) {
        int m = m0 + w * 16 + quad * 4 + r;
        uint p2 = pkk[(size_t)m * N_ + n0 + ns * 16 + c16];
        am[ns][r] = __uint_as_float(p2 << 16);
        ch[ns][r] = __uint_as_float(p2 & 0xFFFF0000u);
      }
    }
    float sv[2][4];
    #pragma unroll
    for (int ns = 0; ns < 2; ++ns) {
      float cmax = -1e30f;
      #pragma unroll
      for (int r = 0; r < 4; ++r) {
        sv[ns][r] = sc[ns][r] * RSQRT_DK + am[ns][r];
        cmax = fmaxf(cmax, sv[ns][r]);
      }
      cmax = fmaxf(cmax, __shfl_xor(cmax, 16));
      cmax = fmaxf(cmax, __shfl_xor(cmax, 32));
      if (lane < 16) pm[w * 32 + ns * 16 + lane] = cmax;
    }
    __syncthreads();
    if (tid < 32) {
      float tm = fmaxf(fmaxf(pm[tid], pm[32 + tid]), fmaxf(pm[64 + tid], pm[96 + tid]));
      float nm = fmaxf(mu[tid], tm);
      fac[tid] = __expf(mu[tid] - nm);
      mu[tid] = nm;
    }
    __syncthreads();
    {
      float f = fac[nn];
      #pragma unroll
      for (int t = 0; t < 12; ++t) accp[t] *= f;
    }
    #pragma unroll
    for (int ns = 0; ns < 2; ++ns) {
      float mcol = mu[ns * 16 + c16];
      float psum = 0.f;
      #pragma unroll
      for (int r = 0; r < 4; ++r) {
        float p = __expf(sv[ns][r] - mcol);
        psum += p;
        s_l[(w * 16 + quad * 4 + r) * 36 + ns * 16 + c16] = p * ch[ns][r];
      }
      psum += __shfl_xor(psum, 16);
      psum += __shfl_xor(psum, 32);
      if (lane < 16) ps[w * 32 + ns * 16 + lane] = psum;
    }
    __syncthreads();
    if (tid < 32)
      ell[tid] = ell[tid] * fac[tid] + ps[tid] + ps[32 + tid] + ps[64 + tid] + ps[96 + tid];
    #pragma unroll
    for (int mi = 0; mi < 8; ++mi) {
      int m = mg * 8 + mi;
      float pv = s_l[m * 36 + nn];
      const float* xr = &x_l[m * 12];
      #pragma unroll
      for (int t = 0; t < 12; ++t) accp[t] = fmaf(pv, xr[t], accp[t]);
    }
    __syncthreads();
  }
  if (tid < 32) inv[tid] = 1.f / ell[tid];
  #pragma unroll
  for (int t = 0; t < 12; ++t) red[(mg * 32 + nn) * 12 + t] = accp[t];
  __syncthreads();
  for (int idx = tid; idx < 384; idx += 256) {
    int n = idx / 12, t = idx - n * 12;
    float s = 0.f;
    #pragma unroll
    for (int g = 0; g < 8; ++g) s += red[(g * 32 + n) * 12 + t];
    rhs[((size_t)(b * K_ + k) * N_ + n0 + n) * 12 + t] = s * inv[n];
  }
}

// ---------------- K8 v2 (MFMA): Theta+relu -> GTU convs (MFMA) -> fcmy -> residual+LN ----------------
// Conv as GEMM per dt: C[co, n=j*32+site] += W_dt[co,ic] * X[site, j+dt, ic], K=ic=32.
// 24 n-tiles (j 0..11 x site-halves) x 2 m-pairs = 48 tasks over 16 waves (3 nt each).
template<int KS, int JV, int JB>
__device__ __forceinline__ void conv_mfma(const ushort* X_th, const ushort* wl_h,
                                          ushort* tc_h, const float* bias0,
                                          int mp, int ntg, int quad, int c16) {
  f32x4 accA[3], accB[3];
  #pragma unroll
  for (int i = 0; i < 3; ++i) { accA[i] = (f32x4){0.f,0.f,0.f,0.f}; accB[i] = (f32x4){0.f,0.f,0.f,0.f}; }
  #pragma unroll
  for (int dt = 0; dt < KS; ++dt) {
    bf16x8 A0 = *(const bf16x8*)&wl_h[dt * 2560 + (mp * 16 + c16) * 40 + quad * 8];
    bf16x8 A1 = *(const bf16x8*)&wl_h[dt * 2560 + ((mp + 2) * 16 + c16) * 40 + quad * 8];
    #pragma unroll
    for (int i = 0; i < 3; ++i) {
      int nt = ntg * 3 + i;
      int j = nt >> 1, sh = nt & 1;
      bf16x8 Bf = *(const bf16x8*)&X_th[(sh * 16 + c16) * 584 + (j + dt) * 32 + quad * 8];
      accA[i] = __builtin_amdgcn_mfma_f32_16x16x32_bf16(A0, Bf, accA[i], 0, 0, 0);
      accB[i] = __builtin_amdgcn_mfma_f32_16x16x32_bf16(A1, Bf, accB[i], 0, 0, 0);
    }
  }
  #pragma unroll
  for (int i = 0; i < 3; ++i) {
    int nt = ntg * 3 + i, j = nt >> 1, sh = nt & 1;
    if (j < JV) {
      int s = sh * 16 + c16;
      #pragma unroll
      for (int r = 0; r < 4; ++r) {
        int cc = mp * 16 + quad * 4 + r;
        float a = accA[i][r] + bias0[cc];
        float g = accB[i][r] + bias0[cc + 32];
        float e2a = __expf(2.f * a);
        float th = 1.f - 2.f / (e2a + 1.f);
        float sg = 1.f / (1.f + __expf(-g));
        tc_h[(s * 32 + cc) * 32 + (JB + j)] = f2bf(th * sg);
      }
    }
  }
}

__global__ __launch_bounds__(1024) void k8_fused(
                       const float* __restrict__ rhs, const float* __restrict__ Theta,
                       const float* __restrict__ x, const float* __restrict__ rw,
                       const float* __restrict__ rb,
                       const float* __restrict__ w3, const float* __restrict__ b3,
                       const float* __restrict__ w5, const float* __restrict__ b5,
                       const float* __restrict__ w7, const float* __restrict__ b7,
                       const float* __restrict__ fw, const float* __restrict__ fb,
                       const float* __restrict__ gf, const float* __restrict__ bf,
                       float* __restrict__ out) {
  int bn0 = blockIdx.x * 32;
  int b = bn0 >> 10, n0 = bn0 & 1023;

  // union region: X_th(37376 B) + wl_h(35840 B) during convs; v_l(49664 B) in epilogue
  __shared__ __align__(16) char uR[73216];
  ushort* X_th = (ushort*)uR;                 // [32 s][18 t][32 ic], site stride 584 shorts
  ushort* wl_h = (ushort*)(uR + 37376);       // [dt][64 co][40], dt stride 2560 shorts
  float*  v_l  = (float*)uR;                  // [32][388]
  __shared__ __align__(16) ushort tc_h[1024 * 32];   // [m=s*32+c][32], j 0..23 used
  __shared__ float rhs_l[32 * 36];
  __shared__ float Th_l[96];
  __shared__ float xr_l[32 * 12];
  __shared__ float fw_l[288];
  __shared__ float fb_l[12];
  __shared__ float bias_l[3][64];
  __shared__ float rw_l[32], rb_l[32], gf_l[32], bf_l[32];
  __shared__ float stm[384], str[384];

  int tid = threadIdx.x;
  int w = tid >> 6, lane = tid & 63, quad = lane >> 4, c16 = lane & 15;
  int mp = w & 1, ntg = w >> 1;
  int c = (tid >> 3) & 31;
  int site = (tid & 7) | ((tid >> 8) << 3);

  // ---- stage globals ----
  for (int idx = tid; idx < 1152; idx += 1024) {
    int s = idx / 36, r = idx - s * 36, k = r / 12, t = r - k * 12;
    rhs_l[idx] = rhs[((size_t)(b * 3 + k) * N_ + n0 + s) * 12 + t];
  }
  if (tid < 384) xr_l[tid] = x[(size_t)(b * N_ + n0) * 12 + tid];
  if (tid < 96) Th_l[tid] = Theta[tid];
  if (tid < 288) fw_l[tid] = fw[tid];
  if (tid < 12) fb_l[tid] = fb[tid];
  if (tid < 64) { bias_l[0][tid] = b3[tid]; bias_l[1][tid] = b5[tid]; bias_l[2][tid] = b7[tid]; }
  if (tid >= 64 && tid < 96)  rw_l[tid - 64] = rw[tid - 64];
  if (tid >= 96 && tid < 128) rb_l[tid - 96] = rb[tid - 96];
  if (tid >= 128 && tid < 160) gf_l[tid - 128] = gf[tid - 128];
  if (tid >= 160 && tid < 192) bf_l[tid - 160] = bf[tid - 160];
  // stage w3 -> wl_h bf16 [dt][co][ic]
  for (int idx = tid; idx < 64 * 32 * 3; idx += 1024) {
    int co = idx / 96, r2 = idx - co * 96, ic = r2 / 3, dt = r2 - ic * 3;
    wl_h[dt * 2560 + co * 40 + ic] = f2bf(w3[idx]);
  }
  __syncthreads();

  // ---- prologue: X = relu(rhs . Theta) -> bf16 X_th[s][t][ic] ; zero pad rows ----
  {
    float th0 = Th_l[c], th1 = Th_l[32 + c], th2 = Th_l[64 + c];
    const float* rs_ = &rhs_l[site * 36];
    ushort* xo = &X_th[site * 584 + c];
    #pragma unroll
    for (int t = 0; t < 12; ++t) {
      float a = rs_[t] * th0 + rs_[12 + t] * th1 + rs_[24 + t] * th2;
      xo[t * 32] = f2bf(fmaxf(a, 0.f));
    }
  }
  for (int idx = tid; idx < 32 * 6 * 32; idx += 1024) {   // zero rows t=12..17
    int s = idx / 192, r2 = idx - s * 192, tt = r2 >> 5, ic = r2 & 31;
    X_th[s * 584 + (12 + tt) * 32 + ic] = 0;
  }
  __syncthreads();

  // ---- conv phases ----
  conv_mfma<3, 10, 0>(X_th, wl_h, tc_h, &bias_l[0][0], mp, ntg, quad, c16);
  __syncthreads();
  for (int idx = tid; idx < 64 * 32 * 5; idx += 1024) {
    int co = idx / 160, r2 = idx - co * 160, ic = r2 / 5, dt = r2 - ic * 5;
    wl_h[dt * 2560 + co * 40 + ic] = f2bf(w5[idx]);
  }
  __syncthreads();
  conv_mfma<5, 8, 10>(X_th, wl_h, tc_h, &bias_l[1][0], mp, ntg, quad, c16);
  __syncthreads();
  for (int idx = tid; idx < 64 * 32 * 7; idx += 1024) {
    int co = idx / 224, r2 = idx - co * 224, ic = r2 / 7, dt = r2 - ic * 7;
    wl_h[dt * 2560 + co * 40 + ic] = f2bf(w7[idx]);
  }
  __syncthreads();
  conv_mfma<7, 6, 18>(X_th, wl_h, tc_h, &bias_l[2][0], mp, ntg, quad, c16);
  __syncthreads();

  // ---- fcmy: o[t] = fb + sum_j tc[j]*fw[j][t] (tc from LDS bf16) ----
  float tcv[24];
  {
    const ushort* tr = &tc_h[(site * 32 + c) * 32];
    #pragma unroll
    for (int j = 0; j < 24; ++j) tcv[j] = __uint_as_float(((uint)tr[j]) << 16);
  }
  float o[12];
  #pragma unroll
  for (int t = 0; t < 12; ++t) o[t] = fb_l[t];
  #pragma unroll
  for (int j = 0; j < 24; ++j) {
    const float4* fp = (const float4*)&fw_l[j * 12];
    float4 f0 = fp[0], f1 = fp[1], f2 = fp[2];
    float fr[12] = {f0.x, f0.y, f0.z, f0.w, f1.x, f1.y, f1.z, f1.w, f2.x, f2.y, f2.z, f2.w};
    #pragma unroll
    for (int t = 0; t < 12; ++t) o[t] = fmaf(tcv[j], fr[t], o[t]);
  }

  // ---- epilogue: v = relu(x_res + relu(o)); LN over c ----
  float v[12];
  {
    float rwc = rw_l[c], rbc = rb_l[c];
    const float* xs = &xr_l[site * 12];
    float* vo = &v_l[site * 388 + c * 12];
    #pragma unroll
    for (int t = 0; t < 12; ++t) {
      float xres = xs[t] * rwc + rbc;
      v[t] = fmaxf(xres + fmaxf(o[t], 0.f), 0.f);
      vo[t] = v[t];
    }
  }
  __syncthreads();
  if (tid < 384) {
    int s = tid / 12, t = tid - s * 12;
    float sm = 0.f, s2 = 0.f;
    #pragma unroll 8
    for (int cc = 0; cc < 32; ++cc) {
      float u = v_l[s * 388 + cc * 12 + t];
      sm += u; s2 += u * u;
    }
    float m = sm * (1.f / 32.f);
    stm[tid] = m;
    str[tid] = rsqrtf(s2 * (1.f / 32.f) - m * m + 1e-5f);
  }
  __syncthreads();
  {
    float gfc = gf_l[c], bfc = bf_l[c];
    const float* sm_ = &stm[site * 12];
    const float* sr_ = &str[site * 12];
    float q[12];
    #pragma unroll
    for (int t = 0; t < 12; ++t) q[t] = (v[t] - sm_[t]) * sr_[t] * gfc + bfc;
    float* op = &out[(size_t)(bn0 + site) * 384 + c * 12];
    ((float4*)op)[0] = make_float4(q[0], q[1], q[2], q[3]);
    ((float4*)op)[1] = make_float4(q[4], q[5], q[6], q[7]);
    ((float4*)op)[2] = make_float4(q[8], q[9], q[10], q[11]);
  }
}

// ---------------- launch ----------------
extern "C" void kernel_launch(void* const* d_in, const int* in_sizes, int n_in,
                              void* d_out, int out_size, void* d_ws, size_t ws_size,
                              hipStream_t stream) {
  const float* x       = (const float*)d_in[0];
  const float* res_att = (const float*)d_in[1];
  const float* posT    = (const float*)d_in[2];
  const float* gT      = (const float*)d_in[3];
  const float* bT      = (const float*)d_in[4];
  const float* WQt     = (const float*)d_in[5];
  const float* WKt     = (const float*)d_in[6];
  const float* WVt     = (const float*)d_in[7];
  const float* fct     = (const float*)d_in[8];
  const float* pcw     = (const float*)d_in[9];
  const float* pcb     = (const float*)d_in[10];
  const float* posS    = (const float*)d_in[11];
  const float* gS      = (const float*)d_in[12];
  const float* bS      = (const float*)d_in[13];
  const float* WQs     = (const float*)d_in[14];
  const float* WKs     = (const float*)d_in[15];
  const float* cheb    = (const float*)d_in[16];
  const float* adj     = (const float*)d_in[17];
  const float* mask    = (const float*)d_in[18];
  const float* Theta   = (const float*)d_in[19];
  const float* w3      = (const float*)d_in[20];
  const float* b3      = (const float*)d_in[21];
  const float* w5      = (const float*)d_in[22];
  const float* b5      = (const float*)d_in[23];
  const float* w7      = (const float*)d_in[24];
  const float* b7      = (const float*)d_in[25];
  const float* rw      = (const float*)d_in[26];
  const float* rb      = (const float*)d_in[27];
  const float* fw      = (const float*)d_in[28];
  const float* fb      = (const float*)d_in[29];
  const float* gf      = (const float*)d_in[30];
  const float* bf      = (const float*)d_in[31];

  float* ws = (float*)d_ws;
  float* TEmx = ws;                         // 196608
  float* qkv  = TEmx + 196608;              // 55296 (unused)
  float* ctx  = qkv + 55296;                // 18432
  float* TAT  = ctx + 18432;                // 196608
  float* SEmx = TAT + 196608;               // 8388608 (reused: part pre-k4, pk during k6)
  float* Qsf  = SEmx + 8388608;             // 1572864 slots (bf16 uses half)
  float* Ksf  = Qsf + 1572864;              // 1572864
  float* rhs  = Ksf + 1572864;              // 589824
  float* part = SEmx;                       // overlay: k2 partials, dead before k4

  __hip_bfloat16* Qh = (__hip_bfloat16*)Qsf;
  __hip_bfloat16* Kh = (__hip_bfloat16*)Ksf;
  uint* pk = (uint*)SEmx;                   // 3M uints = 12 MB, dead after k6

  float* out  = (float*)d_out;
  float* reAt = out + 6291456;

  k1_temporal_ln<<<B_ * T_, 256, 0, stream>>>(x, posT, gT, bT, TEmx);
  k2_qkv<<<dim3(4, B_ * T_), 256, 0, stream>>>(TEmx, WQt, WKt, WVt, part);
  k3a_attn<<<B_, 256, 0, stream>>>(part, res_att, reAt, ctx);
  k3b_tat<<<B_ * T_, 256, 0, stream>>>(ctx, fct, TEmx, TAT);
  k4_preconv_ln<<<B_ * N_, 256, 0, stream>>>(TAT, pcw, pcb, posS, gS, bS, SEmx);
  k5_qks<<<dim3(N_ / 32, B_), 256, 0, stream>>>(SEmx, WQs, WKs, Qh, Kh);
  k6_pre<<<(K_ * N_ * N_) / 256, 256, 0, stream>>>(adj, mask, cheb, pk);
  k6_spatial<<<dim3(B_, K_, N_ / 32), 256, 0, stream>>>(Qh, Kh, pk, x, rhs);
  k8_fused<<<B_ * N_ / 32, 1024, 0, stream>>>(rhs, Theta, x, rw, rb,
                                              w3, b3, w5, b5, w7, b7, fw, fb, gf, bf, out);
}

// Round 9
// 419.654 us; speedup vs baseline: 4.0383x; 1.2238x over previous
//
#include <hip/hip_runtime.h>
#include <hip/hip_bf16.h>
#include <math.h>

#define B_ 16
#define N_ 1024
#define T_ 12
#define DM_ 512
#define H_ 3
#define K_ 3
#define C_ 32
#define RSQRT_DK 0.17677669529663687f

typedef __attribute__((ext_vector_type(8))) short bf16x8;
typedef __attribute__((ext_vector_type(4))) float f32x4;

__device__ __forceinline__ ushort f2bf(float f) {   // RNE float->bf16 bits
  uint u = __float_as_uint(f);
  return (ushort)((u + 0x7FFF + ((u >> 16) & 1)) >> 16);
}

// ---------------- K1: temporal embedding LayerNorm over N ----------------
__global__ void k1_temporal_ln(const float* __restrict__ x, const float* __restrict__ posT,
                               const float* __restrict__ gT, const float* __restrict__ bT,
                               float* __restrict__ TEmx) {
  int row = blockIdx.x;                 // b*T + t
  int b = row / T_, t = row - b * T_;
  __shared__ float red[256], red2[256];
  float v[4]; float s = 0.f, s2 = 0.f;
  for (int i = 0; i < 4; ++i) {
    int n = threadIdx.x + (i << 8);
    float val = x[(b * N_ + n) * T_ + t] + posT[t * N_ + n];
    v[i] = val; s += val; s2 += val * val;
  }
  red[threadIdx.x] = s; red2[threadIdx.x] = s2;
  __syncthreads();
  for (int off = 128; off > 0; off >>= 1) {
    if (threadIdx.x < off) { red[threadIdx.x] += red[threadIdx.x + off]; red2[threadIdx.x] += red2[threadIdx.x + off]; }
    __syncthreads();
  }
  float mu = red[0] * (1.f / N_);
  float rs = rsqrtf(red2[0] * (1.f / N_) - mu * mu + 1e-5f);
  for (int i = 0; i < 4; ++i) {
    int n = threadIdx.x + (i << 8);
    TEmx[row * N_ + n] = (v[i] - mu) * rs * gT[n] + bT[n];
  }
}

// ---------------- K2 v2: temporal Q/K/V projections, K-split x4 ----------------
__global__ __launch_bounds__(256) void k2_qkv(const float* __restrict__ TEmx,
                       const float* __restrict__ WQ, const float* __restrict__ WK,
                       const float* __restrict__ WV, float* __restrict__ part) {
  int kc = blockIdx.x, row = blockIdx.y;
  __shared__ float e[256];
  int tid = threadIdx.x;
  e[tid] = TEmx[row * N_ + kc * 256 + tid];
  __syncthreads();
  for (int col = tid; col < 288; col += 256) {
    int which = col / 96, j = col - which * 96;
    const float* W = (which == 0) ? WQ : ((which == 1) ? WK : WV);
    const float* Wp = W + (size_t)(kc * 256) * 96 + j;
    float acc = 0.f;
    #pragma unroll 8
    for (int n = 0; n < 256; ++n) acc += e[n] * Wp[n * 96];
    part[(row * 4 + kc) * 288 + col] = acc;
  }
}

// ---------------- K3a: temporal attention (sums k2 partials during staging) ----------------
__global__ void k3a_attn(const float* __restrict__ part, const float* __restrict__ res_att,
                         float* __restrict__ reAt_out, float* __restrict__ ctx) {
  int b = blockIdx.x;
  __shared__ float q_l[T_ * 288];
  __shared__ float s_l[H_ * T_ * T_];
  for (int i = threadIdx.x; i < T_ * 288; i += 256) {
    int t = i / 288, col = i - t * 288;
    const float* pr = &part[(size_t)((b * T_ + t) * 4) * 288 + col];
    q_l[i] = pr[0] + pr[288] + pr[576] + pr[864];
  }
  __syncthreads();
  for (int idx = threadIdx.x; idx < H_ * T_ * T_; idx += 256) {
    int h = idx / 144, r = idx - h * 144, qi = r / 12, ki = r - qi * 12;
    float acc = 0.f;
    #pragma unroll
    for (int d = 0; d < 32; ++d)
      acc += q_l[qi * 288 + h * 32 + d] * q_l[ki * 288 + 96 + h * 32 + d];
    float sv = acc * RSQRT_DK + res_att[(b * H_ + h) * 144 + qi * 12 + ki];
    s_l[idx] = sv;
    reAt_out[(b * H_ + h) * 144 + qi * 12 + ki] = sv;
  }
  __syncthreads();
  if (threadIdx.x < 36) {
    int h = threadIdx.x / 12, qi = threadIdx.x - h * 12;
    float mx = -1e30f;
    for (int ki = 0; ki < 12; ++ki) mx = fmaxf(mx, s_l[h * 144 + qi * 12 + ki]);
    float sum = 0.f;
    for (int ki = 0; ki < 12; ++ki) { float p = __expf(s_l[h * 144 + qi * 12 + ki] - mx); s_l[h * 144 + qi * 12 + ki] = p; sum += p; }
    float inv = 1.f / sum;
    for (int ki = 0; ki < 12; ++ki) s_l[h * 144 + qi * 12 + ki] *= inv;
  }
  __syncthreads();
  for (int idx = threadIdx.x; idx < T_ * 96; idx += 256) {
    int qi = idx / 96, hd = idx - qi * 96, h = hd >> 5, d = hd & 31;
    float acc = 0.f;
    for (int ki = 0; ki < 12; ++ki)
      acc += s_l[h * 144 + qi * 12 + ki] * q_l[ki * 288 + 192 + h * 32 + d];
    ctx[(b * T_ + qi) * 96 + hd] = acc;
  }
}

// ---------------- K3b v2: ctx @ fc_t + TEmx, LayerNorm; 1024 thr, 1 n/thread ----------------
__global__ __launch_bounds__(1024) void k3b_tat(const float* __restrict__ ctx,
                        const float* __restrict__ fc_t,
                        const float* __restrict__ TEmx, float* __restrict__ TAT) {
  int row = blockIdx.x;
  __shared__ float c_l[96];
  __shared__ float red[16], red2[16];
  int tid = threadIdx.x;
  if (tid < 96) c_l[tid] = ctx[row * 96 + tid];
  __syncthreads();
  float acc = TEmx[row * N_ + tid];
  #pragma unroll 12
  for (int j = 0; j < 96; ++j) acc = fmaf(c_l[j], fc_t[j * N_ + tid], acc);
  float s = acc, s2 = acc * acc;
  #pragma unroll
  for (int off = 32; off > 0; off >>= 1) {
    s  += __shfl_xor(s, off);
    s2 += __shfl_xor(s2, off);
  }
  int w = tid >> 6;
  if ((tid & 63) == 0) { red[w] = s; red2[w] = s2; }
  __syncthreads();
  if (tid < 16) { /* no-op placeholder for clarity */ }
  float ts = 0.f, ts2 = 0.f;
  #pragma unroll
  for (int i = 0; i < 16; ++i) { ts += red[i]; ts2 += red2[i]; }
  float mu = ts * (1.f / N_);
  float rs = rsqrtf(ts2 * (1.f / N_) - mu * mu + 1e-5f);
  TAT[row * N_ + tid] = (acc - mu) * rs;
}

// ---------------- K4: pre_conv + pos_embed_S + LayerNorm over 512 ----------------
__global__ void k4_preconv_ln(const float* __restrict__ TAT, const float* __restrict__ pcw,
                              const float* __restrict__ pcb, const float* __restrict__ posS,
                              const float* __restrict__ gS, const float* __restrict__ bS,
                              float* __restrict__ SEmx) {
  int bn = blockIdx.x; int b = bn >> 10, n = bn & 1023;
  __shared__ float tc[12];
  __shared__ float red[256], red2[256];
  if (threadIdx.x < 12) tc[threadIdx.x] = TAT[(b * T_ + threadIdx.x) * N_ + n];
  __syncthreads();
  float v[2]; float s = 0.f, s2 = 0.f;
  for (int i = 0; i < 2; ++i) {
    int d = threadIdx.x + (i << 8);
    float acc = pcb[d];
    #pragma unroll
    for (int t = 0; t < 12; ++t) acc += tc[t] * pcw[d * 12 + t];
    acc += posS[n * DM_ + d];
    v[i] = acc; s += acc; s2 += acc * acc;
  }
  red[threadIdx.x] = s; red2[threadIdx.x] = s2;
  __syncthreads();
  for (int off = 128; off > 0; off >>= 1) {
    if (threadIdx.x < off) { red[threadIdx.x] += red[threadIdx.x + off]; red2[threadIdx.x] += red2[threadIdx.x + off]; }
    __syncthreads();
  }
  float mu = red[0] * (1.f / DM_);
  float rs = rsqrtf(red2[0] * (1.f / DM_) - mu * mu + 1e-5f);
  for (int i = 0; i < 2; ++i) {
    int d = threadIdx.x + (i << 8);
    SEmx[bn * DM_ + d] = (v[i] - mu) * rs * gS[d] + bS[d];
  }
}

// ---------------- K5 v4: spatial Q/K GEMM, 32-row tiles ----------------
__global__ __launch_bounds__(256) void k5_qks(const float* __restrict__ SEmx,
                                              const float* __restrict__ WQs,
                                              const float* __restrict__ WKs,
                                              __hip_bfloat16* __restrict__ Qs,
                                              __hip_bfloat16* __restrict__ Ks) {
  int b = blockIdx.y, n0 = blockIdx.x * 32;
  __shared__ float SE_l[32 * 65];
  __shared__ float W_l[64 * 196];
  int tid = threadIdx.x;
  int ng = tid >> 4, cg = tid & 15;
  int ng2 = ng * 2, col0 = cg * 12;
  float acc[2][12];
  #pragma unroll
  for (int i = 0; i < 2; ++i)
    #pragma unroll
    for (int j = 0; j < 12; ++j) acc[i][j] = 0.f;

  for (int dc = 0; dc < DM_; dc += 64) {
    for (int idx = tid; idx < 32 * 64; idx += 256) {
      int i = idx >> 6, j = idx & 63;
      SE_l[i * 65 + j] = SEmx[((b << 10) + n0 + i) * DM_ + dc + j];
    }
    for (int idx = tid; idx < 64 * 192; idx += 256) {
      int d = idx / 192, c = idx - d * 192;
      float v = (c < 96) ? WQs[(dc + d) * 96 + c] : WKs[(dc + d) * 96 + (c - 96)];
      W_l[d * 196 + c] = v;
    }
    __syncthreads();
    #pragma unroll 4
    for (int d = 0; d < 64; ++d) {
      float se[2];
      #pragma unroll
      for (int i = 0; i < 2; ++i) se[i] = SE_l[(ng2 + i) * 65 + d];
      const float4* wp = (const float4*)&W_l[d * 196 + col0];
      float4 w0 = wp[0], w1 = wp[1], w2 = wp[2];
      float wv[12] = {w0.x, w0.y, w0.z, w0.w, w1.x, w1.y, w1.z, w1.w, w2.x, w2.y, w2.z, w2.w};
      #pragma unroll
      for (int i = 0; i < 2; ++i)
        #pragma unroll
        for (int j = 0; j < 12; ++j)
          acc[i][j] = fmaf(se[i], wv[j], acc[i][j]);
    }
    __syncthreads();
  }
  #pragma unroll
  for (int i = 0; i < 2; ++i) {
    int n = n0 + ng2 + i;
    #pragma unroll
    for (int jj = 0; jj < 12; ++jj) {
      int col = col0 + jj;
      int j = (col < 96) ? col : col - 96;
      int k = j >> 5, dd = j & 31;
      __hip_bfloat16* o = (col < 96) ? Qs : Ks;
      o[(((b * K_ + k) * N_) + n) * 32 + dd] = __float2bfloat16(acc[i][jj]);
    }
  }
}

// ---------------- K6pre v2: pack {adj*mask, cheb} as 2xbf16 in uint ----------------
__global__ void k6_pre(const float* __restrict__ adj, const float* __restrict__ mask,
                       const float* __restrict__ cheb, uint* __restrict__ pk) {
  int idx = blockIdx.x * 256 + threadIdx.x;     // over 3*1024*1024
  int mn = idx & (N_ * N_ - 1);
  uint lo = f2bf(adj[mn] * mask[idx]);
  uint hi = f2bf(cheb[idx]);
  pk[idx] = lo | (hi << 16);
}

// ---------------- K6 v4: MFMA scores + online softmax; packed pk; b-major grid ----------------
__global__ __launch_bounds__(256) void k6_spatial(
    const __hip_bfloat16* __restrict__ Qs, const __hip_bfloat16* __restrict__ Ks,
    const uint* __restrict__ pk, const float* __restrict__ x,
    float* __restrict__ rhs) {
  const int b  = blockIdx.x;
  const int k  = blockIdx.y;
  const int n0 = blockIdx.z * 32;
  const ushort* Qb = (const ushort*)(Qs + (size_t)((b * K_ + k) * N_) * 32);
  const ushort* Kb = (const ushort*)(Ks + (size_t)((b * K_ + k) * N_) * 32);
  const uint* pkk = pk + (size_t)k * (N_ * N_);
  const float*  xb  = x + b * N_ * T_;

  __shared__ __align__(16) ushort Q_lh[64 * 32];
  __shared__ __align__(16) ushort K_lh[32 * 32];
  __shared__ __align__(16) float  x_l[64 * 12];
  __shared__ float s_l[64 * 36];
  __shared__ float pm[4 * 32], ps[4 * 32];
  __shared__ float mu[32], ell[32], fac[32], inv[32];
  __shared__ float red[8 * 32 * 12];

  const int tid  = threadIdx.x;
  const int w    = tid >> 6, lane = tid & 63;
  const int quad = lane >> 4, c16 = lane & 15;
  const int mg   = tid >> 5, nn = tid & 31;

  if (tid < 128) *(uint4*)(&K_lh[tid * 8]) = *(const uint4*)(Kb + (size_t)n0 * 32 + tid * 8);
  if (tid < 32) { mu[tid] = -1e30f; ell[tid] = 0.f; }
  float accp[12];
  #pragma unroll
  for (int t = 0; t < 12; ++t) accp[t] = 0.f;
  __syncthreads();

  for (int m0 = 0; m0 < N_; m0 += 64) {
    *(uint4*)(&Q_lh[tid * 8]) = *(const uint4*)(Qb + (size_t)m0 * 32 + tid * 8);
    if (tid < 192) *(float4*)(&x_l[tid * 4]) = *(const float4*)(xb + m0 * 12 + tid * 4);
    __syncthreads();

    bf16x8 afrag = *(const bf16x8*)(&Q_lh[(w * 16 + c16) * 32 + quad * 8]);
    f32x4 sc[2];
    float am[2][4], ch[2][4];
    #pragma unroll
    for (int ns = 0; ns < 2; ++ns) {
      bf16x8 bfrag = *(const bf16x8*)(&K_lh[(ns * 16 + c16) * 32 + quad * 8]);
      f32x4 z = {0.f, 0.f, 0.f, 0.f};
      sc[ns] = __builtin_amdgcn_mfma_f32_16x16x32_bf16(afrag, bfrag, z, 0, 0, 0);
      #pragma unroll
      for (int r = 0; r < 4; ++r) {
        int m = m0 + w * 16 + quad * 4 + r;
        uint p2 = pkk[(size_t)m * N_ + n0 + ns * 16 + c16];
        am[ns][r] = __uint_as_float(p2 << 16);
        ch[ns][r] = __uint_as_float(p2 & 0xFFFF0000u);
      }
    }
    float sv[2][4];
    #pragma unroll
    for (int ns = 0; ns < 2; ++ns) {
      float cmax = -1e30f;
      #pragma unroll
      for (int r = 0; r < 4; ++r) {
        sv[ns][r] = sc[ns][r] * RSQRT_DK + am[ns][r];
        cmax = fmaxf(cmax, sv[ns][r]);
      }
      cmax = fmaxf(cmax, __shfl_xor(cmax, 16));
      cmax = fmaxf(cmax, __shfl_xor(cmax, 32));
      if (lane < 16) pm[w * 32 + ns * 16 + lane] = cmax;
    }
    __syncthreads();
    if (tid < 32) {
      float tm = fmaxf(fmaxf(pm[tid], pm[32 + tid]), fmaxf(pm[64 + tid], pm[96 + tid]));
      float nm = fmaxf(mu[tid], tm);
      fac[tid] = __expf(mu[tid] - nm);
      mu[tid] = nm;
    }
    __syncthreads();
    {
      float f = fac[nn];
      #pragma unroll
      for (int t = 0; t < 12; ++t) accp[t] *= f;
    }
    #pragma unroll
    for (int ns = 0; ns < 2; ++ns) {
      float mcol = mu[ns * 16 + c16];
      float psum = 0.f;
      #pragma unroll
      for (int r = 0; r < 4; ++r) {
        float p = __expf(sv[ns][r] - mcol);
        psum += p;
        s_l[(w * 16 + quad * 4 + r) * 36 + ns * 16 + c16] = p * ch[ns][r];
      }
      psum += __shfl_xor(psum, 16);
      psum += __shfl_xor(psum, 32);
      if (lane < 16) ps[w * 32 + ns * 16 + lane] = psum;
    }
    __syncthreads();
    if (tid < 32)
      ell[tid] = ell[tid] * fac[tid] + ps[tid] + ps[32 + tid] + ps[64 + tid] + ps[96 + tid];
    #pragma unroll
    for (int mi = 0; mi < 8; ++mi) {
      int m = mg * 8 + mi;
      float pv = s_l[m * 36 + nn];
      const float* xr = &x_l[m * 12];
      #pragma unroll
      for (int t = 0; t < 12; ++t) accp[t] = fmaf(pv, xr[t], accp[t]);
    }
    __syncthreads();
  }
  if (tid < 32) inv[tid] = 1.f / ell[tid];
  #pragma unroll
  for (int t = 0; t < 12; ++t) red[(mg * 32 + nn) * 12 + t] = accp[t];
  __syncthreads();
  for (int idx = tid; idx < 384; idx += 256) {
    int n = idx / 12, t = idx - n * 12;
    float s = 0.f;
    #pragma unroll
    for (int g = 0; g < 8; ++g) s += red[(g * 32 + n) * 12 + t];
    rhs[((size_t)(b * K_ + k) * N_ + n0 + n) * 12 + t] = s * inv[n];
  }
}

// ---------------- K8 v2 (MFMA): Theta+relu -> GTU convs (MFMA) -> fcmy -> residual+LN ----------------
template<int KS, int JV, int JB>
__device__ __forceinline__ void conv_mfma(const ushort* X_th, const ushort* wl_h,
                                          ushort* tc_h, const float* bias0,
                                          int mp, int ntg, int quad, int c16) {
  f32x4 accA[3], accB[3];
  #pragma unroll
  for (int i = 0; i < 3; ++i) { accA[i] = (f32x4){0.f,0.f,0.f,0.f}; accB[i] = (f32x4){0.f,0.f,0.f,0.f}; }
  #pragma unroll
  for (int dt = 0; dt < KS; ++dt) {
    bf16x8 A0 = *(const bf16x8*)&wl_h[dt * 2560 + (mp * 16 + c16) * 40 + quad * 8];
    bf16x8 A1 = *(const bf16x8*)&wl_h[dt * 2560 + ((mp + 2) * 16 + c16) * 40 + quad * 8];
    #pragma unroll
    for (int i = 0; i < 3; ++i) {
      int nt = ntg * 3 + i;
      int j = nt >> 1, sh = nt & 1;
      bf16x8 Bf = *(const bf16x8*)&X_th[(sh * 16 + c16) * 584 + (j + dt) * 32 + quad * 8];
      accA[i] = __builtin_amdgcn_mfma_f32_16x16x32_bf16(A0, Bf, accA[i], 0, 0, 0);
      accB[i] = __builtin_amdgcn_mfma_f32_16x16x32_bf16(A1, Bf, accB[i], 0, 0, 0);
    }
  }
  #pragma unroll
  for (int i = 0; i < 3; ++i) {
    int nt = ntg * 3 + i, j = nt >> 1, sh = nt & 1;
    if (j < JV) {
      int s = sh * 16 + c16;
      #pragma unroll
      for (int r = 0; r < 4; ++r) {
        int cc = mp * 16 + quad * 4 + r;
        float a = accA[i][r] + bias0[cc];
        float g = accB[i][r] + bias0[cc + 32];
        float e2a = __expf(2.f * a);
        float th = 1.f - 2.f / (e2a + 1.f);
        float sg = 1.f / (1.f + __expf(-g));
        tc_h[(s * 32 + cc) * 32 + (JB + j)] = f2bf(th * sg);
      }
    }
  }
}

__global__ __launch_bounds__(1024) void k8_fused(
                       const float* __restrict__ rhs, const float* __restrict__ Theta,
                       const float* __restrict__ x, const float* __restrict__ rw,
                       const float* __restrict__ rb,
                       const float* __restrict__ w3, const float* __restrict__ b3,
                       const float* __restrict__ w5, const float* __restrict__ b5,
                       const float* __restrict__ w7, const float* __restrict__ b7,
                       const float* __restrict__ fw, const float* __restrict__ fb,
                       const float* __restrict__ gf, const float* __restrict__ bf,
                       float* __restrict__ out) {
  int bn0 = blockIdx.x * 32;
  int b = bn0 >> 10, n0 = bn0 & 1023;

  __shared__ __align__(16) char uR[73216];
  ushort* X_th = (ushort*)uR;                 // [32 s][18 t][32 ic], site stride 584 shorts
  ushort* wl_h = (ushort*)(uR + 37376);       // [dt][64 co][40], dt stride 2560 shorts
  float*  v_l  = (float*)uR;                  // [32][388]
  __shared__ __align__(16) ushort tc_h[1024 * 32];
  __shared__ float rhs_l[32 * 36];
  __shared__ float Th_l[96];
  __shared__ float xr_l[32 * 12];
  __shared__ float fw_l[288];
  __shared__ float fb_l[12];
  __shared__ float bias_l[3][64];
  __shared__ float rw_l[32], rb_l[32], gf_l[32], bf_l[32];
  __shared__ float stm[384], str[384];

  int tid = threadIdx.x;
  int w = tid >> 6, lane = tid & 63, quad = lane >> 4, c16 = lane & 15;
  int mp = w & 1, ntg = w >> 1;
  int c = (tid >> 3) & 31;
  int site = (tid & 7) | ((tid >> 8) << 3);

  for (int idx = tid; idx < 1152; idx += 1024) {
    int s = idx / 36, r = idx - s * 36, k = r / 12, t = r - k * 12;
    rhs_l[idx] = rhs[((size_t)(b * 3 + k) * N_ + n0 + s) * 12 + t];
  }
  if (tid < 384) xr_l[tid] = x[(size_t)(b * N_ + n0) * 12 + tid];
  if (tid < 96) Th_l[tid] = Theta[tid];
  if (tid < 288) fw_l[tid] = fw[tid];
  if (tid < 12) fb_l[tid] = fb[tid];
  if (tid < 64) { bias_l[0][tid] = b3[tid]; bias_l[1][tid] = b5[tid]; bias_l[2][tid] = b7[tid]; }
  if (tid >= 64 && tid < 96)  rw_l[tid - 64] = rw[tid - 64];
  if (tid >= 96 && tid < 128) rb_l[tid - 96] = rb[tid - 96];
  if (tid >= 128 && tid < 160) gf_l[tid - 128] = gf[tid - 128];
  if (tid >= 160 && tid < 192) bf_l[tid - 160] = bf[tid - 160];
  for (int idx = tid; idx < 64 * 32 * 3; idx += 1024) {
    int co = idx / 96, r2 = idx - co * 96, ic = r2 / 3, dt = r2 - ic * 3;
    wl_h[dt * 2560 + co * 40 + ic] = f2bf(w3[idx]);
  }
  __syncthreads();

  {
    float th0 = Th_l[c], th1 = Th_l[32 + c], th2 = Th_l[64 + c];
    const float* rs_ = &rhs_l[site * 36];
    ushort* xo = &X_th[site * 584 + c];
    #pragma unroll
    for (int t = 0; t < 12; ++t) {
      float a = rs_[t] * th0 + rs_[12 + t] * th1 + rs_[24 + t] * th2;
      xo[t * 32] = f2bf(fmaxf(a, 0.f));
    }
  }
  for (int idx = tid; idx < 32 * 6 * 32; idx += 1024) {
    int s = idx / 192, r2 = idx - s * 192, tt = r2 >> 5, ic = r2 & 31;
    X_th[s * 584 + (12 + tt) * 32 + ic] = 0;
  }
  __syncthreads();

  conv_mfma<3, 10, 0>(X_th, wl_h, tc_h, &bias_l[0][0], mp, ntg, quad, c16);
  __syncthreads();
  for (int idx = tid; idx < 64 * 32 * 5; idx += 1024) {
    int co = idx / 160, r2 = idx - co * 160, ic = r2 / 5, dt = r2 - ic * 5;
    wl_h[dt * 2560 + co * 40 + ic] = f2bf(w5[idx]);
  }
  __syncthreads();
  conv_mfma<5, 8, 10>(X_th, wl_h, tc_h, &bias_l[1][0], mp, ntg, quad, c16);
  __syncthreads();
  for (int idx = tid; idx < 64 * 32 * 7; idx += 1024) {
    int co = idx / 224, r2 = idx - co * 224, ic = r2 / 7, dt = r2 - ic * 7;
    wl_h[dt * 2560 + co * 40 + ic] = f2bf(w7[idx]);
  }
  __syncthreads();
  conv_mfma<7, 6, 18>(X_th, wl_h, tc_h, &bias_l[2][0], mp, ntg, quad, c16);
  __syncthreads();

  float tcv[24];
  {
    const ushort* tr = &tc_h[(site * 32 + c) * 32];
    #pragma unroll
    for (int j = 0; j < 24; ++j) tcv[j] = __uint_as_float(((uint)tr[j]) << 16);
  }
  float o[12];
  #pragma unroll
  for (int t = 0; t < 12; ++t) o[t] = fb_l[t];
  #pragma unroll
  for (int j = 0; j < 24; ++j) {
    const float4* fp = (const float4*)&fw_l[j * 12];
    float4 f0 = fp[0], f1 = fp[1], f2 = fp[2];
    float fr[12] = {f0.x, f0.y, f0.z, f0.w, f1.x, f1.y, f1.z, f1.w, f2.x, f2.y, f2.z, f2.w};
    #pragma unroll
    for (int t = 0; t < 12; ++t) o[t] = fmaf(tcv[j], fr[t], o[t]);
  }

  float v[12];
  {
    float rwc = rw_l[c], rbc = rb_l[c];
    const float* xs = &xr_l[site * 12];
    float* vo = &v_l[site * 388 + c * 12];
    #pragma unroll
    for (int t = 0; t < 12; ++t) {
      float xres = xs[t] * rwc + rbc;
      v[t] = fmaxf(xres + fmaxf(o[t], 0.f), 0.f);
      vo[t] = v[t];
    }
  }
  __syncthreads();
  if (tid < 384) {
    int s = tid / 12, t = tid - s * 12;
    float sm = 0.f, s2 = 0.f;
    #pragma unroll 8
    for (int cc = 0; cc < 32; ++cc) {
      float u = v_l[s * 388 + cc * 12 + t];
      sm += u; s2 += u * u;
    }
    float m = sm * (1.f / 32.f);
    stm[tid] = m;
    str[tid] = rsqrtf(s2 * (1.f / 32.f) - m * m + 1e-5f);
  }
  __syncthreads();
  {
    float gfc = gf_l[c], bfc = bf_l[c];
    const float* sm_ = &stm[site * 12];
    const float* sr_ = &str[site * 12];
    float q[12];
    #pragma unroll
    for (int t = 0; t < 12; ++t) q[t] = (v[t] - sm_[t]) * sr_[t] * gfc + bfc;
    float* op = &out[(size_t)(bn0 + site) * 384 + c * 12];
    ((float4*)op)[0] = make_float4(q[0], q[1], q[2], q[3]);
    ((float4*)op)[1] = make_float4(q[4], q[5], q[6], q[7]);
    ((float4*)op)[2] = make_float4(q[8], q[9], q[10], q[11]);
  }
}

// ---------------- launch ----------------
extern "C" void kernel_launch(void* const* d_in, const int* in_sizes, int n_in,
                              void* d_out, int out_size, void* d_ws, size_t ws_size,
                              hipStream_t stream) {
  const float* x       = (const float*)d_in[0];
  const float* res_att = (const float*)d_in[1];
  const float* posT    = (const float*)d_in[2];
  const float* gT      = (const float*)d_in[3];
  const float* bT      = (const float*)d_in[4];
  const float* WQt     = (const float*)d_in[5];
  const float* WKt     = (const float*)d_in[6];
  const float* WVt     = (const float*)d_in[7];
  const float* fct     = (const float*)d_in[8];
  const float* pcw     = (const float*)d_in[9];
  const float* pcb     = (const float*)d_in[10];
  const float* posS    = (const float*)d_in[11];
  const float* gS      = (const float*)d_in[12];
  const float* bS      = (const float*)d_in[13];
  const float* WQs     = (const float*)d_in[14];
  const float* WKs     = (const float*)d_in[15];
  const float* cheb    = (const float*)d_in[16];
  const float* adj     = (const float*)d_in[17];
  const float* mask    = (const float*)d_in[18];
  const float* Theta   = (const float*)d_in[19];
  const float* w3      = (const float*)d_in[20];
  const float* b3      = (const float*)d_in[21];
  const float* w5      = (const float*)d_in[22];
  const float* b5      = (const float*)d_in[23];
  const float* w7      = (const float*)d_in[24];
  const float* b7      = (const float*)d_in[25];
  const float* rw      = (const float*)d_in[26];
  const float* rb      = (const float*)d_in[27];
  const float* fw      = (const float*)d_in[28];
  const float* fb      = (const float*)d_in[29];
  const float* gf      = (const float*)d_in[30];
  const float* bf      = (const float*)d_in[31];

  float* ws = (float*)d_ws;
  float* TEmx = ws;                         // 196608
  float* qkv  = TEmx + 196608;              // 55296 (unused)
  float* ctx  = qkv + 55296;                // 18432
  float* TAT  = ctx + 18432;                // 196608
  float* SEmx = TAT + 196608;               // 8388608 (reused: part pre-k4, pk during k6)
  float* Qsf  = SEmx + 8388608;             // 1572864 slots (bf16 uses half)
  float* Ksf  = Qsf + 1572864;              // 1572864
  float* rhs  = Ksf + 1572864;              // 589824
  float* part = SEmx;                       // overlay: k2 partials, dead before k4

  __hip_bfloat16* Qh = (__hip_bfloat16*)Qsf;
  __hip_bfloat16* Kh = (__hip_bfloat16*)Ksf;
  uint* pk = (uint*)SEmx;                   // 3M uints = 12 MB, dead after k6

  float* out  = (float*)d_out;
  float* reAt = out + 6291456;

  k1_temporal_ln<<<B_ * T_, 256, 0, stream>>>(x, posT, gT, bT, TEmx);
  k2_qkv<<<dim3(4, B_ * T_), 256, 0, stream>>>(TEmx, WQt, WKt, WVt, part);
  k3a_attn<<<B_, 256, 0, stream>>>(part, res_att, reAt, ctx);
  k3b_tat<<<B_ * T_, 1024, 0, stream>>>(ctx, fct, TEmx, TAT);
  k4_preconv_ln<<<B_ * N_, 256, 0, stream>>>(TAT, pcw, pcb, posS, gS, bS, SEmx);
  k5_qks<<<dim3(N_ / 32, B_), 256, 0, stream>>>(SEmx, WQs, WKs, Qh, Kh);
  k6_pre<<<(K_ * N_ * N_) / 256, 256, 0, stream>>>(adj, mask, cheb, pk);
  k6_spatial<<<dim3(B_, K_, N_ / 32), 256, 0, stream>>>(Qh, Kh, pk, x, rhs);
  k8_fused<<<B_ * N_ / 32, 1024, 0, stream>>>(rhs, Theta, x, rw, rb,
                                              w3, b3, w5, b5, w7, b7, fw, fb, gf, bf, out);
}

// Round 10
// 376.761 us; speedup vs baseline: 4.4980x; 1.1138x over previous
//
#include <hip/hip_runtime.h>
#include <hip/hip_bf16.h>
#include <math.h>

#define B_ 16
#define N_ 1024
#define T_ 12
#define DM_ 512
#define H_ 3
#define K_ 3
#define C_ 32
#define RSQRT_DK 0.17677669529663687f

typedef __attribute__((ext_vector_type(8))) short bf16x8;
typedef __attribute__((ext_vector_type(4))) float f32x4;

__device__ __forceinline__ ushort f2bf(float f) {   // RNE float->bf16 bits
  uint u = __float_as_uint(f);
  return (ushort)((u + 0x7FFF + ((u >> 16) & 1)) >> 16);
}

// ---------------- K1: temporal embedding LayerNorm over N ----------------
__global__ void k1_temporal_ln(const float* __restrict__ x, const float* __restrict__ posT,
                               const float* __restrict__ gT, const float* __restrict__ bT,
                               float* __restrict__ TEmx) {
  int row = blockIdx.x;                 // b*T + t
  int b = row / T_, t = row - b * T_;
  __shared__ float red[256], red2[256];
  float v[4]; float s = 0.f, s2 = 0.f;
  for (int i = 0; i < 4; ++i) {
    int n = threadIdx.x + (i << 8);
    float val = x[(b * N_ + n) * T_ + t] + posT[t * N_ + n];
    v[i] = val; s += val; s2 += val * val;
  }
  red[threadIdx.x] = s; red2[threadIdx.x] = s2;
  __syncthreads();
  for (int off = 128; off > 0; off >>= 1) {
    if (threadIdx.x < off) { red[threadIdx.x] += red[threadIdx.x + off]; red2[threadIdx.x] += red2[threadIdx.x + off]; }
    __syncthreads();
  }
  float mu = red[0] * (1.f / N_);
  float rs = rsqrtf(red2[0] * (1.f / N_) - mu * mu + 1e-5f);
  for (int i = 0; i < 4; ++i) {
    int n = threadIdx.x + (i << 8);
    TEmx[row * N_ + n] = (v[i] - mu) * rs * gT[n] + bT[n];
  }
}

// ---------------- K2 v2: temporal Q/K/V projections, K-split x4 ----------------
__global__ __launch_bounds__(256) void k2_qkv(const float* __restrict__ TEmx,
                       const float* __restrict__ WQ, const float* __restrict__ WK,
                       const float* __restrict__ WV, float* __restrict__ part) {
  int kc = blockIdx.x, row = blockIdx.y;
  __shared__ float e[256];
  int tid = threadIdx.x;
  e[tid] = TEmx[row * N_ + kc * 256 + tid];
  __syncthreads();
  for (int col = tid; col < 288; col += 256) {
    int which = col / 96, j = col - which * 96;
    const float* W = (which == 0) ? WQ : ((which == 1) ? WK : WV);
    const float* Wp = W + (size_t)(kc * 256) * 96 + j;
    float acc = 0.f;
    #pragma unroll 8
    for (int n = 0; n < 256; ++n) acc += e[n] * Wp[n * 96];
    part[(row * 4 + kc) * 288 + col] = acc;
  }
}

// ---------------- K3a: temporal attention (sums k2 partials during staging) ----------------
__global__ void k3a_attn(const float* __restrict__ part, const float* __restrict__ res_att,
                         float* __restrict__ reAt_out, float* __restrict__ ctx) {
  int b = blockIdx.x;
  __shared__ float q_l[T_ * 288];
  __shared__ float s_l[H_ * T_ * T_];
  for (int i = threadIdx.x; i < T_ * 288; i += 256) {
    int t = i / 288, col = i - t * 288;
    const float* pr = &part[(size_t)((b * T_ + t) * 4) * 288 + col];
    q_l[i] = pr[0] + pr[288] + pr[576] + pr[864];
  }
  __syncthreads();
  for (int idx = threadIdx.x; idx < H_ * T_ * T_; idx += 256) {
    int h = idx / 144, r = idx - h * 144, qi = r / 12, ki = r - qi * 12;
    float acc = 0.f;
    #pragma unroll
    for (int d = 0; d < 32; ++d)
      acc += q_l[qi * 288 + h * 32 + d] * q_l[ki * 288 + 96 + h * 32 + d];
    float sv = acc * RSQRT_DK + res_att[(b * H_ + h) * 144 + qi * 12 + ki];
    s_l[idx] = sv;
    reAt_out[(b * H_ + h) * 144 + qi * 12 + ki] = sv;
  }
  __syncthreads();
  if (threadIdx.x < 36) {
    int h = threadIdx.x / 12, qi = threadIdx.x - h * 12;
    float mx = -1e30f;
    for (int ki = 0; ki < 12; ++ki) mx = fmaxf(mx, s_l[h * 144 + qi * 12 + ki]);
    float sum = 0.f;
    for (int ki = 0; ki < 12; ++ki) { float p = __expf(s_l[h * 144 + qi * 12 + ki] - mx); s_l[h * 144 + qi * 12 + ki] = p; sum += p; }
    float inv = 1.f / sum;
    for (int ki = 0; ki < 12; ++ki) s_l[h * 144 + qi * 12 + ki] *= inv;
  }
  __syncthreads();
  for (int idx = threadIdx.x; idx < T_ * 96; idx += 256) {
    int qi = idx / 96, hd = idx - qi * 96, h = hd >> 5, d = hd & 31;
    float acc = 0.f;
    for (int ki = 0; ki < 12; ++ki)
      acc += s_l[h * 144 + qi * 12 + ki] * q_l[ki * 288 + 192 + h * 32 + d];
    ctx[(b * T_ + qi) * 96 + hd] = acc;
  }
}

// ---------------- K3b v2: ctx @ fc_t + TEmx, LayerNorm; 1024 thr, 1 n/thread ----------------
__global__ __launch_bounds__(1024) void k3b_tat(const float* __restrict__ ctx,
                        const float* __restrict__ fc_t,
                        const float* __restrict__ TEmx, float* __restrict__ TAT) {
  int row = blockIdx.x;
  __shared__ float c_l[96];
  __shared__ float red[16], red2[16];
  int tid = threadIdx.x;
  if (tid < 96) c_l[tid] = ctx[row * 96 + tid];
  __syncthreads();
  float acc = TEmx[row * N_ + tid];
  #pragma unroll 12
  for (int j = 0; j < 96; ++j) acc = fmaf(c_l[j], fc_t[j * N_ + tid], acc);
  float s = acc, s2 = acc * acc;
  #pragma unroll
  for (int off = 32; off > 0; off >>= 1) {
    s  += __shfl_xor(s, off);
    s2 += __shfl_xor(s2, off);
  }
  int w = tid >> 6;
  if ((tid & 63) == 0) { red[w] = s; red2[w] = s2; }
  __syncthreads();
  float ts = 0.f, ts2 = 0.f;
  #pragma unroll
  for (int i = 0; i < 16; ++i) { ts += red[i]; ts2 += red2[i]; }
  float mu = ts * (1.f / N_);
  float rs = rsqrtf(ts2 * (1.f / N_) - mu * mu + 1e-5f);
  TAT[row * N_ + tid] = (acc - mu) * rs;
}

// ---------------- K4: pre_conv + pos_embed_S + LayerNorm over 512 ----------------
__global__ void k4_preconv_ln(const float* __restrict__ TAT, const float* __restrict__ pcw,
                              const float* __restrict__ pcb, const float* __restrict__ posS,
                              const float* __restrict__ gS, const float* __restrict__ bS,
                              float* __restrict__ SEmx) {
  int bn = blockIdx.x; int b = bn >> 10, n = bn & 1023;
  __shared__ float tc[12];
  __shared__ float red[256], red2[256];
  if (threadIdx.x < 12) tc[threadIdx.x] = TAT[(b * T_ + threadIdx.x) * N_ + n];
  __syncthreads();
  float v[2]; float s = 0.f, s2 = 0.f;
  for (int i = 0; i < 2; ++i) {
    int d = threadIdx.x + (i << 8);
    float acc = pcb[d];
    #pragma unroll
    for (int t = 0; t < 12; ++t) acc += tc[t] * pcw[d * 12 + t];
    acc += posS[n * DM_ + d];
    v[i] = acc; s += acc; s2 += acc * acc;
  }
  red[threadIdx.x] = s; red2[threadIdx.x] = s2;
  __syncthreads();
  for (int off = 128; off > 0; off >>= 1) {
    if (threadIdx.x < off) { red[threadIdx.x] += red[threadIdx.x + off]; red2[threadIdx.x] += red2[threadIdx.x + off]; }
    __syncthreads();
  }
  float mu = red[0] * (1.f / DM_);
  float rs = rsqrtf(red2[0] * (1.f / DM_) - mu * mu + 1e-5f);
  for (int i = 0; i < 2; ++i) {
    int d = threadIdx.x + (i << 8);
    SEmx[bn * DM_ + d] = (v[i] - mu) * rs * gS[d] + bS[d];
  }
}

// ---------------- K5pre: [WQs|WKs] -> bf16 wpre[col][512] ----------------
__global__ void k5_pre(const float* __restrict__ WQs, const float* __restrict__ WKs,
                       ushort* __restrict__ wpre) {
  int idx = blockIdx.x * 256 + threadIdx.x;   // over 512*192
  int k = idx / 192, col = idx - k * 192;
  float v = (col < 96) ? WQs[k * 96 + col] : WKs[k * 96 + (col - 96)];
  wpre[col * 512 + k] = f2bf(v);
}

// ---------------- K5 v5: spatial Q/K projections as bf16 MFMA GEMM ----------------
// C[col=m][node=n] = sum_d W[d][col]*SE[node][d]; A=wpre[col][512], B=SE_h[node][520]
__global__ __launch_bounds__(256) void k5_qks(const float* __restrict__ SEmx,
                                              const ushort* __restrict__ wpre,
                                              __hip_bfloat16* __restrict__ Qs,
                                              __hip_bfloat16* __restrict__ Ks) {
  int b = blockIdx.y, n0 = blockIdx.x * 32;
  __shared__ __align__(16) ushort SE_h[32 * 520];   // [node][k], pad 8 -> 2-way free
  int tid = threadIdx.x;
  // stage SE tile f32 -> bf16: 16384 elems, 4/iter/thread
  for (int idx = tid; idx < 4096; idx += 256) {
    int r = idx >> 7, cq = idx & 127;
    float4 v = *(const float4*)&SEmx[((size_t)((b << 10) + n0 + r)) * DM_ + cq * 4];
    uint lo = (uint)f2bf(v.x) | ((uint)f2bf(v.y) << 16);
    uint hi = (uint)f2bf(v.z) | ((uint)f2bf(v.w) << 16);
    *(uint2*)&SE_h[r * 520 + cq * 4] = make_uint2(lo, hi);
  }
  __syncthreads();

  int w = tid >> 6, lane = tid & 63, quad = lane >> 4, c16 = lane & 15;
  f32x4 acc[3][2];
  #pragma unroll
  for (int mi = 0; mi < 3; ++mi)
    #pragma unroll
    for (int nt = 0; nt < 2; ++nt) acc[mi][nt] = (f32x4){0.f, 0.f, 0.f, 0.f};

  for (int ks = 0; ks < 16; ++ks) {
    bf16x8 Bf0 = *(const bf16x8*)&SE_h[(0 * 16 + c16) * 520 + ks * 32 + quad * 8];
    bf16x8 Bf1 = *(const bf16x8*)&SE_h[(1 * 16 + c16) * 520 + ks * 32 + quad * 8];
    #pragma unroll
    for (int mi = 0; mi < 3; ++mi) {
      int m = (w * 3 + mi) * 16 + c16;
      bf16x8 Af = *(const bf16x8*)&wpre[m * 512 + ks * 32 + quad * 8];
      acc[mi][0] = __builtin_amdgcn_mfma_f32_16x16x32_bf16(Af, Bf0, acc[mi][0], 0, 0, 0);
      acc[mi][1] = __builtin_amdgcn_mfma_f32_16x16x32_bf16(Af, Bf1, acc[mi][1], 0, 0, 0);
    }
  }
  #pragma unroll
  for (int mi = 0; mi < 3; ++mi) {
    int mb = (w * 3 + mi) * 16;
    #pragma unroll
    for (int nt = 0; nt < 2; ++nt) {
      int node = n0 + nt * 16 + c16;
      #pragma unroll
      for (int r = 0; r < 4; ++r) {
        int m = mb + quad * 4 + r;                 // 0..191
        int j = (m < 96) ? m : m - 96;
        int kk = j >> 5, dd = j & 31;
        __hip_bfloat16* o = (m < 96) ? Qs : Ks;
        o[(((b * K_ + kk) * N_) + node) * 32 + dd] = __float2bfloat16(acc[mi][nt][r]);
      }
    }
  }
}

// ---------------- K6pre v2: pack {adj*mask, cheb} as 2xbf16 in uint ----------------
__global__ void k6_pre(const float* __restrict__ adj, const float* __restrict__ mask,
                       const float* __restrict__ cheb, uint* __restrict__ pk) {
  int idx = blockIdx.x * 256 + threadIdx.x;     // over 3*1024*1024
  int mn = idx & (N_ * N_ - 1);
  uint lo = f2bf(adj[mn] * mask[idx]);
  uint hi = f2bf(cheb[idx]);
  pk[idx] = lo | (hi << 16);
}

// ---------------- K6 v4: MFMA scores + online softmax; packed pk; b-major grid ----------------
__global__ __launch_bounds__(256) void k6_spatial(
    const __hip_bfloat16* __restrict__ Qs, const __hip_bfloat16* __restrict__ Ks,
    const uint* __restrict__ pk, const float* __restrict__ x,
    float* __restrict__ rhs) {
  const int b  = blockIdx.x;
  const int k  = blockIdx.y;
  const int n0 = blockIdx.z * 32;
  const ushort* Qb = (const ushort*)(Qs + (size_t)((b * K_ + k) * N_) * 32);
  const ushort* Kb = (const ushort*)(Ks + (size_t)((b * K_ + k) * N_) * 32);
  const uint* pkk = pk + (size_t)k * (N_ * N_);
  const float*  xb  = x + b * N_ * T_;

  __shared__ __align__(16) ushort Q_lh[64 * 32];
  __shared__ __align__(16) ushort K_lh[32 * 32];
  __shared__ __align__(16) float  x_l[64 * 12];
  __shared__ float s_l[64 * 36];
  __shared__ float pm[4 * 32], ps[4 * 32];
  __shared__ float mu[32], ell[32], fac[32], inv[32];
  __shared__ float red[8 * 32 * 12];

  const int tid  = threadIdx.x;
  const int w    = tid >> 6, lane = tid & 63;
  const int quad = lane >> 4, c16 = lane & 15;
  const int mg   = tid >> 5, nn = tid & 31;

  if (tid < 128) *(uint4*)(&K_lh[tid * 8]) = *(const uint4*)(Kb + (size_t)n0 * 32 + tid * 8);
  if (tid < 32) { mu[tid] = -1e30f; ell[tid] = 0.f; }
  float accp[12];
  #pragma unroll
  for (int t = 0; t < 12; ++t) accp[t] = 0.f;
  __syncthreads();

  for (int m0 = 0; m0 < N_; m0 += 64) {
    *(uint4*)(&Q_lh[tid * 8]) = *(const uint4*)(Qb + (size_t)m0 * 32 + tid * 8);
    if (tid < 192) *(float4*)(&x_l[tid * 4]) = *(const float4*)(xb + m0 * 12 + tid * 4);
    __syncthreads();

    bf16x8 afrag = *(const bf16x8*)(&Q_lh[(w * 16 + c16) * 32 + quad * 8]);
    f32x4 sc[2];
    float am[2][4], ch[2][4];
    #pragma unroll
    for (int ns = 0; ns < 2; ++ns) {
      bf16x8 bfrag = *(const bf16x8*)(&K_lh[(ns * 16 + c16) * 32 + quad * 8]);
      f32x4 z = {0.f, 0.f, 0.f, 0.f};
      sc[ns] = __builtin_amdgcn_mfma_f32_16x16x32_bf16(afrag, bfrag, z, 0, 0, 0);
      #pragma unroll
      for (int r = 0; r < 4; ++r) {
        int m = m0 + w * 16 + quad * 4 + r;
        uint p2 = pkk[(size_t)m * N_ + n0 + ns * 16 + c16];
        am[ns][r] = __uint_as_float(p2 << 16);
        ch[ns][r] = __uint_as_float(p2 & 0xFFFF0000u);
      }
    }
    float sv[2][4];
    #pragma unroll
    for (int ns = 0; ns < 2; ++ns) {
      float cmax = -1e30f;
      #pragma unroll
      for (int r = 0; r < 4; ++r) {
        sv[ns][r] = sc[ns][r] * RSQRT_DK + am[ns][r];
        cmax = fmaxf(cmax, sv[ns][r]);
      }
      cmax = fmaxf(cmax, __shfl_xor(cmax, 16));
      cmax = fmaxf(cmax, __shfl_xor(cmax, 32));
      if (lane < 16) pm[w * 32 + ns * 16 + lane] = cmax;
    }
    __syncthreads();
    if (tid < 32) {
      float tm = fmaxf(fmaxf(pm[tid], pm[32 + tid]), fmaxf(pm[64 + tid], pm[96 + tid]));
      float nm = fmaxf(mu[tid], tm);
      fac[tid] = __expf(mu[tid] - nm);
      mu[tid] = nm;
    }
    __syncthreads();
    {
      float f = fac[nn];
      #pragma unroll
      for (int t = 0; t < 12; ++t) accp[t] *= f;
    }
    #pragma unroll
    for (int ns = 0; ns < 2; ++ns) {
      float mcol = mu[ns * 16 + c16];
      float psum = 0.f;
      #pragma unroll
      for (int r = 0; r < 4; ++r) {
        float p = __expf(sv[ns][r] - mcol);
        psum += p;
        s_l[(w * 16 + quad * 4 + r) * 36 + ns * 16 + c16] = p * ch[ns][r];
      }
      psum += __shfl_xor(psum, 16);
      psum += __shfl_xor(psum, 32);
      if (lane < 16) ps[w * 32 + ns * 16 + lane] = psum;
    }
    __syncthreads();
    if (tid < 32)
      ell[tid] = ell[tid] * fac[tid] + ps[tid] + ps[32 + tid] + ps[64 + tid] + ps[96 + tid];
    #pragma unroll
    for (int mi = 0; mi < 8; ++mi) {
      int m = mg * 8 + mi;
      float pv = s_l[m * 36 + nn];
      const float* xr = &x_l[m * 12];
      #pragma unroll
      for (int t = 0; t < 12; ++t) accp[t] = fmaf(pv, xr[t], accp[t]);
    }
    __syncthreads();
  }
  if (tid < 32) inv[tid] = 1.f / ell[tid];
  #pragma unroll
  for (int t = 0; t < 12; ++t) red[(mg * 32 + nn) * 12 + t] = accp[t];
  __syncthreads();
  for (int idx = tid; idx < 384; idx += 256) {
    int n = idx / 12, t = idx - n * 12;
    float s = 0.f;
    #pragma unroll
    for (int g = 0; g < 8; ++g) s += red[(g * 32 + n) * 12 + t];
    rhs[((size_t)(b * K_ + k) * N_ + n0 + n) * 12 + t] = s * inv[n];
  }
}

// ---------------- K8 v2 (MFMA): Theta+relu -> GTU convs (MFMA) -> fcmy -> residual+LN ----------------
template<int KS, int JV, int JB>
__device__ __forceinline__ void conv_mfma(const ushort* X_th, const ushort* wl_h,
                                          ushort* tc_h, const float* bias0,
                                          int mp, int ntg, int quad, int c16) {
  f32x4 accA[3], accB[3];
  #pragma unroll
  for (int i = 0; i < 3; ++i) { accA[i] = (f32x4){0.f,0.f,0.f,0.f}; accB[i] = (f32x4){0.f,0.f,0.f,0.f}; }
  #pragma unroll
  for (int dt = 0; dt < KS; ++dt) {
    bf16x8 A0 = *(const bf16x8*)&wl_h[dt * 2560 + (mp * 16 + c16) * 40 + quad * 8];
    bf16x8 A1 = *(const bf16x8*)&wl_h[dt * 2560 + ((mp + 2) * 16 + c16) * 40 + quad * 8];
    #pragma unroll
    for (int i = 0; i < 3; ++i) {
      int nt = ntg * 3 + i;
      int j = nt >> 1, sh = nt & 1;
      bf16x8 Bf = *(const bf16x8*)&X_th[(sh * 16 + c16) * 584 + (j + dt) * 32 + quad * 8];
      accA[i] = __builtin_amdgcn_mfma_f32_16x16x32_bf16(A0, Bf, accA[i], 0, 0, 0);
      accB[i] = __builtin_amdgcn_mfma_f32_16x16x32_bf16(A1, Bf, accB[i], 0, 0, 0);
    }
  }
  #pragma unroll
  for (int i = 0; i < 3; ++i) {
    int nt = ntg * 3 + i, j = nt >> 1, sh = nt & 1;
    if (j < JV) {
      int s = sh * 16 + c16;
      #pragma unroll
      for (int r = 0; r < 4; ++r) {
        int cc = mp * 16 + quad * 4 + r;
        float a = accA[i][r] + bias0[cc];
        float g = accB[i][r] + bias0[cc + 32];
        float e2a = __expf(2.f * a);
        float th = 1.f - 2.f / (e2a + 1.f);
        float sg = 1.f / (1.f + __expf(-g));
        tc_h[(s * 32 + cc) * 32 + (JB + j)] = f2bf(th * sg);
      }
    }
  }
}

__global__ __launch_bounds__(1024) void k8_fused(
                       const float* __restrict__ rhs, const float* __restrict__ Theta,
                       const float* __restrict__ x, const float* __restrict__ rw,
                       const float* __restrict__ rb,
                       const float* __restrict__ w3, const float* __restrict__ b3,
                       const float* __restrict__ w5, const float* __restrict__ b5,
                       const float* __restrict__ w7, const float* __restrict__ b7,
                       const float* __restrict__ fw, const float* __restrict__ fb,
                       const float* __restrict__ gf, const float* __restrict__ bf,
                       float* __restrict__ out) {
  int bn0 = blockIdx.x * 32;
  int b = bn0 >> 10, n0 = bn0 & 1023;

  __shared__ __align__(16) char uR[73216];
  ushort* X_th = (ushort*)uR;                 // [32 s][18 t][32 ic], site stride 584 shorts
  ushort* wl_h = (ushort*)(uR + 37376);       // [dt][64 co][40], dt stride 2560 shorts
  float*  v_l  = (float*)uR;                  // [32][388]
  __shared__ __align__(16) ushort tc_h[1024 * 32];
  __shared__ float rhs_l[32 * 36];
  __shared__ float Th_l[96];
  __shared__ float xr_l[32 * 12];
  __shared__ float fw_l[288];
  __shared__ float fb_l[12];
  __shared__ float bias_l[3][64];
  __shared__ float rw_l[32], rb_l[32], gf_l[32], bf_l[32];
  __shared__ float stm[384], str[384];

  int tid = threadIdx.x;
  int w = tid >> 6, lane = tid & 63, quad = lane >> 4, c16 = lane & 15;
  int mp = w & 1, ntg = w >> 1;
  int c = (tid >> 3) & 31;
  int site = (tid & 7) | ((tid >> 8) << 3);

  for (int idx = tid; idx < 1152; idx += 1024) {
    int s = idx / 36, r = idx - s * 36, k = r / 12, t = r - k * 12;
    rhs_l[idx] = rhs[((size_t)(b * 3 + k) * N_ + n0 + s) * 12 + t];
  }
  if (tid < 384) xr_l[tid] = x[(size_t)(b * N_ + n0) * 12 + tid];
  if (tid < 96) Th_l[tid] = Theta[tid];
  if (tid < 288) fw_l[tid] = fw[tid];
  if (tid < 12) fb_l[tid] = fb[tid];
  if (tid < 64) { bias_l[0][tid] = b3[tid]; bias_l[1][tid] = b5[tid]; bias_l[2][tid] = b7[tid]; }
  if (tid >= 64 && tid < 96)  rw_l[tid - 64] = rw[tid - 64];
  if (tid >= 96 && tid < 128) rb_l[tid - 96] = rb[tid - 96];
  if (tid >= 128 && tid < 160) gf_l[tid - 128] = gf[tid - 128];
  if (tid >= 160 && tid < 192) bf_l[tid - 160] = bf[tid - 160];
  for (int idx = tid; idx < 64 * 32 * 3; idx += 1024) {
    int co = idx / 96, r2 = idx - co * 96, ic = r2 / 3, dt = r2 - ic * 3;
    wl_h[dt * 2560 + co * 40 + ic] = f2bf(w3[idx]);
  }
  __syncthreads();

  {
    float th0 = Th_l[c], th1 = Th_l[32 + c], th2 = Th_l[64 + c];
    const float* rs_ = &rhs_l[site * 36];
    ushort* xo = &X_th[site * 584 + c];
    #pragma unroll
    for (int t = 0; t < 12; ++t) {
      float a = rs_[t] * th0 + rs_[12 + t] * th1 + rs_[24 + t] * th2;
      xo[t * 32] = f2bf(fmaxf(a, 0.f));
    }
  }
  for (int idx = tid; idx < 32 * 6 * 32; idx += 1024) {
    int s = idx / 192, r2 = idx - s * 192, tt = r2 >> 5, ic = r2 & 31;
    X_th[s * 584 + (12 + tt) * 32 + ic] = 0;
  }
  __syncthreads();

  conv_mfma<3, 10, 0>(X_th, wl_h, tc_h, &bias_l[0][0], mp, ntg, quad, c16);
  __syncthreads();
  for (int idx = tid; idx < 64 * 32 * 5; idx += 1024) {
    int co = idx / 160, r2 = idx - co * 160, ic = r2 / 5, dt = r2 - ic * 5;
    wl_h[dt * 2560 + co * 40 + ic] = f2bf(w5[idx]);
  }
  __syncthreads();
  conv_mfma<5, 8, 10>(X_th, wl_h, tc_h, &bias_l[1][0], mp, ntg, quad, c16);
  __syncthreads();
  for (int idx = tid; idx < 64 * 32 * 7; idx += 1024) {
    int co = idx / 224, r2 = idx - co * 224, ic = r2 / 7, dt = r2 - ic * 7;
    wl_h[dt * 2560 + co * 40 + ic] = f2bf(w7[idx]);
  }
  __syncthreads();
  conv_mfma<7, 6, 18>(X_th, wl_h, tc_h, &bias_l[2][0], mp, ntg, quad, c16);
  __syncthreads();

  float tcv[24];
  {
    const ushort* tr = &tc_h[(site * 32 + c) * 32];
    #pragma unroll
    for (int j = 0; j < 24; ++j) tcv[j] = __uint_as_float(((uint)tr[j]) << 16);
  }
  float o[12];
  #pragma unroll
  for (int t = 0; t < 12; ++t) o[t] = fb_l[t];
  #pragma unroll
  for (int j = 0; j < 24; ++j) {
    const float4* fp = (const float4*)&fw_l[j * 12];
    float4 f0 = fp[0], f1 = fp[1], f2 = fp[2];
    float fr[12] = {f0.x, f0.y, f0.z, f0.w, f1.x, f1.y, f1.z, f1.w, f2.x, f2.y, f2.z, f2.w};
    #pragma unroll
    for (int t = 0; t < 12; ++t) o[t] = fmaf(tcv[j], fr[t], o[t]);
  }

  float v[12];
  {
    float rwc = rw_l[c], rbc = rb_l[c];
    const float* xs = &xr_l[site * 12];
    float* vo = &v_l[site * 388 + c * 12];
    #pragma unroll
    for (int t = 0; t < 12; ++t) {
      float xres = xs[t] * rwc + rbc;
      v[t] = fmaxf(xres + fmaxf(o[t], 0.f), 0.f);
      vo[t] = v[t];
    }
  }
  __syncthreads();
  if (tid < 384) {
    int s = tid / 12, t = tid - s * 12;
    float sm = 0.f, s2 = 0.f;
    #pragma unroll 8
    for (int cc = 0; cc < 32; ++cc) {
      float u = v_l[s * 388 + cc * 12 + t];
      sm += u; s2 += u * u;
    }
    float m = sm * (1.f / 32.f);
    stm[tid] = m;
    str[tid] = rsqrtf(s2 * (1.f / 32.f) - m * m + 1e-5f);
  }
  __syncthreads();
  {
    float gfc = gf_l[c], bfc = bf_l[c];
    const float* sm_ = &stm[site * 12];
    const float* sr_ = &str[site * 12];
    float q[12];
    #pragma unroll
    for (int t = 0; t < 12; ++t) q[t] = (v[t] - sm_[t]) * sr_[t] * gfc + bfc;
    float* op = &out[(size_t)(bn0 + site) * 384 + c * 12];
    ((float4*)op)[0] = make_float4(q[0], q[1], q[2], q[3]);
    ((float4*)op)[1] = make_float4(q[4], q[5], q[6], q[7]);
    ((float4*)op)[2] = make_float4(q[8], q[9], q[10], q[11]);
  }
}

// ---------------- launch ----------------
extern "C" void kernel_launch(void* const* d_in, const int* in_sizes, int n_in,
                              void* d_out, int out_size, void* d_ws, size_t ws_size,
                              hipStream_t stream) {
  const float* x       = (const float*)d_in[0];
  const float* res_att = (const float*)d_in[1];
  const float* posT    = (const float*)d_in[2];
  const float* gT      = (const float*)d_in[3];
  const float* bT      = (const float*)d_in[4];
  const float* WQt     = (const float*)d_in[5];
  const float* WKt     = (const float*)d_in[6];
  const float* WVt     = (const float*)d_in[7];
  const float* fct     = (const float*)d_in[8];
  const float* pcw     = (const float*)d_in[9];
  const float* pcb     = (const float*)d_in[10];
  const float* posS    = (const float*)d_in[11];
  const float* gS      = (const float*)d_in[12];
  const float* bS      = (const float*)d_in[13];
  const float* WQs     = (const float*)d_in[14];
  const float* WKs     = (const float*)d_in[15];
  const float* cheb    = (const float*)d_in[16];
  const float* adj     = (const float*)d_in[17];
  const float* mask    = (const float*)d_in[18];
  const float* Theta   = (const float*)d_in[19];
  const float* w3      = (const float*)d_in[20];
  const float* b3      = (const float*)d_in[21];
  const float* w5      = (const float*)d_in[22];
  const float* b5      = (const float*)d_in[23];
  const float* w7      = (const float*)d_in[24];
  const float* b7      = (const float*)d_in[25];
  const float* rw      = (const float*)d_in[26];
  const float* rb      = (const float*)d_in[27];
  const float* fw      = (const float*)d_in[28];
  const float* fb      = (const float*)d_in[29];
  const float* gf      = (const float*)d_in[30];
  const float* bf      = (const float*)d_in[31];

  float* ws = (float*)d_ws;
  float* TEmx = ws;                         // 196608
  float* qkv  = TEmx + 196608;              // 55296 (unused)
  float* ctx  = qkv + 55296;                // 18432
  float* TAT  = ctx + 18432;                // 196608
  float* SEmx = TAT + 196608;               // 8388608 (reused: part pre-k4, pk during k6)
  float* Qsf  = SEmx + 8388608;             // 1572864 slots (bf16 uses half)
  float* Ksf  = Qsf + 1572864;              // 1572864
  float* rhs  = Ksf + 1572864;              // 589824
  ushort* wpre = (ushort*)(rhs + 589824);   // 98304 shorts (former tco slot)
  float* part = SEmx;                       // overlay: k2 partials, dead before k4

  __hip_bfloat16* Qh = (__hip_bfloat16*)Qsf;
  __hip_bfloat16* Kh = (__hip_bfloat16*)Ksf;
  uint* pk = (uint*)SEmx;                   // 3M uints = 12 MB, dead after k6

  float* out  = (float*)d_out;
  float* reAt = out + 6291456;

  k5_pre<<<(DM_ * 192) / 256, 256, 0, stream>>>(WQs, WKs, wpre);
  k1_temporal_ln<<<B_ * T_, 256, 0, stream>>>(x, posT, gT, bT, TEmx);
  k2_qkv<<<dim3(4, B_ * T_), 256, 0, stream>>>(TEmx, WQt, WKt, WVt, part);
  k3a_attn<<<B_, 256, 0, stream>>>(part, res_att, reAt, ctx);
  k3b_tat<<<B_ * T_, 1024, 0, stream>>>(ctx, fct, TEmx, TAT);
  k4_preconv_ln<<<B_ * N_, 256, 0, stream>>>(TAT, pcw, pcb, posS, gS, bS, SEmx);
  k5_qks<<<dim3(N_ / 32, B_), 256, 0, stream>>>(SEmx, wpre, Qh, Kh);
  k6_pre<<<(K_ * N_ * N_) / 256, 256, 0, stream>>>(adj, mask, cheb, pk);
  k6_spatial<<<dim3(B_, K_, N_ / 32), 256, 0, stream>>>(Qh, Kh, pk, x, rhs);
  k8_fused<<<B_ * N_ / 32, 1024, 0, stream>>>(rhs, Theta, x, rw, rb,
                                              w3, b3, w5, b5, w7, b7, fw, fb, gf, bf, out);
}